// Round 3
// baseline (1440.732 us; speedup 1.0000x reference)
//
#include <hip/hip_runtime.h>
#include <hip/hip_bf16.h>
#include <cstdint>

#define NSEQ  2048
#define BSZ   2
#define NTOK  4096          // B*N
#define EDIM  1024
#define NEXP  16
#define CAPC  160
#define HFF_R 2730
#define HFF_P 2752          // padded to multiple of 64

typedef __bf16 bf16_t;
typedef __bf16 bf16x8 __attribute__((ext_vector_type(8)));
typedef __bf16 bf16x4 __attribute__((ext_vector_type(4)));
typedef float  f32x4  __attribute__((ext_vector_type(4)));
typedef unsigned int uint32;

__device__ inline bf16x8 zero8() {
    bf16x8 v;
#pragma unroll
    for (int i = 0; i < 8; i++) v[i] = (bf16_t)0.f;
    return v;
}
__device__ inline bf16x8 pack8(float4 a, float4 b) {
    bf16x8 v;
    v[0]=(bf16_t)a.x; v[1]=(bf16_t)a.y; v[2]=(bf16_t)a.z; v[3]=(bf16_t)a.w;
    v[4]=(bf16_t)b.x; v[5]=(bf16_t)b.y; v[6]=(bf16_t)b.z; v[7]=(bf16_t)b.w;
    return v;
}
struct hl_t { bf16_t h, l; };
__device__ inline hl_t split1(float f) {
    hl_t r;
    r.h = (bf16_t)f;
    r.l = (bf16_t)(f - (float)r.h);
    return r;
}

// ---------------------------------------------------------------------------
// Split-precision NT GEMM: C[M,N] = epi(A * B^T + bias), A,B f32.
// Each operand split a = hi + lo (bf16); products hi*hi + hi*lo + lo*hi give
// ~2^-18 relative error (f32-class). BM=BN=128, BK=32, 4 waves 2x2.
// EPI: 0 = bias (+ optional col-scale); 2 = bias + residual.
// C_SPLIT: 1 -> write bf16 hi/lo pair buffers; 0 -> write f32.
// M, N multiples of 128; K multiple of 32 (no guards).
// ---------------------------------------------------------------------------
template <int EPI, int C_SPLIT>
__global__ __launch_bounds__(256) void gemm_split(
    const float* __restrict__ A, const float* __restrict__ Bw,
    const float* __restrict__ bias, const float* __restrict__ resid,
    bf16_t* __restrict__ Chi, bf16_t* __restrict__ Clo, float* __restrict__ Cf,
    int M, int N, int K, int scale_cut, float scale_val)
{
    __shared__ __align__(16) bf16_t Ah[128 * 40], Al[128 * 40];
    __shared__ __align__(16) bf16_t Bh[128 * 40], Bl[128 * 40];
    const int t = threadIdx.x;
    const int m0 = blockIdx.y * 128, n0 = blockIdx.x * 128;
    const int lane = t & 63, l15 = lane & 15, lg = lane >> 4;
    const int wid = t >> 6, wm = wid >> 1, wn = wid & 1;
    const int srow = t >> 1, skc = (t & 1) * 16;

    f32x4 acc[4][4];
    const f32x4 zf = {0.f, 0.f, 0.f, 0.f};
#pragma unroll
    for (int i = 0; i < 4; i++)
#pragma unroll
        for (int j = 0; j < 4; j++) acc[i][j] = zf;

    for (int k0 = 0; k0 < K; k0 += 32) {
        {
            float av[16];
            const float* ap = A + (long)(m0 + srow) * K + k0 + skc;
            *(float4*)&av[0]  = *(const float4*)ap;
            *(float4*)&av[4]  = *(const float4*)(ap + 4);
            *(float4*)&av[8]  = *(const float4*)(ap + 8);
            *(float4*)&av[12] = *(const float4*)(ap + 12);
            bf16x8 h0, h1, l0, l1;
#pragma unroll
            for (int i = 0; i < 8; i++) {
                hl_t a = split1(av[i]);      h0[i] = a.h; l0[i] = a.l;
                hl_t b = split1(av[8 + i]);  h1[i] = b.h; l1[i] = b.l;
            }
            *(bf16x8*)&Ah[srow * 40 + skc] = h0; *(bf16x8*)&Ah[srow * 40 + skc + 8] = h1;
            *(bf16x8*)&Al[srow * 40 + skc] = l0; *(bf16x8*)&Al[srow * 40 + skc + 8] = l1;
        }
        {
            float bv[16];
            const float* bp = Bw + (long)(n0 + srow) * K + k0 + skc;
            *(float4*)&bv[0]  = *(const float4*)bp;
            *(float4*)&bv[4]  = *(const float4*)(bp + 4);
            *(float4*)&bv[8]  = *(const float4*)(bp + 8);
            *(float4*)&bv[12] = *(const float4*)(bp + 12);
            bf16x8 h0, h1, l0, l1;
#pragma unroll
            for (int i = 0; i < 8; i++) {
                hl_t a = split1(bv[i]);      h0[i] = a.h; l0[i] = a.l;
                hl_t b = split1(bv[8 + i]);  h1[i] = b.h; l1[i] = b.l;
            }
            *(bf16x8*)&Bh[srow * 40 + skc] = h0; *(bf16x8*)&Bh[srow * 40 + skc + 8] = h1;
            *(bf16x8*)&Bl[srow * 40 + skc] = l0; *(bf16x8*)&Bl[srow * 40 + skc + 8] = l1;
        }
        __syncthreads();
        bf16x8 amh[4], aml[4], bnh[4], bnl[4];
#pragma unroll
        for (int i = 0; i < 4; i++) {
            int base = (wm * 64 + i * 16 + l15) * 40 + lg * 8;
            amh[i] = *(const bf16x8*)&Ah[base];
            aml[i] = *(const bf16x8*)&Al[base];
        }
#pragma unroll
        for (int j = 0; j < 4; j++) {
            int base = (wn * 64 + j * 16 + l15) * 40 + lg * 8;
            bnh[j] = *(const bf16x8*)&Bh[base];
            bnl[j] = *(const bf16x8*)&Bl[base];
        }
#pragma unroll
        for (int i = 0; i < 4; i++)
#pragma unroll
            for (int j = 0; j < 4; j++) {
                acc[i][j] = __builtin_amdgcn_mfma_f32_16x16x32_bf16(amh[i], bnh[j], acc[i][j], 0, 0, 0);
                acc[i][j] = __builtin_amdgcn_mfma_f32_16x16x32_bf16(amh[i], bnl[j], acc[i][j], 0, 0, 0);
                acc[i][j] = __builtin_amdgcn_mfma_f32_16x16x32_bf16(aml[i], bnh[j], acc[i][j], 0, 0, 0);
            }
        __syncthreads();
    }

#pragma unroll
    for (int i = 0; i < 4; i++) {
        int mgb = m0 + wm * 64 + i * 16 + lg * 4;
#pragma unroll
        for (int j = 0; j < 4; j++) {
            int ng = n0 + wn * 64 + j * 16 + l15;
            float bval = bias[ng];
#pragma unroll
            for (int r = 0; r < 4; r++) {
                int mg = mgb + r;
                float val = acc[i][j][r] + bval;
                if (scale_cut > 0 && ng < scale_cut) val *= scale_val;
                if (EPI == 2) val += resid[(long)mg * N + ng];
                long idx = (long)mg * N + ng;
                if (C_SPLIT) {
                    bf16_t hi = (bf16_t)val;
                    Chi[idx] = hi;
                    Clo[idx] = (bf16_t)(val - (float)hi);
                } else {
                    Cf[idx] = val;
                }
            }
        }
    }
}

// ---------------------------------------------------------------------------
// bf16 NT GEMM (expert FFN path, value-precision only).
// A: bf16 row-major; B: f32 row-major. EPI: 0 bias, 1 bias+LeakyReLU.
// Writes cols [0,Nwr); value forced 0 for cols in [N,Nwr).
// ---------------------------------------------------------------------------
template <int EPI, int C_BF16>
__global__ __launch_bounds__(256) void gemm_nt(
    const bf16_t* __restrict__ Av, const float* __restrict__ Bw,
    const float* __restrict__ bias, void* __restrict__ Cv,
    int M, int N, int Nwr, int KA, int KB,
    long sAe, long sBe, long sBiasE, long sCe, int ldc)
{
    __shared__ __align__(16) bf16_t Alds[128 * 40];
    __shared__ __align__(16) bf16_t Blds[128 * 40];
    const int t = threadIdx.x;
    const int e = blockIdx.z;
    const int m0 = blockIdx.y * 128, n0 = blockIdx.x * 128;
    const int lane = t & 63, l15 = lane & 15, lg = lane >> 4;
    const int wid = t >> 6, wm = wid >> 1, wn = wid & 1;
    const int srow = t >> 1, skc = (t & 1) * 16;

    f32x4 acc[4][4];
    const f32x4 zf = {0.f, 0.f, 0.f, 0.f};
#pragma unroll
    for (int i = 0; i < 4; i++)
#pragma unroll
        for (int j = 0; j < 4; j++) acc[i][j] = zf;

    for (int k0 = 0; k0 < KA; k0 += 32) {
        {
            int mg = m0 + srow;
            bf16x8 v0 = zero8(), v1 = zero8();
            if (mg < M) {
                const bf16_t* ap = Av + (long)e * sAe + (long)mg * KA + k0 + skc;
                v0 = *(const bf16x8*)ap;
                v1 = *(const bf16x8*)(ap + 8);
            }
            *(bf16x8*)&Alds[srow * 40 + skc] = v0;
            *(bf16x8*)&Alds[srow * 40 + skc + 8] = v1;
        }
        {
            int ng = n0 + srow;
            bf16x8 v0 = zero8(), v1 = zero8();
            if (ng < N) {
                const float* bp = Bw + (long)e * sBe + (long)ng * KB + k0 + skc;
                if (k0 + 32 <= KB) {
                    float4 a = *(const float4*)bp, b = *(const float4*)(bp + 4);
                    float4 c = *(const float4*)(bp + 8), d = *(const float4*)(bp + 12);
                    v0 = pack8(a, b); v1 = pack8(c, d);
                } else {
#pragma unroll
                    for (int i = 0; i < 8; i++) {
                        int kk = k0 + skc + i;
                        v0[i] = (kk < KB) ? (bf16_t)bp[i] : (bf16_t)0.f;
                    }
#pragma unroll
                    for (int i = 0; i < 8; i++) {
                        int kk = k0 + skc + 8 + i;
                        v1[i] = (kk < KB) ? (bf16_t)bp[8 + i] : (bf16_t)0.f;
                    }
                }
            }
            *(bf16x8*)&Blds[srow * 40 + skc] = v0;
            *(bf16x8*)&Blds[srow * 40 + skc + 8] = v1;
        }
        __syncthreads();
        bf16x8 am[4], bn[4];
#pragma unroll
        for (int i = 0; i < 4; i++)
            am[i] = *(const bf16x8*)&Alds[(wm * 64 + i * 16 + l15) * 40 + lg * 8];
#pragma unroll
        for (int i = 0; i < 4; i++)
            bn[i] = *(const bf16x8*)&Blds[(wn * 64 + i * 16 + l15) * 40 + lg * 8];
#pragma unroll
        for (int i = 0; i < 4; i++)
#pragma unroll
            for (int j = 0; j < 4; j++)
                acc[i][j] = __builtin_amdgcn_mfma_f32_16x16x32_bf16(am[i], bn[j], acc[i][j], 0, 0, 0);
        __syncthreads();
    }

    const float* biasp = bias + (long)e * sBiasE;
#pragma unroll
    for (int i = 0; i < 4; i++) {
        int mgb = m0 + wm * 64 + i * 16 + lg * 4;
#pragma unroll
        for (int j = 0; j < 4; j++) {
            int ng = n0 + wn * 64 + j * 16 + l15;
            if (ng < Nwr) {
                float bval = (ng < N) ? biasp[ng] : 0.f;
#pragma unroll
                for (int r = 0; r < 4; r++) {
                    int mg = mgb + r;
                    if (mg < M) {
                        float val = acc[i][j][r] + bval;
                        if (EPI == 1) val = (val >= 0.f) ? val : 0.01f * val;
                        if (ng >= N) val = 0.f;
                        long cidx = (long)e * sCe + (long)mg * ldc + ng;
                        if (C_BF16) ((bf16_t*)Cv)[cidx] = (bf16_t)val;
                        else        ((float*)Cv)[cidx] = val;
                    }
                }
            }
        }
    }
}

// ---------------------------------------------------------------------------
// Split-precision flash attention (block-causal analytic; Q pre-scaled 1/8).
// Q,K,V,P all represented hi+lo bf16; 3 MFMAs per logical product.
// grid = (32 qblocks, 16 heads, 2 batch); 256 thr = 4 waves x 16 queries.
// ---------------------------------------------------------------------------
__global__ __launch_bounds__(256) void attn_split(const bf16_t* __restrict__ qh,
                                                  const bf16_t* __restrict__ ql,
                                                  float* __restrict__ o)
{
    __shared__ __align__(16) bf16_t Kh[64 * 72], Kl[64 * 72];
    __shared__ __align__(16) bf16_t Vh[64 * 72], Vl[64 * 72];   // transposed [d][key]
    __shared__ __align__(16) bf16_t Ph[4][16 * 72], Pl[4][16 * 72];
    const int qb = blockIdx.x, h = blockIdx.y, b = blockIdx.z;
    const int t = threadIdx.x, wid = t >> 6, lane = t & 63, l15 = lane & 15, lg = lane >> 4;

    const int qrow = qb * 64 + wid * 16 + l15;
    const long qoff = (long)(b * NSEQ + qrow) * 3072 + h * 64 + lg * 8;
    bf16x8 qh0 = *(const bf16x8*)(qh + qoff);
    bf16x8 qh1 = *(const bf16x8*)(qh + qoff + 32);
    bf16x8 ql0 = *(const bf16x8*)(ql + qoff);
    bf16x8 ql1 = *(const bf16x8*)(ql + qoff + 32);

    const f32x4 zf = {0.f, 0.f, 0.f, 0.f};
    f32x4 Oac[4];
    float m_run[4], l_run[4];
#pragma unroll
    for (int r = 0; r < 4; r++) { Oac[r] = zf; m_run[r] = -1e30f; l_run[r] = 0.f; }

    const int srow = t >> 2, sc0 = (t & 3) * 16;
    const long koff0 = (long)(b * NSEQ + srow) * 3072 + 1024 + h * 64 + sc0;
    for (int kb = 0; kb <= qb; kb++) {
        __syncthreads();
        const long koff = koff0 + (long)kb * 64 * 3072;
        {   // K rows
            bf16x8 a0 = *(const bf16x8*)(qh + koff);
            bf16x8 a1 = *(const bf16x8*)(qh + koff + 8);
            bf16x8 b0 = *(const bf16x8*)(ql + koff);
            bf16x8 b1 = *(const bf16x8*)(ql + koff + 8);
            *(bf16x8*)&Kh[srow * 72 + sc0] = a0;
            *(bf16x8*)&Kh[srow * 72 + sc0 + 8] = a1;
            *(bf16x8*)&Kl[srow * 72 + sc0] = b0;
            *(bf16x8*)&Kl[srow * 72 + sc0 + 8] = b1;
        }
        {   // V transposed
            bf16x8 a0 = *(const bf16x8*)(qh + koff + 1024);
            bf16x8 a1 = *(const bf16x8*)(qh + koff + 1032);
            bf16x8 b0 = *(const bf16x8*)(ql + koff + 1024);
            bf16x8 b1 = *(const bf16x8*)(ql + koff + 1032);
#pragma unroll
            for (int i = 0; i < 8; i++) {
                Vh[(sc0 + i) * 72 + srow]     = a0[i];
                Vh[(sc0 + 8 + i) * 72 + srow] = a1[i];
                Vl[(sc0 + i) * 72 + srow]     = b0[i];
                Vl[(sc0 + 8 + i) * 72 + srow] = b1[i];
            }
        }
        __syncthreads();
        // S = Q K^T
        f32x4 s[4];
#pragma unroll
        for (int ks = 0; ks < 4; ks++) {
            s[ks] = zf;
            int base = (ks * 16 + l15) * 72 + lg * 8;
            bf16x8 kh0 = *(const bf16x8*)&Kh[base];
            bf16x8 kh1 = *(const bf16x8*)&Kh[base + 32];
            bf16x8 kl0 = *(const bf16x8*)&Kl[base];
            bf16x8 kl1 = *(const bf16x8*)&Kl[base + 32];
            s[ks] = __builtin_amdgcn_mfma_f32_16x16x32_bf16(qh0, kh0, s[ks], 0, 0, 0);
            s[ks] = __builtin_amdgcn_mfma_f32_16x16x32_bf16(qh1, kh1, s[ks], 0, 0, 0);
            s[ks] = __builtin_amdgcn_mfma_f32_16x16x32_bf16(qh0, kl0, s[ks], 0, 0, 0);
            s[ks] = __builtin_amdgcn_mfma_f32_16x16x32_bf16(qh1, kl1, s[ks], 0, 0, 0);
            s[ks] = __builtin_amdgcn_mfma_f32_16x16x32_bf16(ql0, kh0, s[ks], 0, 0, 0);
            s[ks] = __builtin_amdgcn_mfma_f32_16x16x32_bf16(ql1, kh1, s[ks], 0, 0, 0);
        }
        // online softmax (row r lives across the 16 lanes sharing lg)
        float alpha[4];
#pragma unroll
        for (int r = 0; r < 4; r++) {
            float mt = fmaxf(fmaxf(s[0][r], s[1][r]), fmaxf(s[2][r], s[3][r]));
#pragma unroll
            for (int m = 1; m < 16; m <<= 1) mt = fmaxf(mt, __shfl_xor(mt, m));
            float mn = fmaxf(m_run[r], mt);
            alpha[r] = __expf(m_run[r] - mn);
            m_run[r] = mn;
        }
        float ladd[4] = {0.f, 0.f, 0.f, 0.f};
#pragma unroll
        for (int ks = 0; ks < 4; ks++)
#pragma unroll
            for (int r = 0; r < 4; r++) {
                float p = __expf(s[ks][r] - m_run[r]);
                s[ks][r] = p;
                ladd[r] += p;
            }
#pragma unroll
        for (int r = 0; r < 4; r++) {
#pragma unroll
            for (int m = 1; m < 16; m <<= 1) ladd[r] += __shfl_xor(ladd[r], m);
            l_run[r] = l_run[r] * alpha[r] + ladd[r];
        }
#pragma unroll
        for (int sb = 0; sb < 4; sb++)
#pragma unroll
            for (int r = 0; r < 4; r++) Oac[sb][r] *= alpha[r];
        // P -> LDS, split
        bf16_t* pwh = &Ph[wid][0];
        bf16_t* pwl = &Pl[wid][0];
#pragma unroll
        for (int ks = 0; ks < 4; ks++)
#pragma unroll
            for (int r = 0; r < 4; r++) {
                hl_t pv = split1(s[ks][r]);
                pwh[(lg * 4 + r) * 72 + ks * 16 + l15] = pv.h;
                pwl[(lg * 4 + r) * 72 + ks * 16 + l15] = pv.l;
            }
        __syncthreads();
        // O += P V
#pragma unroll
        for (int kst = 0; kst < 2; kst++) {
            bf16x8 pfh = *(const bf16x8*)&pwh[l15 * 72 + kst * 32 + lg * 8];
            bf16x8 pfl = *(const bf16x8*)&pwl[l15 * 72 + kst * 32 + lg * 8];
#pragma unroll
            for (int sb = 0; sb < 4; sb++) {
                int base = (sb * 16 + l15) * 72 + kst * 32 + lg * 8;
                bf16x8 vfh = *(const bf16x8*)&Vh[base];
                bf16x8 vfl = *(const bf16x8*)&Vl[base];
                Oac[sb] = __builtin_amdgcn_mfma_f32_16x16x32_bf16(pfh, vfh, Oac[sb], 0, 0, 0);
                Oac[sb] = __builtin_amdgcn_mfma_f32_16x16x32_bf16(pfh, vfl, Oac[sb], 0, 0, 0);
                Oac[sb] = __builtin_amdgcn_mfma_f32_16x16x32_bf16(pfl, vfh, Oac[sb], 0, 0, 0);
            }
        }
    }
#pragma unroll
    for (int sb = 0; sb < 4; sb++)
#pragma unroll
        for (int r = 0; r < 4; r++) {
            int qg = qb * 64 + wid * 16 + lg * 4 + r;
            o[(long)(b * NSEQ + qg) * 1024 + h * 64 + sb * 16 + l15] = Oac[sb][r] / l_run[r];
        }
}

// ---------------------------------------------------------------------------
__global__ __launch_bounds__(256) void rmsnorm_kernel(const float* __restrict__ y,
                                                      const float* __restrict__ gamma,
                                                      float* __restrict__ moe)
{
    long base = (long)blockIdx.x * 1024;
    float4 v = ((const float4*)(y + base))[threadIdx.x];
    float ss = v.x * v.x + v.y * v.y + v.z * v.z + v.w * v.w;
#pragma unroll
    for (int m = 32; m; m >>= 1) ss += __shfl_xor(ss, m);
    __shared__ float ls[4];
    if ((threadIdx.x & 63) == 0) ls[threadIdx.x >> 6] = ss;
    __syncthreads();
    float tot = ls[0] + ls[1] + ls[2] + ls[3];
    float sc = 32.0f / fmaxf(sqrtf(tot), 1e-12f);
    float4 g = ((const float4*)gamma)[threadIdx.x];
    float4 ov;
    ov.x = v.x * sc * g.x; ov.y = v.y * sc * g.y; ov.z = v.z * sc * g.z; ov.w = v.w * sc * g.w;
    ((float4*)(moe + base))[threadIdx.x] = ov;
}

// ---------------------------------------------------------------------------
// Gating. Top-2 selected on raw f32 logits (tie -> lower index, like top_k).
// g0n/g1n via exact logistic form. tokpack: e0 | e1<<4 | sr1<<8.
// acc: [0..31]=proxy, [32..63]=dens1 count, [64]=z.
// ---------------------------------------------------------------------------
__global__ __launch_bounds__(256) void gating_kernel(
    const float* __restrict__ moe, const float* __restrict__ gw,
    const float* __restrict__ runif, uint32* __restrict__ tokpack,
    float* __restrict__ tokg, float* __restrict__ acc)
{
    const int wid = threadIdx.x >> 6, lane = threadIdx.x & 63;
    const int tk = blockIdx.x * 4 + wid;
    const int b = tk >> 11, n = tk & 2047;
    float xv[16];
    const float4* xr4 = (const float4*)(moe + (long)tk * 1024 + lane * 16);
#pragma unroll
    for (int i = 0; i < 4; i++) {
        float4 v = xr4[i];
        xv[4 * i] = v.x; xv[4 * i + 1] = v.y; xv[4 * i + 2] = v.z; xv[4 * i + 3] = v.w;
    }
    float logit[16];
#pragma unroll
    for (int e = 0; e < 16; e++) {
        const float4* wr4 = (const float4*)(gw + e * 1024 + lane * 16);
        float p = 0.f;
#pragma unroll
        for (int i = 0; i < 4; i++) {
            float4 w = wr4[i];
            p = fmaf(xv[4 * i], w.x, p);     p = fmaf(xv[4 * i + 1], w.y, p);
            p = fmaf(xv[4 * i + 2], w.z, p); p = fmaf(xv[4 * i + 3], w.w, p);
        }
#pragma unroll
        for (int m = 1; m < 64; m <<= 1) p += __shfl_xor(p, m);
        logit[e] = p;
    }
    int e0 = 0; float t0 = logit[0];
#pragma unroll
    for (int e = 1; e < 16; e++) if (logit[e] > t0) { t0 = logit[e]; e0 = e; }
    int e1 = (e0 == 0) ? 1 : 0; float t1 = logit[e1];
#pragma unroll
    for (int e = 0; e < 16; e++) if (e != e0 && logit[e] > t1) { t1 = logit[e]; e1 = e; }
    float g0n = 1.f / (1.f + __expf(t1 - t0));
    float g1n = 1.f / (1.f + __expf(t0 - t1));
    int sr1 = (runif[(long)(BSZ + b) * NSEQ + n] < g1n / 0.2f) ? 1 : 0;
    // aux values (value-precision)
    float mx = t0, sum = 0.f, raw[16];
#pragma unroll
    for (int e = 0; e < 16; e++) { raw[e] = __expf(logit[e] - mx); sum += raw[e]; }
    float inv = 1.f / sum;
    float lse = mx + __logf(sum);
    if (lane == 0) {
        tokpack[tk] = (uint32)e0 | ((uint32)e1 << 4) | ((uint32)sr1 << 8);
        tokg[2 * tk] = g0n; tokg[2 * tk + 1] = g1n;
        atomicAdd(&acc[32 + b * 16 + e0], 1.0f);
        atomicAdd(&acc[64], lse * lse);
    }
    if (lane < 16) atomicAdd(&acc[b * 16 + lane], raw[lane] * inv);
}

// ---------------------------------------------------------------------------
__global__ void scan_kernel(const uint32* __restrict__ tokpack,
                            uint32* __restrict__ r0, uint32* __restrict__ r1,
                            int* __restrict__ prev)
{
    int t = threadIdx.x;
    if (t >= 64) return;
    int rank = t >> 5, be = t & 31, b = be >> 4, e = be & 15;
    const uint4* tp = (const uint4*)(tokpack + b * NSEQ);
    uint32* rr = (rank ? r1 : r0) + b * NSEQ;
    int cnt = 0;
    for (int n4 = 0; n4 < NSEQ / 4; n4++) {
        uint4 pk = tp[n4];
        uint32 vals[4] = {pk.x, pk.y, pk.z, pk.w};
#pragma unroll
        for (int i = 0; i < 4; i++) {
            uint32 p = vals[i];
            int n = n4 * 4 + i;
            if (rank == 0) {
                if ((int)(p & 15) == e) {
                    int kept = (cnt < CAPC) ? 1 : 0;
                    rr[n] = (uint32)e | ((uint32)kept << 4) | ((uint32)cnt << 5);
                    cnt++;
                }
            } else {
                if ((int)((p >> 4) & 15) == e) {
                    int sr1 = (p >> 8) & 1;
                    rr[n] = (uint32)e | ((uint32)sr1 << 4) | ((uint32)cnt << 5);
                    cnt += sr1;
                }
            }
        }
    }
    if (rank == 0) prev[be] = (cnt < CAPC) ? cnt : CAPC;
}

// ---------------------------------------------------------------------------
__global__ __launch_bounds__(256) void gather_kernel(
    const float* __restrict__ moe, const uint32* __restrict__ r0,
    const uint32* __restrict__ r1, const int* __restrict__ prev,
    float* __restrict__ ein)
{
    int tk = blockIdx.x, b = tk >> 11;
    float4 v = ((const float4*)(moe + (long)tk * 1024))[threadIdx.x];
    uint32 a = r0[tk];
    if ((a >> 4) & 1) {
        long row = ((long)(a & 15) * 2 + b) * CAPC + (int)(a >> 5);
        ((float4*)(ein + row * 1024))[threadIdx.x] = v;
    }
    uint32 c = r1[tk];
    {
        int e = c & 15, sr1 = (c >> 4) & 1;
        int slot = (int)(c >> 5) + prev[b * 16 + e];
        if (sr1 && slot < CAPC) {
            long row = ((long)e * 2 + b) * CAPC + slot;
            ((float4*)(ein + row * 1024))[threadIdx.x] = v;
        }
    }
}

// ---------------------------------------------------------------------------
__global__ __launch_bounds__(256) void expert_ln_kernel(
    const float* __restrict__ ein, const float* __restrict__ g,
    const float* __restrict__ bb, bf16_t* __restrict__ eout)
{
    int row = blockIdx.x, e = row / (BSZ * CAPC);
    long base = (long)row * 1024;
    float4 v = ((const float4*)(ein + base))[threadIdx.x];
    float s = v.x + v.y + v.z + v.w;
    float ss = v.x * v.x + v.y * v.y + v.z * v.z + v.w * v.w;
#pragma unroll
    for (int m = 32; m; m >>= 1) { s += __shfl_xor(s, m); ss += __shfl_xor(ss, m); }
    __shared__ float l1[4], l2[4];
    if ((threadIdx.x & 63) == 0) { l1[threadIdx.x >> 6] = s; l2[threadIdx.x >> 6] = ss; }
    __syncthreads();
    float st = l1[0] + l1[1] + l1[2] + l1[3];
    float sst = l2[0] + l2[1] + l2[2] + l2[3];
    float mu = st * (1.f / 1024.f);
    float var = sst * (1.f / 1024.f) - mu * mu;
    float rstd = rsqrtf(var + 1e-5f);
    int d = threadIdx.x * 4;
    float4 gg = *(const float4*)(g + e * 1024 + d);
    float4 bv = *(const float4*)(bb + e * 1024 + d);
    bf16x4 ov;
    ov[0] = (bf16_t)((v.x - mu) * rstd * gg.x + bv.x);
    ov[1] = (bf16_t)((v.y - mu) * rstd * gg.y + bv.y);
    ov[2] = (bf16_t)((v.z - mu) * rstd * gg.z + bv.z);
    ov[3] = (bf16_t)((v.w - mu) * rstd * gg.w + bv.w);
    *(bf16x4*)(eout + base + d) = ov;
}

// ---------------------------------------------------------------------------
__global__ __launch_bounds__(256) void combine_kernel(
    const float* __restrict__ y, const float* __restrict__ eout,
    const uint32* __restrict__ r0, const uint32* __restrict__ r1,
    const float* __restrict__ tokg, const int* __restrict__ prev,
    float* __restrict__ out)
{
    int tk = blockIdx.x, b = tk >> 11;
    uint32 a = r0[tk], c = r1[tk];
    int k0f = (a >> 4) & 1;
    float w0 = k0f ? tokg[2 * tk] : 0.f;
    long row0 = ((long)(a & 15) * 2 + b) * CAPC + (int)(a >> 5);
    int e1 = c & 15;
    int slot1 = (int)(c >> 5) + prev[b * 16 + e1];
    int k1f = (((c >> 4) & 1) && slot1 < CAPC) ? 1 : 0;
    float w1 = k1f ? tokg[2 * tk + 1] : 0.f;
    long row1 = ((long)e1 * 2 + b) * CAPC + slot1;
    int i = threadIdx.x;
    float4 vy = ((const float4*)(y + (long)tk * 1024))[i];
    float4 a0 = {0.f, 0.f, 0.f, 0.f}, a1 = {0.f, 0.f, 0.f, 0.f};
    if (k0f) a0 = ((const float4*)(eout + row0 * 1024))[i];
    if (k1f) a1 = ((const float4*)(eout + row1 * 1024))[i];
    float4 ov;
    ov.x = vy.x + w0 * a0.x + w1 * a1.x;
    ov.y = vy.y + w0 * a0.y + w1 * a1.y;
    ov.z = vy.z + w0 * a0.z + w1 * a1.z;
    ov.w = vy.w + w0 * a0.w + w1 * a1.w;
    ((float4*)(out + (long)tk * 1024))[i] = ov;
}

__global__ void zero_acc_kernel(float* acc)
{
    if (threadIdx.x < 65) acc[threadIdx.x] = 0.f;
}

__global__ void finalize_kernel(const float* __restrict__ acc, float* __restrict__ tail)
{
    int t = threadIdx.x;
    float v = (t < 32) ? acc[t] * acc[32 + t] : 0.f;
#pragma unroll
    for (int m = 1; m < 64; m <<= 1) v += __shfl_xor(v, m);
    if (t == 0) {
        float bal = v * (8.0f / (2048.f * 2048.f));
        float z = acc[64] / 4096.f;
        tail[0] = 0.01f * bal + 0.001f * z;
        tail[1] = bal;
        tail[2] = z;
    }
}

// ---------------------------------------------------------------------------
extern "C" void kernel_launch(void* const* d_in, const int* in_sizes, int n_in,
                              void* d_out, int out_size, void* d_ws, size_t ws_size,
                              hipStream_t stream)
{
    (void)in_sizes; (void)n_in; (void)out_size; (void)ws_size;
    const float* x     = (const float*)d_in[0];
    // d_in[1] = attn_mask: block-causal, computed analytically; never read.
    const float* in_w  = (const float*)d_in[2];
    const float* in_b  = (const float*)d_in[3];
    const float* out_w = (const float*)d_in[4];
    const float* out_b = (const float*)d_in[5];
    const float* rg    = (const float*)d_in[6];
    const float* gw    = (const float*)d_in[7];
    const float* lng   = (const float*)d_in[8];
    const float* lnb   = (const float*)d_in[9];
    const float* w1    = (const float*)d_in[10];
    const float* b1    = (const float*)d_in[11];
    const float* w2    = (const float*)d_in[12];
    const float* b2    = (const float*)d_in[13];
    const float* runif = (const float*)d_in[14];
    float* out = (float*)d_out;

    size_t off = 0;
    char* wsb = (char*)d_ws;
    auto take = [&](size_t bytes) -> char* {
        char* p = wsb + off;
        off += (bytes + 255) & ~(size_t)255;
        return p;
    };
    bf16_t* qkvh = (bf16_t*)take((size_t)NTOK * 3072 * 2);   // 25.2 MB
    bf16_t* qkvl = (bf16_t*)take((size_t)NTOK * 3072 * 2);   // 25.2 MB
    float*  obuf = (float*)take((size_t)NTOK * 1024 * 4);
    float*  ybuf = (float*)take((size_t)NTOK * 1024 * 4);
    float*  moe  = (float*)take((size_t)NTOK * 1024 * 4);
    bf16_t* eln  = (bf16_t*)take((size_t)NEXP * BSZ * CAPC * 1024 * 2);
    bf16_t* hbuf = (bf16_t*)take((size_t)NEXP * BSZ * CAPC * HFF_P * 2);
    uint32* tokpack = (uint32*)take(NTOK * 4);
    float*  tokg = (float*)take(NTOK * 8);
    uint32* r0   = (uint32*)take(NTOK * 4);
    uint32* r1   = (uint32*)take(NTOK * 4);
    int*    prev = (int*)take(128);
    float*  acc  = (float*)take(1024);
    // aliases: qkv hi/lo are dead after attention
    float*  ein  = (float*)qkvl;   // 21.0 MB <= 25.2
    float*  eoutv = (float*)qkvh;  // 21.0 MB <= 25.2

    zero_acc_kernel<<<1, 128, 0, stream>>>(acc);

    // QKV = x @ in_proj_w^T + b  (split precision); Q cols pre-scaled 1/8
    gemm_split<0, 1><<<dim3(24, 32), 256, 0, stream>>>(
        x, in_w, in_b, nullptr, qkvh, qkvl, nullptr,
        NTOK, 3072, 1024, 1024, 0.125f);

    attn_split<<<dim3(32, 16, 2), 256, 0, stream>>>(qkvh, qkvl, obuf);

    // y = o @ out_proj_w^T + b + x  (split precision, f32 out)
    gemm_split<2, 0><<<dim3(8, 32), 256, 0, stream>>>(
        obuf, out_w, out_b, x, nullptr, nullptr, ybuf,
        NTOK, 1024, 1024, 0, 1.0f);

    rmsnorm_kernel<<<NTOK, 256, 0, stream>>>(ybuf, rg, moe);
    gating_kernel<<<NTOK / 4, 256, 0, stream>>>(moe, gw, runif, tokpack, tokg, acc);
    scan_kernel<<<1, 64, 0, stream>>>(tokpack, r0, r1, prev);
    gather_kernel<<<NTOK, 256, 0, stream>>>(moe, r0, r1, prev, ein);
    expert_ln_kernel<<<NEXP * BSZ * CAPC, 256, 0, stream>>>(ein, lng, lnb, eln);

    // h = LeakyReLU(LN @ w1^T + b1) -> bf16, padded cols [2730,2752) zeroed
    gemm_nt<1, 1><<<dim3(22, 3, 16), 256, 0, stream>>>(
        eln, w1, b1, hbuf, 320, HFF_R, HFF_P, 1024, 1024,
        (long)320 * 1024, (long)HFF_R * 1024, HFF_R, (long)320 * HFF_P, HFF_P);

    // expert_out = h @ w2^T + b2 -> f32
    gemm_nt<0, 0><<<dim3(8, 3, 16), 256, 0, stream>>>(
        hbuf, w2, b2, eoutv, 320, 1024, 1024, HFF_P, HFF_R,
        (long)320 * HFF_P, (long)1024 * HFF_R, 1024, (long)320 * 1024, 1024);

    combine_kernel<<<NTOK, 256, 0, stream>>>(ybuf, eoutv, r0, r1, tokg, prev, out);
    finalize_kernel<<<1, 64, 0, stream>>>(acc, out + (size_t)NTOK * 1024);
}

// Round 4
// 848.633 us; speedup vs baseline: 1.6977x; 1.6977x over previous
//
#include <hip/hip_runtime.h>
#include <hip/hip_bf16.h>
#include <cstdint>

#define NSEQ  2048
#define BSZ   2
#define NTOK  4096          // B*N
#define EDIM  1024
#define NEXP  16
#define CAPC  160
#define HFF_R 2730
#define HFF_P 2752          // padded to multiple of 64

typedef __bf16 bf16_t;
typedef __bf16 bf16x8 __attribute__((ext_vector_type(8)));
typedef __bf16 bf16x4 __attribute__((ext_vector_type(4)));
typedef float  f32x4  __attribute__((ext_vector_type(4)));
typedef unsigned int uint32;

__device__ inline bf16x8 zero8() {
    bf16x8 v;
#pragma unroll
    for (int i = 0; i < 8; i++) v[i] = (bf16_t)0.f;
    return v;
}
__device__ inline bf16x8 pack8(float4 a, float4 b) {
    bf16x8 v;
    v[0]=(bf16_t)a.x; v[1]=(bf16_t)a.y; v[2]=(bf16_t)a.z; v[3]=(bf16_t)a.w;
    v[4]=(bf16_t)b.x; v[5]=(bf16_t)b.y; v[6]=(bf16_t)b.z; v[7]=(bf16_t)b.w;
    return v;
}
struct hl_t { bf16_t h, l; };
__device__ inline hl_t split1(float f) {
    hl_t r;
    r.h = (bf16_t)f;
    r.l = (bf16_t)(f - (float)r.h);
    return r;
}

// ---------------------------------------------------------------------------
// Split-precision NT GEMM: C[M,N] = epi(A * B^T + bias), A,B f32.
// Each operand split a = hi + lo (bf16); products hi*hi + hi*lo + lo*hi give
// ~2^-18 relative error (f32-class). BM=BN=128, BK=32, 4 waves 2x2.
// EPI: 0 = bias (+ optional col-scale); 2 = bias + residual.
// C_SPLIT: 1 -> write bf16 hi/lo pair buffers; 0 -> write f32.
// M, N multiples of 128; K multiple of 32 (no guards).
// ---------------------------------------------------------------------------
template <int EPI, int C_SPLIT>
__global__ __launch_bounds__(256) void gemm_split(
    const float* __restrict__ A, const float* __restrict__ Bw,
    const float* __restrict__ bias, const float* __restrict__ resid,
    bf16_t* __restrict__ Chi, bf16_t* __restrict__ Clo, float* __restrict__ Cf,
    int M, int N, int K, int scale_cut, float scale_val)
{
    __shared__ __align__(16) bf16_t Ah[128 * 40], Al[128 * 40];
    __shared__ __align__(16) bf16_t Bh[128 * 40], Bl[128 * 40];
    const int t = threadIdx.x;
    const int m0 = blockIdx.y * 128, n0 = blockIdx.x * 128;
    const int lane = t & 63, l15 = lane & 15, lg = lane >> 4;
    const int wid = t >> 6, wm = wid >> 1, wn = wid & 1;
    const int srow = t >> 1, skc = (t & 1) * 16;

    f32x4 acc[4][4];
    const f32x4 zf = {0.f, 0.f, 0.f, 0.f};
#pragma unroll
    for (int i = 0; i < 4; i++)
#pragma unroll
        for (int j = 0; j < 4; j++) acc[i][j] = zf;

    for (int k0 = 0; k0 < K; k0 += 32) {
        {
            float av[16];
            const float* ap = A + (long)(m0 + srow) * K + k0 + skc;
            *(float4*)&av[0]  = *(const float4*)ap;
            *(float4*)&av[4]  = *(const float4*)(ap + 4);
            *(float4*)&av[8]  = *(const float4*)(ap + 8);
            *(float4*)&av[12] = *(const float4*)(ap + 12);
            bf16x8 h0, h1, l0, l1;
#pragma unroll
            for (int i = 0; i < 8; i++) {
                hl_t a = split1(av[i]);      h0[i] = a.h; l0[i] = a.l;
                hl_t b = split1(av[8 + i]);  h1[i] = b.h; l1[i] = b.l;
            }
            *(bf16x8*)&Ah[srow * 40 + skc] = h0; *(bf16x8*)&Ah[srow * 40 + skc + 8] = h1;
            *(bf16x8*)&Al[srow * 40 + skc] = l0; *(bf16x8*)&Al[srow * 40 + skc + 8] = l1;
        }
        {
            float bv[16];
            const float* bp = Bw + (long)(n0 + srow) * K + k0 + skc;
            *(float4*)&bv[0]  = *(const float4*)bp;
            *(float4*)&bv[4]  = *(const float4*)(bp + 4);
            *(float4*)&bv[8]  = *(const float4*)(bp + 8);
            *(float4*)&bv[12] = *(const float4*)(bp + 12);
            bf16x8 h0, h1, l0, l1;
#pragma unroll
            for (int i = 0; i < 8; i++) {
                hl_t a = split1(bv[i]);      h0[i] = a.h; l0[i] = a.l;
                hl_t b = split1(bv[8 + i]);  h1[i] = b.h; l1[i] = b.l;
            }
            *(bf16x8*)&Bh[srow * 40 + skc] = h0; *(bf16x8*)&Bh[srow * 40 + skc + 8] = h1;
            *(bf16x8*)&Bl[srow * 40 + skc] = l0; *(bf16x8*)&Bl[srow * 40 + skc + 8] = l1;
        }
        __syncthreads();
        bf16x8 amh[4], aml[4], bnh[4], bnl[4];
#pragma unroll
        for (int i = 0; i < 4; i++) {
            int base = (wm * 64 + i * 16 + l15) * 40 + lg * 8;
            amh[i] = *(const bf16x8*)&Ah[base];
            aml[i] = *(const bf16x8*)&Al[base];
        }
#pragma unroll
        for (int j = 0; j < 4; j++) {
            int base = (wn * 64 + j * 16 + l15) * 40 + lg * 8;
            bnh[j] = *(const bf16x8*)&Bh[base];
            bnl[j] = *(const bf16x8*)&Bl[base];
        }
#pragma unroll
        for (int i = 0; i < 4; i++)
#pragma unroll
            for (int j = 0; j < 4; j++) {
                acc[i][j] = __builtin_amdgcn_mfma_f32_16x16x32_bf16(amh[i], bnh[j], acc[i][j], 0, 0, 0);
                acc[i][j] = __builtin_amdgcn_mfma_f32_16x16x32_bf16(amh[i], bnl[j], acc[i][j], 0, 0, 0);
                acc[i][j] = __builtin_amdgcn_mfma_f32_16x16x32_bf16(aml[i], bnh[j], acc[i][j], 0, 0, 0);
            }
        __syncthreads();
    }

#pragma unroll
    for (int i = 0; i < 4; i++) {
        int mgb = m0 + wm * 64 + i * 16 + lg * 4;
#pragma unroll
        for (int j = 0; j < 4; j++) {
            int ng = n0 + wn * 64 + j * 16 + l15;
            float bval = bias[ng];
#pragma unroll
            for (int r = 0; r < 4; r++) {
                int mg = mgb + r;
                float val = acc[i][j][r] + bval;
                if (scale_cut > 0 && ng < scale_cut) val *= scale_val;
                if (EPI == 2) val += resid[(long)mg * N + ng];
                long idx = (long)mg * N + ng;
                if (C_SPLIT) {
                    bf16_t hi = (bf16_t)val;
                    Chi[idx] = hi;
                    Clo[idx] = (bf16_t)(val - (float)hi);
                } else {
                    Cf[idx] = val;
                }
            }
        }
    }
}

// ---------------------------------------------------------------------------
// bf16 NT GEMM (expert FFN path, value-precision only).
// A: bf16 row-major; B: f32 row-major. EPI: 0 bias, 1 bias+LeakyReLU.
// Writes cols [0,Nwr); value forced 0 for cols in [N,Nwr).
// ---------------------------------------------------------------------------
template <int EPI, int C_BF16>
__global__ __launch_bounds__(256) void gemm_nt(
    const bf16_t* __restrict__ Av, const float* __restrict__ Bw,
    const float* __restrict__ bias, void* __restrict__ Cv,
    int M, int N, int Nwr, int KA, int KB,
    long sAe, long sBe, long sBiasE, long sCe, int ldc)
{
    __shared__ __align__(16) bf16_t Alds[128 * 40];
    __shared__ __align__(16) bf16_t Blds[128 * 40];
    const int t = threadIdx.x;
    const int e = blockIdx.z;
    const int m0 = blockIdx.y * 128, n0 = blockIdx.x * 128;
    const int lane = t & 63, l15 = lane & 15, lg = lane >> 4;
    const int wid = t >> 6, wm = wid >> 1, wn = wid & 1;
    const int srow = t >> 1, skc = (t & 1) * 16;

    f32x4 acc[4][4];
    const f32x4 zf = {0.f, 0.f, 0.f, 0.f};
#pragma unroll
    for (int i = 0; i < 4; i++)
#pragma unroll
        for (int j = 0; j < 4; j++) acc[i][j] = zf;

    for (int k0 = 0; k0 < KA; k0 += 32) {
        {
            int mg = m0 + srow;
            bf16x8 v0 = zero8(), v1 = zero8();
            if (mg < M) {
                const bf16_t* ap = Av + (long)e * sAe + (long)mg * KA + k0 + skc;
                v0 = *(const bf16x8*)ap;
                v1 = *(const bf16x8*)(ap + 8);
            }
            *(bf16x8*)&Alds[srow * 40 + skc] = v0;
            *(bf16x8*)&Alds[srow * 40 + skc + 8] = v1;
        }
        {
            int ng = n0 + srow;
            bf16x8 v0 = zero8(), v1 = zero8();
            if (ng < N) {
                const float* bp = Bw + (long)e * sBe + (long)ng * KB + k0 + skc;
                if (k0 + 32 <= KB) {
                    float4 a = *(const float4*)bp, b = *(const float4*)(bp + 4);
                    float4 c = *(const float4*)(bp + 8), d = *(const float4*)(bp + 12);
                    v0 = pack8(a, b); v1 = pack8(c, d);
                } else {
#pragma unroll
                    for (int i = 0; i < 8; i++) {
                        int kk = k0 + skc + i;
                        v0[i] = (kk < KB) ? (bf16_t)bp[i] : (bf16_t)0.f;
                    }
#pragma unroll
                    for (int i = 0; i < 8; i++) {
                        int kk = k0 + skc + 8 + i;
                        v1[i] = (kk < KB) ? (bf16_t)bp[8 + i] : (bf16_t)0.f;
                    }
                }
            }
            *(bf16x8*)&Blds[srow * 40 + skc] = v0;
            *(bf16x8*)&Blds[srow * 40 + skc + 8] = v1;
        }
        __syncthreads();
        bf16x8 am[4], bn[4];
#pragma unroll
        for (int i = 0; i < 4; i++)
            am[i] = *(const bf16x8*)&Alds[(wm * 64 + i * 16 + l15) * 40 + lg * 8];
#pragma unroll
        for (int i = 0; i < 4; i++)
            bn[i] = *(const bf16x8*)&Blds[(wn * 64 + i * 16 + l15) * 40 + lg * 8];
#pragma unroll
        for (int i = 0; i < 4; i++)
#pragma unroll
            for (int j = 0; j < 4; j++)
                acc[i][j] = __builtin_amdgcn_mfma_f32_16x16x32_bf16(am[i], bn[j], acc[i][j], 0, 0, 0);
        __syncthreads();
    }

    const float* biasp = bias + (long)e * sBiasE;
#pragma unroll
    for (int i = 0; i < 4; i++) {
        int mgb = m0 + wm * 64 + i * 16 + lg * 4;
#pragma unroll
        for (int j = 0; j < 4; j++) {
            int ng = n0 + wn * 64 + j * 16 + l15;
            if (ng < Nwr) {
                float bval = (ng < N) ? biasp[ng] : 0.f;
#pragma unroll
                for (int r = 0; r < 4; r++) {
                    int mg = mgb + r;
                    if (mg < M) {
                        float val = acc[i][j][r] + bval;
                        if (EPI == 1) val = (val >= 0.f) ? val : 0.01f * val;
                        if (ng >= N) val = 0.f;
                        long cidx = (long)e * sCe + (long)mg * ldc + ng;
                        if (C_BF16) ((bf16_t*)Cv)[cidx] = (bf16_t)val;
                        else        ((float*)Cv)[cidx] = val;
                    }
                }
            }
        }
    }
}

// ---------------------------------------------------------------------------
// Split-precision flash attention (block-causal analytic; Q pre-scaled 1/8).
// ---------------------------------------------------------------------------
__global__ __launch_bounds__(256) void attn_split(const bf16_t* __restrict__ qh,
                                                  const bf16_t* __restrict__ ql,
                                                  float* __restrict__ o)
{
    __shared__ __align__(16) bf16_t Kh[64 * 72], Kl[64 * 72];
    __shared__ __align__(16) bf16_t Vh[64 * 72], Vl[64 * 72];   // transposed [d][key]
    __shared__ __align__(16) bf16_t Ph[4][16 * 72], Pl[4][16 * 72];
    const int qb = blockIdx.x, h = blockIdx.y, b = blockIdx.z;
    const int t = threadIdx.x, wid = t >> 6, lane = t & 63, l15 = lane & 15, lg = lane >> 4;

    const int qrow = qb * 64 + wid * 16 + l15;
    const long qoff = (long)(b * NSEQ + qrow) * 3072 + h * 64 + lg * 8;
    bf16x8 qh0 = *(const bf16x8*)(qh + qoff);
    bf16x8 qh1 = *(const bf16x8*)(qh + qoff + 32);
    bf16x8 ql0 = *(const bf16x8*)(ql + qoff);
    bf16x8 ql1 = *(const bf16x8*)(ql + qoff + 32);

    const f32x4 zf = {0.f, 0.f, 0.f, 0.f};
    f32x4 Oac[4];
    float m_run[4], l_run[4];
#pragma unroll
    for (int r = 0; r < 4; r++) { Oac[r] = zf; m_run[r] = -1e30f; l_run[r] = 0.f; }

    const int srow = t >> 2, sc0 = (t & 3) * 16;
    const long koff0 = (long)(b * NSEQ + srow) * 3072 + 1024 + h * 64 + sc0;
    for (int kb = 0; kb <= qb; kb++) {
        __syncthreads();
        const long koff = koff0 + (long)kb * 64 * 3072;
        {   // K rows
            bf16x8 a0 = *(const bf16x8*)(qh + koff);
            bf16x8 a1 = *(const bf16x8*)(qh + koff + 8);
            bf16x8 b0 = *(const bf16x8*)(ql + koff);
            bf16x8 b1 = *(const bf16x8*)(ql + koff + 8);
            *(bf16x8*)&Kh[srow * 72 + sc0] = a0;
            *(bf16x8*)&Kh[srow * 72 + sc0 + 8] = a1;
            *(bf16x8*)&Kl[srow * 72 + sc0] = b0;
            *(bf16x8*)&Kl[srow * 72 + sc0 + 8] = b1;
        }
        {   // V transposed
            bf16x8 a0 = *(const bf16x8*)(qh + koff + 1024);
            bf16x8 a1 = *(const bf16x8*)(qh + koff + 1032);
            bf16x8 b0 = *(const bf16x8*)(ql + koff + 1024);
            bf16x8 b1 = *(const bf16x8*)(ql + koff + 1032);
#pragma unroll
            for (int i = 0; i < 8; i++) {
                Vh[(sc0 + i) * 72 + srow]     = a0[i];
                Vh[(sc0 + 8 + i) * 72 + srow] = a1[i];
                Vl[(sc0 + i) * 72 + srow]     = b0[i];
                Vl[(sc0 + 8 + i) * 72 + srow] = b1[i];
            }
        }
        __syncthreads();
        // S = Q K^T
        f32x4 s[4];
#pragma unroll
        for (int ks = 0; ks < 4; ks++) {
            s[ks] = zf;
            int base = (ks * 16 + l15) * 72 + lg * 8;
            bf16x8 kh0 = *(const bf16x8*)&Kh[base];
            bf16x8 kh1 = *(const bf16x8*)&Kh[base + 32];
            bf16x8 kl0 = *(const bf16x8*)&Kl[base];
            bf16x8 kl1 = *(const bf16x8*)&Kl[base + 32];
            s[ks] = __builtin_amdgcn_mfma_f32_16x16x32_bf16(qh0, kh0, s[ks], 0, 0, 0);
            s[ks] = __builtin_amdgcn_mfma_f32_16x16x32_bf16(qh1, kh1, s[ks], 0, 0, 0);
            s[ks] = __builtin_amdgcn_mfma_f32_16x16x32_bf16(qh0, kl0, s[ks], 0, 0, 0);
            s[ks] = __builtin_amdgcn_mfma_f32_16x16x32_bf16(qh1, kl1, s[ks], 0, 0, 0);
            s[ks] = __builtin_amdgcn_mfma_f32_16x16x32_bf16(ql0, kh0, s[ks], 0, 0, 0);
            s[ks] = __builtin_amdgcn_mfma_f32_16x16x32_bf16(ql1, kh1, s[ks], 0, 0, 0);
        }
        // online softmax
        float alpha[4];
#pragma unroll
        for (int r = 0; r < 4; r++) {
            float mt = fmaxf(fmaxf(s[0][r], s[1][r]), fmaxf(s[2][r], s[3][r]));
#pragma unroll
            for (int m = 1; m < 16; m <<= 1) mt = fmaxf(mt, __shfl_xor(mt, m));
            float mn = fmaxf(m_run[r], mt);
            alpha[r] = __expf(m_run[r] - mn);
            m_run[r] = mn;
        }
        float ladd[4] = {0.f, 0.f, 0.f, 0.f};
#pragma unroll
        for (int ks = 0; ks < 4; ks++)
#pragma unroll
            for (int r = 0; r < 4; r++) {
                float p = __expf(s[ks][r] - m_run[r]);
                s[ks][r] = p;
                ladd[r] += p;
            }
#pragma unroll
        for (int r = 0; r < 4; r++) {
#pragma unroll
            for (int m = 1; m < 16; m <<= 1) ladd[r] += __shfl_xor(ladd[r], m);
            l_run[r] = l_run[r] * alpha[r] + ladd[r];
        }
#pragma unroll
        for (int sb = 0; sb < 4; sb++)
#pragma unroll
            for (int r = 0; r < 4; r++) Oac[sb][r] *= alpha[r];
        // P -> LDS, split
        bf16_t* pwh = &Ph[wid][0];
        bf16_t* pwl = &Pl[wid][0];
#pragma unroll
        for (int ks = 0; ks < 4; ks++)
#pragma unroll
            for (int r = 0; r < 4; r++) {
                hl_t pv = split1(s[ks][r]);
                pwh[(lg * 4 + r) * 72 + ks * 16 + l15] = pv.h;
                pwl[(lg * 4 + r) * 72 + ks * 16 + l15] = pv.l;
            }
        __syncthreads();
        // O += P V
#pragma unroll
        for (int kst = 0; kst < 2; kst++) {
            bf16x8 pfh = *(const bf16x8*)&pwh[l15 * 72 + kst * 32 + lg * 8];
            bf16x8 pfl = *(const bf16x8*)&pwl[l15 * 72 + kst * 32 + lg * 8];
#pragma unroll
            for (int sb = 0; sb < 4; sb++) {
                int base = (sb * 16 + l15) * 72 + kst * 32 + lg * 8;
                bf16x8 vfh = *(const bf16x8*)&Vh[base];
                bf16x8 vfl = *(const bf16x8*)&Vl[base];
                Oac[sb] = __builtin_amdgcn_mfma_f32_16x16x32_bf16(pfh, vfh, Oac[sb], 0, 0, 0);
                Oac[sb] = __builtin_amdgcn_mfma_f32_16x16x32_bf16(pfh, vfl, Oac[sb], 0, 0, 0);
                Oac[sb] = __builtin_amdgcn_mfma_f32_16x16x32_bf16(pfl, vfh, Oac[sb], 0, 0, 0);
            }
        }
    }
#pragma unroll
    for (int sb = 0; sb < 4; sb++)
#pragma unroll
        for (int r = 0; r < 4; r++) {
            int qg = qb * 64 + wid * 16 + lg * 4 + r;
            o[(long)(b * NSEQ + qg) * 1024 + h * 64 + sb * 16 + l15] = Oac[sb][r] / l_run[r];
        }
}

// ---------------------------------------------------------------------------
__global__ __launch_bounds__(256) void rmsnorm_kernel(const float* __restrict__ y,
                                                      const float* __restrict__ gamma,
                                                      float* __restrict__ moe)
{
    long base = (long)blockIdx.x * 1024;
    float4 v = ((const float4*)(y + base))[threadIdx.x];
    float ss = v.x * v.x + v.y * v.y + v.z * v.z + v.w * v.w;
#pragma unroll
    for (int m = 32; m; m >>= 1) ss += __shfl_xor(ss, m);
    __shared__ float ls[4];
    if ((threadIdx.x & 63) == 0) ls[threadIdx.x >> 6] = ss;
    __syncthreads();
    float tot = ls[0] + ls[1] + ls[2] + ls[3];
    float sc = 32.0f / fmaxf(sqrtf(tot), 1e-12f);
    float4 g = ((const float4*)gamma)[threadIdx.x];
    float4 ov;
    ov.x = v.x * sc * g.x; ov.y = v.y * sc * g.y; ov.z = v.z * sc * g.z; ov.w = v.w * sc * g.w;
    ((float4*)(moe + base))[threadIdx.x] = ov;
}

// ---------------------------------------------------------------------------
// Gating. Top-2 on raw f32 logits; exact logistic gates; aux accums.
// ---------------------------------------------------------------------------
__global__ __launch_bounds__(256) void gating_kernel(
    const float* __restrict__ moe, const float* __restrict__ gw,
    const float* __restrict__ runif, uint32* __restrict__ tokpack,
    float* __restrict__ tokg, float* __restrict__ acc)
{
    const int wid = threadIdx.x >> 6, lane = threadIdx.x & 63;
    const int tk = blockIdx.x * 4 + wid;
    const int b = tk >> 11, n = tk & 2047;
    float xv[16];
    const float4* xr4 = (const float4*)(moe + (long)tk * 1024 + lane * 16);
#pragma unroll
    for (int i = 0; i < 4; i++) {
        float4 v = xr4[i];
        xv[4 * i] = v.x; xv[4 * i + 1] = v.y; xv[4 * i + 2] = v.z; xv[4 * i + 3] = v.w;
    }
    float logit[16];
#pragma unroll
    for (int e = 0; e < 16; e++) {
        const float4* wr4 = (const float4*)(gw + e * 1024 + lane * 16);
        float p = 0.f;
#pragma unroll
        for (int i = 0; i < 4; i++) {
            float4 w = wr4[i];
            p = fmaf(xv[4 * i], w.x, p);     p = fmaf(xv[4 * i + 1], w.y, p);
            p = fmaf(xv[4 * i + 2], w.z, p); p = fmaf(xv[4 * i + 3], w.w, p);
        }
#pragma unroll
        for (int m = 1; m < 64; m <<= 1) p += __shfl_xor(p, m);
        logit[e] = p;
    }
    int e0 = 0; float t0 = logit[0];
#pragma unroll
    for (int e = 1; e < 16; e++) if (logit[e] > t0) { t0 = logit[e]; e0 = e; }
    int e1 = (e0 == 0) ? 1 : 0; float t1 = logit[e1];
#pragma unroll
    for (int e = 0; e < 16; e++) if (e != e0 && logit[e] > t1) { t1 = logit[e]; e1 = e; }
    float g0n = 1.f / (1.f + __expf(t1 - t0));
    float g1n = 1.f / (1.f + __expf(t0 - t1));
    int sr1 = (runif[(long)(BSZ + b) * NSEQ + n] < g1n / 0.2f) ? 1 : 0;
    float mx = t0, sum = 0.f, raw[16];
#pragma unroll
    for (int e = 0; e < 16; e++) { raw[e] = __expf(logit[e] - mx); sum += raw[e]; }
    float inv = 1.f / sum;
    float lse = mx + __logf(sum);
    if (lane == 0) {
        tokpack[tk] = (uint32)e0 | ((uint32)e1 << 4) | ((uint32)sr1 << 8);
        tokg[2 * tk] = g0n; tokg[2 * tk + 1] = g1n;
        atomicAdd(&acc[32 + b * 16 + e0], 1.0f);
        atomicAdd(&acc[64], lse * lse);
    }
    if (lane < 16) atomicAdd(&acc[b * 16 + lane], raw[lane] * inv);
}

// ---------------------------------------------------------------------------
// Parallel position scan. One block per batch, 512 threads x 4 tokens.
// Per-expert counts packed as 8 x u32 (16-bit fields, expert e in word e>>1,
// half (e&1)). Intra-wave Kogge-Stone via shfl_up; wave totals via LDS.
// All expert indexing via static select chains (no scratch spill).
// r0: e | kept<<4 | slot<<5 ; r1: e | sr1<<4 | localslot<<5.
// ---------------------------------------------------------------------------
__global__ __launch_bounds__(512) void scan_kernel(const uint32* __restrict__ tokpack,
                                                   uint32* __restrict__ r0,
                                                   uint32* __restrict__ r1,
                                                   int* __restrict__ prev)
{
    const int b = blockIdx.x, t = threadIdx.x;
    const int wv = t >> 6, lane = t & 63;
    uint32 toks[4];
    *(uint4*)toks = ((const uint4*)(tokpack + b * NSEQ))[t];

    uint32 c0[8], c1[8];
#pragma unroll
    for (int j = 0; j < 8; j++) { c0[j] = 0u; c1[j] = 0u; }
#pragma unroll
    for (int i = 0; i < 4; i++) {
        uint32 p = toks[i];
        uint32 e0 = p & 15, e1 = (p >> 4) & 15, sr1 = (p >> 8) & 1;
        uint32 inc0 = 1u << ((e0 & 1) * 16);
        uint32 inc1 = sr1 << ((e1 & 1) * 16);
#pragma unroll
        for (int j = 0; j < 8; j++) {
            c0[j] += ((e0 >> 1) == (uint32)j) ? inc0 : 0u;
            c1[j] += ((e1 >> 1) == (uint32)j) ? inc1 : 0u;
        }
    }
    // intra-wave inclusive scan
    uint32 i0[8], i1[8];
#pragma unroll
    for (int j = 0; j < 8; j++) { i0[j] = c0[j]; i1[j] = c1[j]; }
#pragma unroll
    for (int off = 1; off < 64; off <<= 1) {
#pragma unroll
        for (int j = 0; j < 8; j++) {
            uint32 u0 = __shfl_up(i0[j], off);
            uint32 u1 = __shfl_up(i1[j], off);
            if (lane >= off) { i0[j] += u0; i1[j] += u1; }
        }
    }
    __shared__ uint32 wsum0[8][8], wsum1[8][8];   // [wave][word]
    if (lane == 63) {
#pragma unroll
        for (int j = 0; j < 8; j++) { wsum0[wv][j] = i0[j]; wsum1[wv][j] = i1[j]; }
    }
    __syncthreads();
    uint32 b0[8], b1[8];
#pragma unroll
    for (int j = 0; j < 8; j++) {
        uint32 s0 = 0u, s1 = 0u;
#pragma unroll
        for (int w = 0; w < 8; w++) {
            s0 += (w < wv) ? wsum0[w][j] : 0u;
            s1 += (w < wv) ? wsum1[w][j] : 0u;
        }
        b0[j] = s0 + i0[j] - c0[j];   // exclusive base at this thread's first token
        b1[j] = s1 + i1[j] - c1[j];
    }
    if (t == 0) {
#pragma unroll
        for (int j = 0; j < 8; j++) {
            uint32 tot = 0u;
#pragma unroll
            for (int w = 0; w < 8; w++) tot += wsum0[w][j];
            int tlo = (int)(tot & 0xffffu), thi = (int)(tot >> 16);
            prev[b * 16 + 2 * j]     = tlo < CAPC ? tlo : CAPC;
            prev[b * 16 + 2 * j + 1] = thi < CAPC ? thi : CAPC;
        }
    }
    // emit entries for my 4 tokens
    uint32* rr0 = r0 + b * NSEQ + t * 4;
    uint32* rr1 = r1 + b * NSEQ + t * 4;
#pragma unroll
    for (int i = 0; i < 4; i++) {
        uint32 p = toks[i];
        uint32 e0 = p & 15, e1 = (p >> 4) & 15, sr1 = (p >> 8) & 1;
        uint32 sh0 = (e0 & 1) * 16, sh1 = (e1 & 1) * 16;
        uint32 w0 = 0u, w1 = 0u;
#pragma unroll
        for (int j = 0; j < 8; j++) {
            w0 += ((e0 >> 1) == (uint32)j) ? b0[j] : 0u;
            w1 += ((e1 >> 1) == (uint32)j) ? b1[j] : 0u;
        }
        uint32 s0 = (w0 >> sh0) & 0xffffu;
        uint32 s1v = (w1 >> sh1) & 0xffffu;
        uint32 kept = (s0 < CAPC) ? 1u : 0u;
        rr0[i] = e0 | (kept << 4) | (s0 << 5);
        rr1[i] = e1 | (sr1 << 4) | (s1v << 5);
        uint32 inc0 = 1u << sh0;
        uint32 inc1 = sr1 << sh1;
#pragma unroll
        for (int j = 0; j < 8; j++) {
            b0[j] += ((e0 >> 1) == (uint32)j) ? inc0 : 0u;
            b1[j] += ((e1 >> 1) == (uint32)j) ? inc1 : 0u;
        }
    }
}

// ---------------------------------------------------------------------------
__global__ __launch_bounds__(256) void gather_kernel(
    const float* __restrict__ moe, const uint32* __restrict__ r0,
    const uint32* __restrict__ r1, const int* __restrict__ prev,
    float* __restrict__ ein)
{
    int tk = blockIdx.x, b = tk >> 11;
    float4 v = ((const float4*)(moe + (long)tk * 1024))[threadIdx.x];
    uint32 a = r0[tk];
    if ((a >> 4) & 1) {
        long row = ((long)(a & 15) * 2 + b) * CAPC + (int)(a >> 5);
        ((float4*)(ein + row * 1024))[threadIdx.x] = v;
    }
    uint32 c = r1[tk];
    {
        int e = c & 15, sr1 = (c >> 4) & 1;
        int slot = (int)(c >> 5) + prev[b * 16 + e];
        if (sr1 && slot < CAPC) {
            long row = ((long)e * 2 + b) * CAPC + slot;
            ((float4*)(ein + row * 1024))[threadIdx.x] = v;
        }
    }
}

// ---------------------------------------------------------------------------
__global__ __launch_bounds__(256) void expert_ln_kernel(
    const float* __restrict__ ein, const float* __restrict__ g,
    const float* __restrict__ bb, bf16_t* __restrict__ eout)
{
    int row = blockIdx.x, e = row / (BSZ * CAPC);
    long base = (long)row * 1024;
    float4 v = ((const float4*)(ein + base))[threadIdx.x];
    float s = v.x + v.y + v.z + v.w;
    float ss = v.x * v.x + v.y * v.y + v.z * v.z + v.w * v.w;
#pragma unroll
    for (int m = 32; m; m >>= 1) { s += __shfl_xor(s, m); ss += __shfl_xor(ss, m); }
    __shared__ float l1[4], l2[4];
    if ((threadIdx.x & 63) == 0) { l1[threadIdx.x >> 6] = s; l2[threadIdx.x >> 6] = ss; }
    __syncthreads();
    float st = l1[0] + l1[1] + l1[2] + l1[3];
    float sst = l2[0] + l2[1] + l2[2] + l2[3];
    float mu = st * (1.f / 1024.f);
    float var = sst * (1.f / 1024.f) - mu * mu;
    float rstd = rsqrtf(var + 1e-5f);
    int d = threadIdx.x * 4;
    float4 gg = *(const float4*)(g + e * 1024 + d);
    float4 bv = *(const float4*)(bb + e * 1024 + d);
    bf16x4 ov;
    ov[0] = (bf16_t)((v.x - mu) * rstd * gg.x + bv.x);
    ov[1] = (bf16_t)((v.y - mu) * rstd * gg.y + bv.y);
    ov[2] = (bf16_t)((v.z - mu) * rstd * gg.z + bv.z);
    ov[3] = (bf16_t)((v.w - mu) * rstd * gg.w + bv.w);
    *(bf16x4*)(eout + base + d) = ov;
}

// ---------------------------------------------------------------------------
__global__ __launch_bounds__(256) void combine_kernel(
    const float* __restrict__ y, const float* __restrict__ eout,
    const uint32* __restrict__ r0, const uint32* __restrict__ r1,
    const float* __restrict__ tokg, const int* __restrict__ prev,
    float* __restrict__ out)
{
    int tk = blockIdx.x, b = tk >> 11;
    uint32 a = r0[tk], c = r1[tk];
    int k0f = (a >> 4) & 1;
    float w0 = k0f ? tokg[2 * tk] : 0.f;
    long row0 = ((long)(a & 15) * 2 + b) * CAPC + (int)(a >> 5);
    int e1 = c & 15;
    int slot1 = (int)(c >> 5) + prev[b * 16 + e1];
    int k1f = (((c >> 4) & 1) && slot1 < CAPC) ? 1 : 0;
    float w1 = k1f ? tokg[2 * tk + 1] : 0.f;
    long row1 = ((long)e1 * 2 + b) * CAPC + slot1;
    int i = threadIdx.x;
    float4 vy = ((const float4*)(y + (long)tk * 1024))[i];
    float4 a0 = {0.f, 0.f, 0.f, 0.f}, a1 = {0.f, 0.f, 0.f, 0.f};
    if (k0f) a0 = ((const float4*)(eout + row0 * 1024))[i];
    if (k1f) a1 = ((const float4*)(eout + row1 * 1024))[i];
    float4 ov;
    ov.x = vy.x + w0 * a0.x + w1 * a1.x;
    ov.y = vy.y + w0 * a0.y + w1 * a1.y;
    ov.z = vy.z + w0 * a0.z + w1 * a1.z;
    ov.w = vy.w + w0 * a0.w + w1 * a1.w;
    ((float4*)(out + (long)tk * 1024))[i] = ov;
}

__global__ void zero_acc_kernel(float* acc)
{
    if (threadIdx.x < 65) acc[threadIdx.x] = 0.f;
}

__global__ void finalize_kernel(const float* __restrict__ acc, float* __restrict__ tail)
{
    int t = threadIdx.x;
    float v = (t < 32) ? acc[t] * acc[32 + t] : 0.f;
#pragma unroll
    for (int m = 1; m < 64; m <<= 1) v += __shfl_xor(v, m);
    if (t == 0) {
        float bal = v * (8.0f / (2048.f * 2048.f));
        float z = acc[64] / 4096.f;
        tail[0] = 0.01f * bal + 0.001f * z;
        tail[1] = bal;
        tail[2] = z;
    }
}

// ---------------------------------------------------------------------------
extern "C" void kernel_launch(void* const* d_in, const int* in_sizes, int n_in,
                              void* d_out, int out_size, void* d_ws, size_t ws_size,
                              hipStream_t stream)
{
    (void)in_sizes; (void)n_in; (void)out_size; (void)ws_size;
    const float* x     = (const float*)d_in[0];
    // d_in[1] = attn_mask: block-causal, computed analytically; never read.
    const float* in_w  = (const float*)d_in[2];
    const float* in_b  = (const float*)d_in[3];
    const float* out_w = (const float*)d_in[4];
    const float* out_b = (const float*)d_in[5];
    const float* rg    = (const float*)d_in[6];
    const float* gw    = (const float*)d_in[7];
    const float* lng   = (const float*)d_in[8];
    const float* lnb   = (const float*)d_in[9];
    const float* w1    = (const float*)d_in[10];
    const float* b1    = (const float*)d_in[11];
    const float* w2    = (const float*)d_in[12];
    const float* b2    = (const float*)d_in[13];
    const float* runif = (const float*)d_in[14];
    float* out = (float*)d_out;

    size_t off = 0;
    char* wsb = (char*)d_ws;
    auto take = [&](size_t bytes) -> char* {
        char* p = wsb + off;
        off += (bytes + 255) & ~(size_t)255;
        return p;
    };
    bf16_t* qkvh = (bf16_t*)take((size_t)NTOK * 3072 * 2);   // 25.2 MB
    bf16_t* qkvl = (bf16_t*)take((size_t)NTOK * 3072 * 2);   // 25.2 MB
    float*  obuf = (float*)take((size_t)NTOK * 1024 * 4);
    float*  ybuf = (float*)take((size_t)NTOK * 1024 * 4);
    float*  moe  = (float*)take((size_t)NTOK * 1024 * 4);
    bf16_t* eln  = (bf16_t*)take((size_t)NEXP * BSZ * CAPC * 1024 * 2);
    bf16_t* hbuf = (bf16_t*)take((size_t)NEXP * BSZ * CAPC * HFF_P * 2);
    uint32* tokpack = (uint32*)take(NTOK * 4);
    float*  tokg = (float*)take(NTOK * 8);
    uint32* r0   = (uint32*)take(NTOK * 4);
    uint32* r1   = (uint32*)take(NTOK * 4);
    int*    prev = (int*)take(128);
    float*  acc  = (float*)take(1024);
    // aliases: qkv hi/lo are dead after attention
    float*  ein  = (float*)qkvl;   // 21.0 MB <= 25.2
    float*  eoutv = (float*)qkvh;  // 21.0 MB <= 25.2

    zero_acc_kernel<<<1, 128, 0, stream>>>(acc);

    // QKV = x @ in_proj_w^T + b  (split precision); Q cols pre-scaled 1/8
    gemm_split<0, 1><<<dim3(24, 32), 256, 0, stream>>>(
        x, in_w, in_b, nullptr, qkvh, qkvl, nullptr,
        NTOK, 3072, 1024, 1024, 0.125f);

    attn_split<<<dim3(32, 16, 2), 256, 0, stream>>>(qkvh, qkvl, obuf);

    // y = o @ out_proj_w^T + b + x  (split precision, f32 out)
    gemm_split<2, 0><<<dim3(8, 32), 256, 0, stream>>>(
        obuf, out_w, out_b, x, nullptr, nullptr, ybuf,
        NTOK, 1024, 1024, 0, 1.0f);

    rmsnorm_kernel<<<NTOK, 256, 0, stream>>>(ybuf, rg, moe);
    gating_kernel<<<NTOK / 4, 256, 0, stream>>>(moe, gw, runif, tokpack, tokg, acc);
    scan_kernel<<<dim3(BSZ), 512, 0, stream>>>(tokpack, r0, r1, prev);
    gather_kernel<<<NTOK, 256, 0, stream>>>(moe, r0, r1, prev, ein);
    expert_ln_kernel<<<NEXP * BSZ * CAPC, 256, 0, stream>>>(ein, lng, lnb, eln);

    // h = LeakyReLU(LN @ w1^T + b1) -> bf16, padded cols [2730,2752) zeroed
    gemm_nt<1, 1><<<dim3(22, 3, 16), 256, 0, stream>>>(
        eln, w1, b1, hbuf, 320, HFF_R, HFF_P, 1024, 1024,
        (long)320 * 1024, (long)HFF_R * 1024, HFF_R, (long)320 * HFF_P, HFF_P);

    // expert_out = h @ w2^T + b2 -> f32
    gemm_nt<0, 0><<<dim3(8, 3, 16), 256, 0, stream>>>(
        hbuf, w2, b2, eoutv, 320, 1024, 1024, HFF_P, HFF_R,
        (long)320 * HFF_P, (long)1024 * HFF_R, 1024, (long)320 * 1024, 1024);

    combine_kernel<<<NTOK, 256, 0, stream>>>(ybuf, eoutv, r0, r1, tokg, prev, out);
    finalize_kernel<<<1, 64, 0, stream>>>(acc, out + (size_t)NTOK * 1024);
}

// Round 5
// 785.576 us; speedup vs baseline: 1.8340x; 1.0803x over previous
//
#include <hip/hip_runtime.h>
#include <hip/hip_bf16.h>
#include <cstdint>

#define NSEQ  2048
#define BSZ   2
#define NTOK  4096          // B*N
#define EDIM  1024
#define NEXP  16
#define CAPC  160
#define HFF_R 2730
#define HFF_P 2752          // padded to multiple of 64

typedef __bf16 bf16_t;
typedef __bf16 bf16x8 __attribute__((ext_vector_type(8)));
typedef __bf16 bf16x4 __attribute__((ext_vector_type(4)));
typedef float  f32x4  __attribute__((ext_vector_type(4)));
typedef unsigned int uint32;

__device__ inline bf16x8 zero8() {
    bf16x8 v;
#pragma unroll
    for (int i = 0; i < 8; i++) v[i] = (bf16_t)0.f;
    return v;
}
__device__ inline bf16x8 pack8(float4 a, float4 b) {
    bf16x8 v;
    v[0]=(bf16_t)a.x; v[1]=(bf16_t)a.y; v[2]=(bf16_t)a.z; v[3]=(bf16_t)a.w;
    v[4]=(bf16_t)b.x; v[5]=(bf16_t)b.y; v[6]=(bf16_t)b.z; v[7]=(bf16_t)b.w;
    return v;
}
struct hl_t { bf16_t h, l; };
__device__ inline hl_t split1(float f) {
    hl_t r;
    r.h = (bf16_t)f;
    r.l = (bf16_t)(f - (float)r.h);
    return r;
}

// ---------------------------------------------------------------------------
// Split-precision NT GEMM: C[M,N] = epi(A * B^T + bias), A,B f32.
// hi*hi + hi*lo + lo*hi -> ~2^-18 relative error. BM=BN=128, BK=32.
// ---------------------------------------------------------------------------
template <int EPI, int C_SPLIT>
__global__ __launch_bounds__(256) void gemm_split(
    const float* __restrict__ A, const float* __restrict__ Bw,
    const float* __restrict__ bias, const float* __restrict__ resid,
    bf16_t* __restrict__ Chi, bf16_t* __restrict__ Clo, float* __restrict__ Cf,
    int M, int N, int K, int scale_cut, float scale_val)
{
    __shared__ __align__(16) bf16_t Ah[128 * 40], Al[128 * 40];
    __shared__ __align__(16) bf16_t Bh[128 * 40], Bl[128 * 40];
    const int t = threadIdx.x;
    const int m0 = blockIdx.y * 128, n0 = blockIdx.x * 128;
    const int lane = t & 63, l15 = lane & 15, lg = lane >> 4;
    const int wid = t >> 6, wm = wid >> 1, wn = wid & 1;
    const int srow = t >> 1, skc = (t & 1) * 16;

    f32x4 acc[4][4];
    const f32x4 zf = {0.f, 0.f, 0.f, 0.f};
#pragma unroll
    for (int i = 0; i < 4; i++)
#pragma unroll
        for (int j = 0; j < 4; j++) acc[i][j] = zf;

    for (int k0 = 0; k0 < K; k0 += 32) {
        {
            float av[16];
            const float* ap = A + (long)(m0 + srow) * K + k0 + skc;
            *(float4*)&av[0]  = *(const float4*)ap;
            *(float4*)&av[4]  = *(const float4*)(ap + 4);
            *(float4*)&av[8]  = *(const float4*)(ap + 8);
            *(float4*)&av[12] = *(const float4*)(ap + 12);
            bf16x8 h0, h1, l0, l1;
#pragma unroll
            for (int i = 0; i < 8; i++) {
                hl_t a = split1(av[i]);      h0[i] = a.h; l0[i] = a.l;
                hl_t b = split1(av[8 + i]);  h1[i] = b.h; l1[i] = b.l;
            }
            *(bf16x8*)&Ah[srow * 40 + skc] = h0; *(bf16x8*)&Ah[srow * 40 + skc + 8] = h1;
            *(bf16x8*)&Al[srow * 40 + skc] = l0; *(bf16x8*)&Al[srow * 40 + skc + 8] = l1;
        }
        {
            float bv[16];
            const float* bp = Bw + (long)(n0 + srow) * K + k0 + skc;
            *(float4*)&bv[0]  = *(const float4*)bp;
            *(float4*)&bv[4]  = *(const float4*)(bp + 4);
            *(float4*)&bv[8]  = *(const float4*)(bp + 8);
            *(float4*)&bv[12] = *(const float4*)(bp + 12);
            bf16x8 h0, h1, l0, l1;
#pragma unroll
            for (int i = 0; i < 8; i++) {
                hl_t a = split1(bv[i]);      h0[i] = a.h; l0[i] = a.l;
                hl_t b = split1(bv[8 + i]);  h1[i] = b.h; l1[i] = b.l;
            }
            *(bf16x8*)&Bh[srow * 40 + skc] = h0; *(bf16x8*)&Bh[srow * 40 + skc + 8] = h1;
            *(bf16x8*)&Bl[srow * 40 + skc] = l0; *(bf16x8*)&Bl[srow * 40 + skc + 8] = l1;
        }
        __syncthreads();
        bf16x8 amh[4], aml[4], bnh[4], bnl[4];
#pragma unroll
        for (int i = 0; i < 4; i++) {
            int base = (wm * 64 + i * 16 + l15) * 40 + lg * 8;
            amh[i] = *(const bf16x8*)&Ah[base];
            aml[i] = *(const bf16x8*)&Al[base];
        }
#pragma unroll
        for (int j = 0; j < 4; j++) {
            int base = (wn * 64 + j * 16 + l15) * 40 + lg * 8;
            bnh[j] = *(const bf16x8*)&Bh[base];
            bnl[j] = *(const bf16x8*)&Bl[base];
        }
#pragma unroll
        for (int i = 0; i < 4; i++)
#pragma unroll
            for (int j = 0; j < 4; j++) {
                acc[i][j] = __builtin_amdgcn_mfma_f32_16x16x32_bf16(amh[i], bnh[j], acc[i][j], 0, 0, 0);
                acc[i][j] = __builtin_amdgcn_mfma_f32_16x16x32_bf16(amh[i], bnl[j], acc[i][j], 0, 0, 0);
                acc[i][j] = __builtin_amdgcn_mfma_f32_16x16x32_bf16(aml[i], bnh[j], acc[i][j], 0, 0, 0);
            }
        __syncthreads();
    }

#pragma unroll
    for (int i = 0; i < 4; i++) {
        int mgb = m0 + wm * 64 + i * 16 + lg * 4;
#pragma unroll
        for (int j = 0; j < 4; j++) {
            int ng = n0 + wn * 64 + j * 16 + l15;
            float bval = bias[ng];
#pragma unroll
            for (int r = 0; r < 4; r++) {
                int mg = mgb + r;
                float val = acc[i][j][r] + bval;
                if (scale_cut > 0 && ng < scale_cut) val *= scale_val;
                if (EPI == 2) val += resid[(long)mg * N + ng];
                long idx = (long)mg * N + ng;
                if (C_SPLIT) {
                    bf16_t hi = (bf16_t)val;
                    Chi[idx] = hi;
                    Clo[idx] = (bf16_t)(val - (float)hi);
                } else {
                    Cf[idx] = val;
                }
            }
        }
    }
}

// ---------------------------------------------------------------------------
// bf16 NT GEMM (expert FFN path, value-precision only).
// ---------------------------------------------------------------------------
template <int EPI, int C_BF16>
__global__ __launch_bounds__(256) void gemm_nt(
    const bf16_t* __restrict__ Av, const float* __restrict__ Bw,
    const float* __restrict__ bias, void* __restrict__ Cv,
    int M, int N, int Nwr, int KA, int KB,
    long sAe, long sBe, long sBiasE, long sCe, int ldc)
{
    __shared__ __align__(16) bf16_t Alds[128 * 40];
    __shared__ __align__(16) bf16_t Blds[128 * 40];
    const int t = threadIdx.x;
    const int e = blockIdx.z;
    const int m0 = blockIdx.y * 128, n0 = blockIdx.x * 128;
    const int lane = t & 63, l15 = lane & 15, lg = lane >> 4;
    const int wid = t >> 6, wm = wid >> 1, wn = wid & 1;
    const int srow = t >> 1, skc = (t & 1) * 16;

    f32x4 acc[4][4];
    const f32x4 zf = {0.f, 0.f, 0.f, 0.f};
#pragma unroll
    for (int i = 0; i < 4; i++)
#pragma unroll
        for (int j = 0; j < 4; j++) acc[i][j] = zf;

    for (int k0 = 0; k0 < KA; k0 += 32) {
        {
            int mg = m0 + srow;
            bf16x8 v0 = zero8(), v1 = zero8();
            if (mg < M) {
                const bf16_t* ap = Av + (long)e * sAe + (long)mg * KA + k0 + skc;
                v0 = *(const bf16x8*)ap;
                v1 = *(const bf16x8*)(ap + 8);
            }
            *(bf16x8*)&Alds[srow * 40 + skc] = v0;
            *(bf16x8*)&Alds[srow * 40 + skc + 8] = v1;
        }
        {
            int ng = n0 + srow;
            bf16x8 v0 = zero8(), v1 = zero8();
            if (ng < N) {
                const float* bp = Bw + (long)e * sBe + (long)ng * KB + k0 + skc;
                if (k0 + 32 <= KB) {
                    float4 a = *(const float4*)bp, b = *(const float4*)(bp + 4);
                    float4 c = *(const float4*)(bp + 8), d = *(const float4*)(bp + 12);
                    v0 = pack8(a, b); v1 = pack8(c, d);
                } else {
#pragma unroll
                    for (int i = 0; i < 8; i++) {
                        int kk = k0 + skc + i;
                        v0[i] = (kk < KB) ? (bf16_t)bp[i] : (bf16_t)0.f;
                    }
#pragma unroll
                    for (int i = 0; i < 8; i++) {
                        int kk = k0 + skc + 8 + i;
                        v1[i] = (kk < KB) ? (bf16_t)bp[8 + i] : (bf16_t)0.f;
                    }
                }
            }
            *(bf16x8*)&Blds[srow * 40 + skc] = v0;
            *(bf16x8*)&Blds[srow * 40 + skc + 8] = v1;
        }
        __syncthreads();
        bf16x8 am[4], bn[4];
#pragma unroll
        for (int i = 0; i < 4; i++)
            am[i] = *(const bf16x8*)&Alds[(wm * 64 + i * 16 + l15) * 40 + lg * 8];
#pragma unroll
        for (int i = 0; i < 4; i++)
            bn[i] = *(const bf16x8*)&Blds[(wn * 64 + i * 16 + l15) * 40 + lg * 8];
#pragma unroll
        for (int i = 0; i < 4; i++)
#pragma unroll
            for (int j = 0; j < 4; j++)
                acc[i][j] = __builtin_amdgcn_mfma_f32_16x16x32_bf16(am[i], bn[j], acc[i][j], 0, 0, 0);
        __syncthreads();
    }

    const float* biasp = bias + (long)e * sBiasE;
#pragma unroll
    for (int i = 0; i < 4; i++) {
        int mgb = m0 + wm * 64 + i * 16 + lg * 4;
#pragma unroll
        for (int j = 0; j < 4; j++) {
            int ng = n0 + wn * 64 + j * 16 + l15;
            if (ng < Nwr) {
                float bval = (ng < N) ? biasp[ng] : 0.f;
#pragma unroll
                for (int r = 0; r < 4; r++) {
                    int mg = mgb + r;
                    if (mg < M) {
                        float val = acc[i][j][r] + bval;
                        if (EPI == 1) val = (val >= 0.f) ? val : 0.01f * val;
                        if (ng >= N) val = 0.f;
                        long cidx = (long)e * sCe + (long)mg * ldc + ng;
                        if (C_BF16) ((bf16_t*)Cv)[cidx] = (bf16_t)val;
                        else        ((float*)Cv)[cidx] = val;
                    }
                }
            }
        }
    }
}

// ---------------------------------------------------------------------------
// Split-precision flash attention, 8 waves x 16 queries (QBLK=128).
// K/V tile (64 keys) staged once, shared by all 8 waves. V stored transposed
// [d][k] with k = lane -> conflict-free-ish stores. P buffers wave-private.
// Block-causal analytic; Q pre-scaled 1/8 in QKV epilogue.
// grid = (16 qblocks, 16 heads, 2 batch).
// ---------------------------------------------------------------------------
__global__ __launch_bounds__(512) void attn_split(const bf16_t* __restrict__ qh,
                                                  const bf16_t* __restrict__ ql,
                                                  float* __restrict__ o)
{
    __shared__ __align__(16) bf16_t Kh[64 * 72], Kl[64 * 72];
    __shared__ __align__(16) bf16_t Vh[64 * 72], Vl[64 * 72];   // transposed [d][key]
    __shared__ __align__(16) bf16_t Ph[8][16 * 72], Pl[8][16 * 72];
    const int qb = blockIdx.x, h = blockIdx.y, b = blockIdx.z;
    const int t = threadIdx.x, wid = t >> 6, lane = t & 63, l15 = lane & 15, lg = lane >> 4;

    const int qrow = qb * 128 + wid * 16 + l15;
    const long qoff = (long)(b * NSEQ + qrow) * 3072 + h * 64 + lg * 8;
    bf16x8 qh0 = *(const bf16x8*)(qh + qoff);
    bf16x8 qh1 = *(const bf16x8*)(qh + qoff + 32);
    bf16x8 ql0 = *(const bf16x8*)(ql + qoff);
    bf16x8 ql1 = *(const bf16x8*)(ql + qoff + 32);

    const f32x4 zf = {0.f, 0.f, 0.f, 0.f};
    f32x4 Oac[4];
    float m_run[4], l_run[4];
#pragma unroll
    for (int r = 0; r < 4; r++) { Oac[r] = zf; m_run[r] = -1e30f; l_run[r] = 0.f; }

    // staging assignments
    const int krow = t >> 3, kdc = (t & 7) * 8;     // K: row, d-col
    const int vk = t & 63, vdg = (t >> 6) * 8;      // V: key (= lane), d-group
    const long kbase = (long)(b * NSEQ) * 3072 + 1024 + h * 64;
    const int kbmax = 2 * qb + (wid >> 2);          // wave-visible max key block
    const int nkb = 2 * qb + 2;

    for (int kb = 0; kb < nkb; kb++) {
        __syncthreads();
        {   // K rows (vector store, conflict-free)
            long ko = kbase + (long)(kb * 64 + krow) * 3072 + kdc;
            bf16x8 a = *(const bf16x8*)(qh + ko);
            bf16x8 bl_ = *(const bf16x8*)(ql + ko);
            *(bf16x8*)&Kh[krow * 72 + kdc] = a;
            *(bf16x8*)&Kl[krow * 72 + kdc] = bl_;
        }
        {   // V transposed: lane owns key vk, 8 d-values vdg..vdg+7
            long vo = kbase + 1024 + (long)(kb * 64 + vk) * 3072 + vdg;
            bf16x8 c = *(const bf16x8*)(qh + vo);
            bf16x8 d = *(const bf16x8*)(ql + vo);
#pragma unroll
            for (int i = 0; i < 8; i++) {
                Vh[(vdg + i) * 72 + vk] = c[i];
                Vl[(vdg + i) * 72 + vk] = d[i];
            }
        }
        __syncthreads();
        if (kb <= kbmax) {
            // S = Q K^T
            f32x4 s[4];
#pragma unroll
            for (int ks = 0; ks < 4; ks++) {
                s[ks] = zf;
                int base = (ks * 16 + l15) * 72 + lg * 8;
                bf16x8 kh0 = *(const bf16x8*)&Kh[base];
                bf16x8 kh1 = *(const bf16x8*)&Kh[base + 32];
                bf16x8 kl0 = *(const bf16x8*)&Kl[base];
                bf16x8 kl1 = *(const bf16x8*)&Kl[base + 32];
                s[ks] = __builtin_amdgcn_mfma_f32_16x16x32_bf16(qh0, kh0, s[ks], 0, 0, 0);
                s[ks] = __builtin_amdgcn_mfma_f32_16x16x32_bf16(qh1, kh1, s[ks], 0, 0, 0);
                s[ks] = __builtin_amdgcn_mfma_f32_16x16x32_bf16(qh0, kl0, s[ks], 0, 0, 0);
                s[ks] = __builtin_amdgcn_mfma_f32_16x16x32_bf16(qh1, kl1, s[ks], 0, 0, 0);
                s[ks] = __builtin_amdgcn_mfma_f32_16x16x32_bf16(ql0, kh0, s[ks], 0, 0, 0);
                s[ks] = __builtin_amdgcn_mfma_f32_16x16x32_bf16(ql1, kh1, s[ks], 0, 0, 0);
            }
            // online softmax (rows in 16-lane groups; butterfly over low 4 bits)
            float alpha[4];
#pragma unroll
            for (int r = 0; r < 4; r++) {
                float mt = fmaxf(fmaxf(s[0][r], s[1][r]), fmaxf(s[2][r], s[3][r]));
#pragma unroll
                for (int m = 1; m < 16; m <<= 1) mt = fmaxf(mt, __shfl_xor(mt, m));
                float mn = fmaxf(m_run[r], mt);
                alpha[r] = __expf(m_run[r] - mn);
                m_run[r] = mn;
            }
            float ladd[4] = {0.f, 0.f, 0.f, 0.f};
#pragma unroll
            for (int ks = 0; ks < 4; ks++)
#pragma unroll
                for (int r = 0; r < 4; r++) {
                    float p = __expf(s[ks][r] - m_run[r]);
                    s[ks][r] = p;
                    ladd[r] += p;
                }
#pragma unroll
            for (int r = 0; r < 4; r++) {
#pragma unroll
                for (int m = 1; m < 16; m <<= 1) ladd[r] += __shfl_xor(ladd[r], m);
                l_run[r] = l_run[r] * alpha[r] + ladd[r];
            }
#pragma unroll
            for (int sb = 0; sb < 4; sb++)
#pragma unroll
                for (int r = 0; r < 4; r++) Oac[sb][r] *= alpha[r];
            // P -> LDS (wave-private region; no cross-wave barrier needed)
            bf16_t* pwh = &Ph[wid][0];
            bf16_t* pwl = &Pl[wid][0];
#pragma unroll
            for (int ks = 0; ks < 4; ks++)
#pragma unroll
                for (int r = 0; r < 4; r++) {
                    hl_t pv = split1(s[ks][r]);
                    pwh[(lg * 4 + r) * 72 + ks * 16 + l15] = pv.h;
                    pwl[(lg * 4 + r) * 72 + ks * 16 + l15] = pv.l;
                }
            // O += P V
#pragma unroll
            for (int kst = 0; kst < 2; kst++) {
                bf16x8 pfh = *(const bf16x8*)&pwh[l15 * 72 + kst * 32 + lg * 8];
                bf16x8 pfl = *(const bf16x8*)&pwl[l15 * 72 + kst * 32 + lg * 8];
#pragma unroll
                for (int sb = 0; sb < 4; sb++) {
                    int base = (sb * 16 + l15) * 72 + kst * 32 + lg * 8;
                    bf16x8 vfh = *(const bf16x8*)&Vh[base];
                    bf16x8 vfl = *(const bf16x8*)&Vl[base];
                    Oac[sb] = __builtin_amdgcn_mfma_f32_16x16x32_bf16(pfh, vfh, Oac[sb], 0, 0, 0);
                    Oac[sb] = __builtin_amdgcn_mfma_f32_16x16x32_bf16(pfh, vfl, Oac[sb], 0, 0, 0);
                    Oac[sb] = __builtin_amdgcn_mfma_f32_16x16x32_bf16(pfl, vfh, Oac[sb], 0, 0, 0);
                }
            }
        }
    }
#pragma unroll
    for (int sb = 0; sb < 4; sb++)
#pragma unroll
        for (int r = 0; r < 4; r++) {
            int qg = qb * 128 + wid * 16 + lg * 4 + r;
            o[(long)(b * NSEQ + qg) * 1024 + h * 64 + sb * 16 + l15] = Oac[sb][r] / l_run[r];
        }
}

// ---------------------------------------------------------------------------
__global__ __launch_bounds__(256) void rmsnorm_kernel(const float* __restrict__ y,
                                                      const float* __restrict__ gamma,
                                                      float* __restrict__ moe)
{
    long base = (long)blockIdx.x * 1024;
    float4 v = ((const float4*)(y + base))[threadIdx.x];
    float ss = v.x * v.x + v.y * v.y + v.z * v.z + v.w * v.w;
#pragma unroll
    for (int m = 32; m; m >>= 1) ss += __shfl_xor(ss, m);
    __shared__ float ls[4];
    if ((threadIdx.x & 63) == 0) ls[threadIdx.x >> 6] = ss;
    __syncthreads();
    float tot = ls[0] + ls[1] + ls[2] + ls[3];
    float sc = 32.0f / fmaxf(sqrtf(tot), 1e-12f);
    float4 g = ((const float4*)gamma)[threadIdx.x];
    float4 ov;
    ov.x = v.x * sc * g.x; ov.y = v.y * sc * g.y; ov.z = v.z * sc * g.z; ov.w = v.w * sc * g.w;
    ((float4*)(moe + base))[threadIdx.x] = ov;
}

// ---------------------------------------------------------------------------
// Gating. Top-2 on raw f32 logits; exact logistic gates; aux accums.
// ---------------------------------------------------------------------------
__global__ __launch_bounds__(256) void gating_kernel(
    const float* __restrict__ moe, const float* __restrict__ gw,
    const float* __restrict__ runif, uint32* __restrict__ tokpack,
    float* __restrict__ tokg, float* __restrict__ acc)
{
    const int wid = threadIdx.x >> 6, lane = threadIdx.x & 63;
    const int tk = blockIdx.x * 4 + wid;
    const int b = tk >> 11, n = tk & 2047;
    float xv[16];
    const float4* xr4 = (const float4*)(moe + (long)tk * 1024 + lane * 16);
#pragma unroll
    for (int i = 0; i < 4; i++) {
        float4 v = xr4[i];
        xv[4 * i] = v.x; xv[4 * i + 1] = v.y; xv[4 * i + 2] = v.z; xv[4 * i + 3] = v.w;
    }
    float logit[16];
#pragma unroll
    for (int e = 0; e < 16; e++) {
        const float4* wr4 = (const float4*)(gw + e * 1024 + lane * 16);
        float p = 0.f;
#pragma unroll
        for (int i = 0; i < 4; i++) {
            float4 w = wr4[i];
            p = fmaf(xv[4 * i], w.x, p);     p = fmaf(xv[4 * i + 1], w.y, p);
            p = fmaf(xv[4 * i + 2], w.z, p); p = fmaf(xv[4 * i + 3], w.w, p);
        }
#pragma unroll
        for (int m = 1; m < 64; m <<= 1) p += __shfl_xor(p, m);
        logit[e] = p;
    }
    int e0 = 0; float t0 = logit[0];
#pragma unroll
    for (int e = 1; e < 16; e++) if (logit[e] > t0) { t0 = logit[e]; e0 = e; }
    int e1 = (e0 == 0) ? 1 : 0; float t1 = logit[e1];
#pragma unroll
    for (int e = 0; e < 16; e++) if (e != e0 && logit[e] > t1) { t1 = logit[e]; e1 = e; }
    float g0n = 1.f / (1.f + __expf(t1 - t0));
    float g1n = 1.f / (1.f + __expf(t0 - t1));
    int sr1 = (runif[(long)(BSZ + b) * NSEQ + n] < g1n / 0.2f) ? 1 : 0;
    float mx = t0, sum = 0.f, raw[16];
#pragma unroll
    for (int e = 0; e < 16; e++) { raw[e] = __expf(logit[e] - mx); sum += raw[e]; }
    float inv = 1.f / sum;
    float lse = mx + __logf(sum);
    if (lane == 0) {
        tokpack[tk] = (uint32)e0 | ((uint32)e1 << 4) | ((uint32)sr1 << 8);
        tokg[2 * tk] = g0n; tokg[2 * tk + 1] = g1n;
        atomicAdd(&acc[32 + b * 16 + e0], 1.0f);
        atomicAdd(&acc[64], lse * lse);
    }
    if (lane < 16) atomicAdd(&acc[b * 16 + lane], raw[lane] * inv);
}

// ---------------------------------------------------------------------------
// Parallel position scan. One block per batch, 512 threads x 4 tokens.
// ---------------------------------------------------------------------------
__global__ __launch_bounds__(512) void scan_kernel(const uint32* __restrict__ tokpack,
                                                   uint32* __restrict__ r0,
                                                   uint32* __restrict__ r1,
                                                   int* __restrict__ prev)
{
    const int b = blockIdx.x, t = threadIdx.x;
    const int wv = t >> 6, lane = t & 63;
    uint32 toks[4];
    *(uint4*)toks = ((const uint4*)(tokpack + b * NSEQ))[t];

    uint32 c0[8], c1[8];
#pragma unroll
    for (int j = 0; j < 8; j++) { c0[j] = 0u; c1[j] = 0u; }
#pragma unroll
    for (int i = 0; i < 4; i++) {
        uint32 p = toks[i];
        uint32 e0 = p & 15, e1 = (p >> 4) & 15, sr1 = (p >> 8) & 1;
        uint32 inc0 = 1u << ((e0 & 1) * 16);
        uint32 inc1 = sr1 << ((e1 & 1) * 16);
#pragma unroll
        for (int j = 0; j < 8; j++) {
            c0[j] += ((e0 >> 1) == (uint32)j) ? inc0 : 0u;
            c1[j] += ((e1 >> 1) == (uint32)j) ? inc1 : 0u;
        }
    }
    uint32 i0[8], i1[8];
#pragma unroll
    for (int j = 0; j < 8; j++) { i0[j] = c0[j]; i1[j] = c1[j]; }
#pragma unroll
    for (int off = 1; off < 64; off <<= 1) {
#pragma unroll
        for (int j = 0; j < 8; j++) {
            uint32 u0 = __shfl_up(i0[j], off);
            uint32 u1 = __shfl_up(i1[j], off);
            if (lane >= off) { i0[j] += u0; i1[j] += u1; }
        }
    }
    __shared__ uint32 wsum0[8][8], wsum1[8][8];
    if (lane == 63) {
#pragma unroll
        for (int j = 0; j < 8; j++) { wsum0[wv][j] = i0[j]; wsum1[wv][j] = i1[j]; }
    }
    __syncthreads();
    uint32 b0[8], b1[8];
#pragma unroll
    for (int j = 0; j < 8; j++) {
        uint32 s0 = 0u, s1 = 0u;
#pragma unroll
        for (int w = 0; w < 8; w++) {
            s0 += (w < wv) ? wsum0[w][j] : 0u;
            s1 += (w < wv) ? wsum1[w][j] : 0u;
        }
        b0[j] = s0 + i0[j] - c0[j];
        b1[j] = s1 + i1[j] - c1[j];
    }
    if (t == 0) {
#pragma unroll
        for (int j = 0; j < 8; j++) {
            uint32 tot = 0u;
#pragma unroll
            for (int w = 0; w < 8; w++) tot += wsum0[w][j];
            int tlo = (int)(tot & 0xffffu), thi = (int)(tot >> 16);
            prev[b * 16 + 2 * j]     = tlo < CAPC ? tlo : CAPC;
            prev[b * 16 + 2 * j + 1] = thi < CAPC ? thi : CAPC;
        }
    }
    uint32* rr0 = r0 + b * NSEQ + t * 4;
    uint32* rr1 = r1 + b * NSEQ + t * 4;
#pragma unroll
    for (int i = 0; i < 4; i++) {
        uint32 p = toks[i];
        uint32 e0 = p & 15, e1 = (p >> 4) & 15, sr1 = (p >> 8) & 1;
        uint32 sh0 = (e0 & 1) * 16, sh1 = (e1 & 1) * 16;
        uint32 w0 = 0u, w1 = 0u;
#pragma unroll
        for (int j = 0; j < 8; j++) {
            w0 += ((e0 >> 1) == (uint32)j) ? b0[j] : 0u;
            w1 += ((e1 >> 1) == (uint32)j) ? b1[j] : 0u;
        }
        uint32 s0 = (w0 >> sh0) & 0xffffu;
        uint32 s1v = (w1 >> sh1) & 0xffffu;
        uint32 kept = (s0 < CAPC) ? 1u : 0u;
        rr0[i] = e0 | (kept << 4) | (s0 << 5);
        rr1[i] = e1 | (sr1 << 4) | (s1v << 5);
        uint32 inc0 = 1u << sh0;
        uint32 inc1 = sr1 << sh1;
#pragma unroll
        for (int j = 0; j < 8; j++) {
            b0[j] += ((e0 >> 1) == (uint32)j) ? inc0 : 0u;
            b1[j] += ((e1 >> 1) == (uint32)j) ? inc1 : 0u;
        }
    }
}

// ---------------------------------------------------------------------------
__global__ __launch_bounds__(256) void gather_kernel(
    const float* __restrict__ moe, const uint32* __restrict__ r0,
    const uint32* __restrict__ r1, const int* __restrict__ prev,
    float* __restrict__ ein)
{
    int tk = blockIdx.x, b = tk >> 11;
    float4 v = ((const float4*)(moe + (long)tk * 1024))[threadIdx.x];
    uint32 a = r0[tk];
    if ((a >> 4) & 1) {
        long row = ((long)(a & 15) * 2 + b) * CAPC + (int)(a >> 5);
        ((float4*)(ein + row * 1024))[threadIdx.x] = v;
    }
    uint32 c = r1[tk];
    {
        int e = c & 15, sr1 = (c >> 4) & 1;
        int slot = (int)(c >> 5) + prev[b * 16 + e];
        if (sr1 && slot < CAPC) {
            long row = ((long)e * 2 + b) * CAPC + slot;
            ((float4*)(ein + row * 1024))[threadIdx.x] = v;
        }
    }
}

// ---------------------------------------------------------------------------
__global__ __launch_bounds__(256) void expert_ln_kernel(
    const float* __restrict__ ein, const float* __restrict__ g,
    const float* __restrict__ bb, bf16_t* __restrict__ eout)
{
    int row = blockIdx.x, e = row / (BSZ * CAPC);
    long base = (long)row * 1024;
    float4 v = ((const float4*)(ein + base))[threadIdx.x];
    float s = v.x + v.y + v.z + v.w;
    float ss = v.x * v.x + v.y * v.y + v.z * v.z + v.w * v.w;
#pragma unroll
    for (int m = 32; m; m >>= 1) { s += __shfl_xor(s, m); ss += __shfl_xor(ss, m); }
    __shared__ float l1[4], l2[4];
    if ((threadIdx.x & 63) == 0) { l1[threadIdx.x >> 6] = s; l2[threadIdx.x >> 6] = ss; }
    __syncthreads();
    float st = l1[0] + l1[1] + l1[2] + l1[3];
    float sst = l2[0] + l2[1] + l2[2] + l2[3];
    float mu = st * (1.f / 1024.f);
    float var = sst * (1.f / 1024.f) - mu * mu;
    float rstd = rsqrtf(var + 1e-5f);
    int d = threadIdx.x * 4;
    float4 gg = *(const float4*)(g + e * 1024 + d);
    float4 bv = *(const float4*)(bb + e * 1024 + d);
    bf16x4 ov;
    ov[0] = (bf16_t)((v.x - mu) * rstd * gg.x + bv.x);
    ov[1] = (bf16_t)((v.y - mu) * rstd * gg.y + bv.y);
    ov[2] = (bf16_t)((v.z - mu) * rstd * gg.z + bv.z);
    ov[3] = (bf16_t)((v.w - mu) * rstd * gg.w + bv.w);
    *(bf16x4*)(eout + base + d) = ov;
}

// ---------------------------------------------------------------------------
__global__ __launch_bounds__(256) void combine_kernel(
    const float* __restrict__ y, const float* __restrict__ eout,
    const uint32* __restrict__ r0, const uint32* __restrict__ r1,
    const float* __restrict__ tokg, const int* __restrict__ prev,
    float* __restrict__ out)
{
    int tk = blockIdx.x, b = tk >> 11;
    uint32 a = r0[tk], c = r1[tk];
    int k0f = (a >> 4) & 1;
    float w0 = k0f ? tokg[2 * tk] : 0.f;
    long row0 = ((long)(a & 15) * 2 + b) * CAPC + (int)(a >> 5);
    int e1 = c & 15;
    int slot1 = (int)(c >> 5) + prev[b * 16 + e1];
    int k1f = (((c >> 4) & 1) && slot1 < CAPC) ? 1 : 0;
    float w1 = k1f ? tokg[2 * tk + 1] : 0.f;
    long row1 = ((long)e1 * 2 + b) * CAPC + slot1;
    int i = threadIdx.x;
    float4 vy = ((const float4*)(y + (long)tk * 1024))[i];
    float4 a0 = {0.f, 0.f, 0.f, 0.f}, a1 = {0.f, 0.f, 0.f, 0.f};
    if (k0f) a0 = ((const float4*)(eout + row0 * 1024))[i];
    if (k1f) a1 = ((const float4*)(eout + row1 * 1024))[i];
    float4 ov;
    ov.x = vy.x + w0 * a0.x + w1 * a1.x;
    ov.y = vy.y + w0 * a0.y + w1 * a1.y;
    ov.z = vy.z + w0 * a0.z + w1 * a1.z;
    ov.w = vy.w + w0 * a0.w + w1 * a1.w;
    ((float4*)(out + (long)tk * 1024))[i] = ov;
}

__global__ void zero_acc_kernel(float* acc)
{
    if (threadIdx.x < 65) acc[threadIdx.x] = 0.f;
}

__global__ void finalize_kernel(const float* __restrict__ acc, float* __restrict__ tail)
{
    int t = threadIdx.x;
    float v = (t < 32) ? acc[t] * acc[32 + t] : 0.f;
#pragma unroll
    for (int m = 1; m < 64; m <<= 1) v += __shfl_xor(v, m);
    if (t == 0) {
        float bal = v * (8.0f / (2048.f * 2048.f));
        float z = acc[64] / 4096.f;
        tail[0] = 0.01f * bal + 0.001f * z;
        tail[1] = bal;
        tail[2] = z;
    }
}

// ---------------------------------------------------------------------------
extern "C" void kernel_launch(void* const* d_in, const int* in_sizes, int n_in,
                              void* d_out, int out_size, void* d_ws, size_t ws_size,
                              hipStream_t stream)
{
    (void)in_sizes; (void)n_in; (void)out_size; (void)ws_size;
    const float* x     = (const float*)d_in[0];
    // d_in[1] = attn_mask: block-causal, computed analytically; never read.
    const float* in_w  = (const float*)d_in[2];
    const float* in_b  = (const float*)d_in[3];
    const float* out_w = (const float*)d_in[4];
    const float* out_b = (const float*)d_in[5];
    const float* rg    = (const float*)d_in[6];
    const float* gw    = (const float*)d_in[7];
    const float* lng   = (const float*)d_in[8];
    const float* lnb   = (const float*)d_in[9];
    const float* w1    = (const float*)d_in[10];
    const float* b1    = (const float*)d_in[11];
    const float* w2    = (const float*)d_in[12];
    const float* b2    = (const float*)d_in[13];
    const float* runif = (const float*)d_in[14];
    float* out = (float*)d_out;

    size_t off = 0;
    char* wsb = (char*)d_ws;
    auto take = [&](size_t bytes) -> char* {
        char* p = wsb + off;
        off += (bytes + 255) & ~(size_t)255;
        return p;
    };
    bf16_t* qkvh = (bf16_t*)take((size_t)NTOK * 3072 * 2);   // 25.2 MB
    bf16_t* qkvl = (bf16_t*)take((size_t)NTOK * 3072 * 2);   // 25.2 MB
    float*  obuf = (float*)take((size_t)NTOK * 1024 * 4);
    float*  ybuf = (float*)take((size_t)NTOK * 1024 * 4);
    float*  moe  = (float*)take((size_t)NTOK * 1024 * 4);
    bf16_t* eln  = (bf16_t*)take((size_t)NEXP * BSZ * CAPC * 1024 * 2);
    bf16_t* hbuf = (bf16_t*)take((size_t)NEXP * BSZ * CAPC * HFF_P * 2);
    uint32* tokpack = (uint32*)take(NTOK * 4);
    float*  tokg = (float*)take(NTOK * 8);
    uint32* r0   = (uint32*)take(NTOK * 4);
    uint32* r1   = (uint32*)take(NTOK * 4);
    int*    prev = (int*)take(128);
    float*  acc  = (float*)take(1024);
    // aliases: qkv hi/lo are dead after attention
    float*  ein  = (float*)qkvl;   // 21.0 MB <= 25.2
    float*  eoutv = (float*)qkvh;  // 21.0 MB <= 25.2

    zero_acc_kernel<<<1, 128, 0, stream>>>(acc);

    // QKV = x @ in_proj_w^T + b  (split precision); Q cols pre-scaled 1/8
    gemm_split<0, 1><<<dim3(24, 32), 256, 0, stream>>>(
        x, in_w, in_b, nullptr, qkvh, qkvl, nullptr,
        NTOK, 3072, 1024, 1024, 0.125f);

    attn_split<<<dim3(16, 16, 2), 512, 0, stream>>>(qkvh, qkvl, obuf);

    // y = o @ out_proj_w^T + b + x  (split precision, f32 out)
    gemm_split<2, 0><<<dim3(8, 32), 256, 0, stream>>>(
        obuf, out_w, out_b, x, nullptr, nullptr, ybuf,
        NTOK, 1024, 1024, 0, 1.0f);

    rmsnorm_kernel<<<NTOK, 256, 0, stream>>>(ybuf, rg, moe);
    gating_kernel<<<NTOK / 4, 256, 0, stream>>>(moe, gw, runif, tokpack, tokg, acc);
    scan_kernel<<<dim3(BSZ), 512, 0, stream>>>(tokpack, r0, r1, prev);
    gather_kernel<<<NTOK, 256, 0, stream>>>(moe, r0, r1, prev, ein);
    expert_ln_kernel<<<NEXP * BSZ * CAPC, 256, 0, stream>>>(ein, lng, lnb, eln);

    // h = LeakyReLU(LN @ w1^T + b1) -> bf16, padded cols [2730,2752) zeroed
    gemm_nt<1, 1><<<dim3(22, 3, 16), 256, 0, stream>>>(
        eln, w1, b1, hbuf, 320, HFF_R, HFF_P, 1024, 1024,
        (long)320 * 1024, (long)HFF_R * 1024, HFF_R, (long)320 * HFF_P, HFF_P);

    // expert_out = h @ w2^T + b2 -> f32
    gemm_nt<0, 0><<<dim3(8, 3, 16), 256, 0, stream>>>(
        hbuf, w2, b2, eoutv, 320, 1024, 1024, HFF_P, HFF_R,
        (long)320 * HFF_P, (long)1024 * HFF_R, 1024, (long)320 * 1024, 1024);

    combine_kernel<<<NTOK, 256, 0, stream>>>(ybuf, eoutv, r0, r1, tokg, prev, out);
    finalize_kernel<<<1, 64, 0, stream>>>(acc, out + (size_t)NTOK * 1024);
}

// Round 6
// 778.075 us; speedup vs baseline: 1.8517x; 1.0096x over previous
//
#include <hip/hip_runtime.h>
#include <hip/hip_bf16.h>
#include <cstdint>

#define NSEQ  2048
#define BSZ   2
#define NTOK  4096          // B*N
#define EDIM  1024
#define NEXP  16
#define CAPC  160
#define HFF_R 2730
#define HFF_P 2752          // padded to multiple of 64

typedef __bf16 bf16_t;
typedef __bf16 bf16x8 __attribute__((ext_vector_type(8)));
typedef __bf16 bf16x4 __attribute__((ext_vector_type(4)));
typedef float  f32x4  __attribute__((ext_vector_type(4)));
typedef unsigned int uint32;

__device__ inline bf16x8 zero8() {
    bf16x8 v;
#pragma unroll
    for (int i = 0; i < 8; i++) v[i] = (bf16_t)0.f;
    return v;
}
__device__ inline bf16x8 pack8(float4 a, float4 b) {
    bf16x8 v;
    v[0]=(bf16_t)a.x; v[1]=(bf16_t)a.y; v[2]=(bf16_t)a.z; v[3]=(bf16_t)a.w;
    v[4]=(bf16_t)b.x; v[5]=(bf16_t)b.y; v[6]=(bf16_t)b.z; v[7]=(bf16_t)b.w;
    return v;
}
struct hl_t { bf16_t h, l; };
__device__ inline hl_t split1(float f) {
    hl_t r;
    r.h = (bf16_t)f;
    r.l = (bf16_t)(f - (float)r.h);
    return r;
}

// ---------------------------------------------------------------------------
// Split-precision NT GEMM: C[M,N] = epi(A * B^T + bias), A,B f32.
// hi*hi + hi*lo + lo*hi -> ~2^-18 relative error. BM=BN=128, BK=32.
// ---------------------------------------------------------------------------
template <int EPI, int C_SPLIT>
__global__ __launch_bounds__(256) void gemm_split(
    const float* __restrict__ A, const float* __restrict__ Bw,
    const float* __restrict__ bias, const float* __restrict__ resid,
    bf16_t* __restrict__ Chi, bf16_t* __restrict__ Clo, float* __restrict__ Cf,
    int M, int N, int K, int scale_cut, float scale_val)
{
    __shared__ __align__(16) bf16_t Ah[128 * 40], Al[128 * 40];
    __shared__ __align__(16) bf16_t Bh[128 * 40], Bl[128 * 40];
    const int t = threadIdx.x;
    const int m0 = blockIdx.y * 128, n0 = blockIdx.x * 128;
    const int lane = t & 63, l15 = lane & 15, lg = lane >> 4;
    const int wid = t >> 6, wm = wid >> 1, wn = wid & 1;
    const int srow = t >> 1, skc = (t & 1) * 16;

    f32x4 acc[4][4];
    const f32x4 zf = {0.f, 0.f, 0.f, 0.f};
#pragma unroll
    for (int i = 0; i < 4; i++)
#pragma unroll
        for (int j = 0; j < 4; j++) acc[i][j] = zf;

    for (int k0 = 0; k0 < K; k0 += 32) {
        {
            float av[16];
            const float* ap = A + (long)(m0 + srow) * K + k0 + skc;
            *(float4*)&av[0]  = *(const float4*)ap;
            *(float4*)&av[4]  = *(const float4*)(ap + 4);
            *(float4*)&av[8]  = *(const float4*)(ap + 8);
            *(float4*)&av[12] = *(const float4*)(ap + 12);
            bf16x8 h0, h1, l0, l1;
#pragma unroll
            for (int i = 0; i < 8; i++) {
                hl_t a = split1(av[i]);      h0[i] = a.h; l0[i] = a.l;
                hl_t b = split1(av[8 + i]);  h1[i] = b.h; l1[i] = b.l;
            }
            *(bf16x8*)&Ah[srow * 40 + skc] = h0; *(bf16x8*)&Ah[srow * 40 + skc + 8] = h1;
            *(bf16x8*)&Al[srow * 40 + skc] = l0; *(bf16x8*)&Al[srow * 40 + skc + 8] = l1;
        }
        {
            float bv[16];
            const float* bp = Bw + (long)(n0 + srow) * K + k0 + skc;
            *(float4*)&bv[0]  = *(const float4*)bp;
            *(float4*)&bv[4]  = *(const float4*)(bp + 4);
            *(float4*)&bv[8]  = *(const float4*)(bp + 8);
            *(float4*)&bv[12] = *(const float4*)(bp + 12);
            bf16x8 h0, h1, l0, l1;
#pragma unroll
            for (int i = 0; i < 8; i++) {
                hl_t a = split1(bv[i]);      h0[i] = a.h; l0[i] = a.l;
                hl_t b = split1(bv[8 + i]);  h1[i] = b.h; l1[i] = b.l;
            }
            *(bf16x8*)&Bh[srow * 40 + skc] = h0; *(bf16x8*)&Bh[srow * 40 + skc + 8] = h1;
            *(bf16x8*)&Bl[srow * 40 + skc] = l0; *(bf16x8*)&Bl[srow * 40 + skc + 8] = l1;
        }
        __syncthreads();
        bf16x8 amh[4], aml[4], bnh[4], bnl[4];
#pragma unroll
        for (int i = 0; i < 4; i++) {
            int base = (wm * 64 + i * 16 + l15) * 40 + lg * 8;
            amh[i] = *(const bf16x8*)&Ah[base];
            aml[i] = *(const bf16x8*)&Al[base];
        }
#pragma unroll
        for (int j = 0; j < 4; j++) {
            int base = (wn * 64 + j * 16 + l15) * 40 + lg * 8;
            bnh[j] = *(const bf16x8*)&Bh[base];
            bnl[j] = *(const bf16x8*)&Bl[base];
        }
#pragma unroll
        for (int i = 0; i < 4; i++)
#pragma unroll
            for (int j = 0; j < 4; j++) {
                acc[i][j] = __builtin_amdgcn_mfma_f32_16x16x32_bf16(amh[i], bnh[j], acc[i][j], 0, 0, 0);
                acc[i][j] = __builtin_amdgcn_mfma_f32_16x16x32_bf16(amh[i], bnl[j], acc[i][j], 0, 0, 0);
                acc[i][j] = __builtin_amdgcn_mfma_f32_16x16x32_bf16(aml[i], bnh[j], acc[i][j], 0, 0, 0);
            }
        __syncthreads();
    }

#pragma unroll
    for (int i = 0; i < 4; i++) {
        int mgb = m0 + wm * 64 + i * 16 + lg * 4;
#pragma unroll
        for (int j = 0; j < 4; j++) {
            int ng = n0 + wn * 64 + j * 16 + l15;
            float bval = bias[ng];
#pragma unroll
            for (int r = 0; r < 4; r++) {
                int mg = mgb + r;
                float val = acc[i][j][r] + bval;
                if (scale_cut > 0 && ng < scale_cut) val *= scale_val;
                if (EPI == 2) val += resid[(long)mg * N + ng];
                long idx = (long)mg * N + ng;
                if (C_SPLIT) {
                    bf16_t hi = (bf16_t)val;
                    Chi[idx] = hi;
                    Clo[idx] = (bf16_t)(val - (float)hi);
                } else {
                    Cf[idx] = val;
                }
            }
        }
    }
}

// ---------------------------------------------------------------------------
// bf16 NT GEMM (expert FFN path, value-precision only).
// ---------------------------------------------------------------------------
template <int EPI, int C_BF16>
__global__ __launch_bounds__(256) void gemm_nt(
    const bf16_t* __restrict__ Av, const float* __restrict__ Bw,
    const float* __restrict__ bias, void* __restrict__ Cv,
    int M, int N, int Nwr, int KA, int KB,
    long sAe, long sBe, long sBiasE, long sCe, int ldc)
{
    __shared__ __align__(16) bf16_t Alds[128 * 40];
    __shared__ __align__(16) bf16_t Blds[128 * 40];
    const int t = threadIdx.x;
    const int e = blockIdx.z;
    const int m0 = blockIdx.y * 128, n0 = blockIdx.x * 128;
    const int lane = t & 63, l15 = lane & 15, lg = lane >> 4;
    const int wid = t >> 6, wm = wid >> 1, wn = wid & 1;
    const int srow = t >> 1, skc = (t & 1) * 16;

    f32x4 acc[4][4];
    const f32x4 zf = {0.f, 0.f, 0.f, 0.f};
#pragma unroll
    for (int i = 0; i < 4; i++)
#pragma unroll
        for (int j = 0; j < 4; j++) acc[i][j] = zf;

    for (int k0 = 0; k0 < KA; k0 += 32) {
        {
            int mg = m0 + srow;
            bf16x8 v0 = zero8(), v1 = zero8();
            if (mg < M) {
                const bf16_t* ap = Av + (long)e * sAe + (long)mg * KA + k0 + skc;
                v0 = *(const bf16x8*)ap;
                v1 = *(const bf16x8*)(ap + 8);
            }
            *(bf16x8*)&Alds[srow * 40 + skc] = v0;
            *(bf16x8*)&Alds[srow * 40 + skc + 8] = v1;
        }
        {
            int ng = n0 + srow;
            bf16x8 v0 = zero8(), v1 = zero8();
            if (ng < N) {
                const float* bp = Bw + (long)e * sBe + (long)ng * KB + k0 + skc;
                if (k0 + 32 <= KB) {
                    float4 a = *(const float4*)bp, b = *(const float4*)(bp + 4);
                    float4 c = *(const float4*)(bp + 8), d = *(const float4*)(bp + 12);
                    v0 = pack8(a, b); v1 = pack8(c, d);
                } else {
#pragma unroll
                    for (int i = 0; i < 8; i++) {
                        int kk = k0 + skc + i;
                        v0[i] = (kk < KB) ? (bf16_t)bp[i] : (bf16_t)0.f;
                    }
#pragma unroll
                    for (int i = 0; i < 8; i++) {
                        int kk = k0 + skc + 8 + i;
                        v1[i] = (kk < KB) ? (bf16_t)bp[8 + i] : (bf16_t)0.f;
                    }
                }
            }
            *(bf16x8*)&Blds[srow * 40 + skc] = v0;
            *(bf16x8*)&Blds[srow * 40 + skc + 8] = v1;
        }
        __syncthreads();
        bf16x8 am[4], bn[4];
#pragma unroll
        for (int i = 0; i < 4; i++)
            am[i] = *(const bf16x8*)&Alds[(wm * 64 + i * 16 + l15) * 40 + lg * 8];
#pragma unroll
        for (int i = 0; i < 4; i++)
            bn[i] = *(const bf16x8*)&Blds[(wn * 64 + i * 16 + l15) * 40 + lg * 8];
#pragma unroll
        for (int i = 0; i < 4; i++)
#pragma unroll
            for (int j = 0; j < 4; j++)
                acc[i][j] = __builtin_amdgcn_mfma_f32_16x16x32_bf16(am[i], bn[j], acc[i][j], 0, 0, 0);
        __syncthreads();
    }

    const float* biasp = bias + (long)e * sBiasE;
#pragma unroll
    for (int i = 0; i < 4; i++) {
        int mgb = m0 + wm * 64 + i * 16 + lg * 4;
#pragma unroll
        for (int j = 0; j < 4; j++) {
            int ng = n0 + wn * 64 + j * 16 + l15;
            if (ng < Nwr) {
                float bval = (ng < N) ? biasp[ng] : 0.f;
#pragma unroll
                for (int r = 0; r < 4; r++) {
                    int mg = mgb + r;
                    if (mg < M) {
                        float val = acc[i][j][r] + bval;
                        if (EPI == 1) val = (val >= 0.f) ? val : 0.01f * val;
                        if (ng >= N) val = 0.f;
                        long cidx = (long)e * sCe + (long)mg * ldc + ng;
                        if (C_BF16) ((bf16_t*)Cv)[cidx] = (bf16_t)val;
                        else        ((float*)Cv)[cidx] = val;
                    }
                }
            }
        }
    }
}

// ---------------------------------------------------------------------------
// Split-precision flash attention, balanced + double-buffered.
// 4 waves x 32 q-rows (2 row-groups) = 128-row q-tile. Each block processes
// q-tiles pr and 15-pr sequentially -> uniform 34 K-tile iterations/block.
// K/V double-buffered (reg-staged); K/V fragments read from LDS once per
// iteration and reused by both row-groups. Block-causal analytic; Q pre-
// scaled 1/8. grid = (8, 16, 2), 256 threads, 1 block/CU.
// ---------------------------------------------------------------------------
__global__ __launch_bounds__(256) void attn_split(const bf16_t* __restrict__ qh,
                                                  const bf16_t* __restrict__ ql,
                                                  float* __restrict__ o)
{
    __shared__ __align__(16) bf16_t KhS[2][64 * 72], KlS[2][64 * 72];
    __shared__ __align__(16) bf16_t VhS[2][64 * 72], VlS[2][64 * 72];
    __shared__ __align__(16) bf16_t PhS[4][2][16 * 72], PlS[4][2][16 * 72];
    const int pr = blockIdx.x, h = blockIdx.y, b = blockIdx.z;
    const int t = threadIdx.x, wid = t >> 6, lane = t & 63, l15 = lane & 15, lg = lane >> 4;
    const int krow = t >> 2, kdc = (t & 3) * 16;
    const int vk = t & 63, vdg = (t >> 6) * 16;
    const long kvb = (long)(b * NSEQ) * 3072 + 1024 + h * 64;
    const f32x4 zf = {0.f, 0.f, 0.f, 0.f};

    for (int half = 0; half < 2; half++) {
        const int qt = half ? (15 - pr) : pr;
        const int nkb = 2 * qt + 2;
        // Q fragments, two row-groups (rows wid*16.. and 64+wid*16..)
        const long qo0 = (long)(b * NSEQ + qt * 128 + wid * 16 + l15) * 3072 + h * 64 + lg * 8;
        const long qo1 = qo0 + (long)64 * 3072;
        bf16x8 q0h0 = *(const bf16x8*)(qh + qo0), q0h1 = *(const bf16x8*)(qh + qo0 + 32);
        bf16x8 q0l0 = *(const bf16x8*)(ql + qo0), q0l1 = *(const bf16x8*)(ql + qo0 + 32);
        bf16x8 q1h0 = *(const bf16x8*)(qh + qo1), q1h1 = *(const bf16x8*)(qh + qo1 + 32);
        bf16x8 q1l0 = *(const bf16x8*)(ql + qo1), q1l1 = *(const bf16x8*)(ql + qo1 + 32);

        f32x4 O0[4], O1[4];
        float m0r[4], l0r[4], m1r[4], l1r[4];
#pragma unroll
        for (int r = 0; r < 4; r++) {
            O0[r] = zf; O1[r] = zf;
            m0r[r] = -1e30f; l0r[r] = 0.f; m1r[r] = -1e30f; l1r[r] = 0.f;
        }

        // staging registers
        bf16x8 skh0, skh1, skl0, skl1, svh0, svh1, svl0, svl1;
        auto LOADKV = [&](int kb) {
            long ko = kvb + (long)(kb * 64 + krow) * 3072 + kdc;
            skh0 = *(const bf16x8*)(qh + ko); skh1 = *(const bf16x8*)(qh + ko + 8);
            skl0 = *(const bf16x8*)(ql + ko); skl1 = *(const bf16x8*)(ql + ko + 8);
            long vo = kvb + 1024 + (long)(kb * 64 + vk) * 3072 + vdg;
            svh0 = *(const bf16x8*)(qh + vo); svh1 = *(const bf16x8*)(qh + vo + 8);
            svl0 = *(const bf16x8*)(ql + vo); svl1 = *(const bf16x8*)(ql + vo + 8);
        };
        auto WRITEKV = [&](int buf) {
            *(bf16x8*)&KhS[buf][krow * 72 + kdc]     = skh0;
            *(bf16x8*)&KhS[buf][krow * 72 + kdc + 8] = skh1;
            *(bf16x8*)&KlS[buf][krow * 72 + kdc]     = skl0;
            *(bf16x8*)&KlS[buf][krow * 72 + kdc + 8] = skl1;
#pragma unroll
            for (int i = 0; i < 8; i++) {
                VhS[buf][(vdg + i) * 72 + vk]     = svh0[i];
                VhS[buf][(vdg + 8 + i) * 72 + vk] = svh1[i];
                VlS[buf][(vdg + i) * 72 + vk]     = svl0[i];
                VlS[buf][(vdg + 8 + i) * 72 + vk] = svl1[i];
            }
        };

        LOADKV(0);
        WRITEKV(0);
        __syncthreads();
        int cur = 0;
        for (int kb = 0; kb < nkb; kb++) {
            const bool more = (kb + 1 < nkb);
            if (more) LOADKV(kb + 1);
            const bool g0a = (kb < nkb - 1);   // group0 (rows 0-63) sees kb <= 2qt
            const bf16_t* Khc = KhS[cur];
            const bf16_t* Klc = KlS[cur];
            const bf16_t* Vhc = VhS[cur];
            const bf16_t* Vlc = VlS[cur];
            // ---- S = Q K^T (K frags shared between both row-groups) ----
            f32x4 s0[4], s1[4];
#pragma unroll
            for (int ks = 0; ks < 4; ks++) {
                int base = (ks * 16 + l15) * 72 + lg * 8;
                bf16x8 kh0 = *(const bf16x8*)&Khc[base];
                bf16x8 kh1 = *(const bf16x8*)&Khc[base + 32];
                bf16x8 kl0 = *(const bf16x8*)&Klc[base];
                bf16x8 kl1 = *(const bf16x8*)&Klc[base + 32];
                f32x4 a = zf;
                a = __builtin_amdgcn_mfma_f32_16x16x32_bf16(q1h0, kh0, a, 0, 0, 0);
                a = __builtin_amdgcn_mfma_f32_16x16x32_bf16(q1h1, kh1, a, 0, 0, 0);
                a = __builtin_amdgcn_mfma_f32_16x16x32_bf16(q1h0, kl0, a, 0, 0, 0);
                a = __builtin_amdgcn_mfma_f32_16x16x32_bf16(q1h1, kl1, a, 0, 0, 0);
                a = __builtin_amdgcn_mfma_f32_16x16x32_bf16(q1l0, kh0, a, 0, 0, 0);
                a = __builtin_amdgcn_mfma_f32_16x16x32_bf16(q1l1, kh1, a, 0, 0, 0);
                s1[ks] = a;
                f32x4 c = zf;
                if (g0a) {
                    c = __builtin_amdgcn_mfma_f32_16x16x32_bf16(q0h0, kh0, c, 0, 0, 0);
                    c = __builtin_amdgcn_mfma_f32_16x16x32_bf16(q0h1, kh1, c, 0, 0, 0);
                    c = __builtin_amdgcn_mfma_f32_16x16x32_bf16(q0h0, kl0, c, 0, 0, 0);
                    c = __builtin_amdgcn_mfma_f32_16x16x32_bf16(q0h1, kl1, c, 0, 0, 0);
                    c = __builtin_amdgcn_mfma_f32_16x16x32_bf16(q0l0, kh0, c, 0, 0, 0);
                    c = __builtin_amdgcn_mfma_f32_16x16x32_bf16(q0l1, kh1, c, 0, 0, 0);
                }
                s0[ks] = c;
            }
            // ---- online softmax + P store, group1 (always active) ----
            {
                float alpha[4];
#pragma unroll
                for (int r = 0; r < 4; r++) {
                    float mt = fmaxf(fmaxf(s1[0][r], s1[1][r]), fmaxf(s1[2][r], s1[3][r]));
#pragma unroll
                    for (int m = 1; m < 16; m <<= 1) mt = fmaxf(mt, __shfl_xor(mt, m));
                    float mn = fmaxf(m1r[r], mt);
                    alpha[r] = __expf(m1r[r] - mn);
                    m1r[r] = mn;
                }
                float ladd[4] = {0.f, 0.f, 0.f, 0.f};
#pragma unroll
                for (int ks = 0; ks < 4; ks++)
#pragma unroll
                    for (int r = 0; r < 4; r++) {
                        float p = __expf(s1[ks][r] - m1r[r]);
                        s1[ks][r] = p;
                        ladd[r] += p;
                    }
#pragma unroll
                for (int r = 0; r < 4; r++) {
#pragma unroll
                    for (int m = 1; m < 16; m <<= 1) ladd[r] += __shfl_xor(ladd[r], m);
                    l1r[r] = l1r[r] * alpha[r] + ladd[r];
                }
#pragma unroll
                for (int sb = 0; sb < 4; sb++)
#pragma unroll
                    for (int r = 0; r < 4; r++) O1[sb][r] *= alpha[r];
                bf16_t* pwh = &PhS[wid][1][0];
                bf16_t* pwl = &PlS[wid][1][0];
#pragma unroll
                for (int ks = 0; ks < 4; ks++)
#pragma unroll
                    for (int r = 0; r < 4; r++) {
                        hl_t pv = split1(s1[ks][r]);
                        pwh[(lg * 4 + r) * 72 + ks * 16 + l15] = pv.h;
                        pwl[(lg * 4 + r) * 72 + ks * 16 + l15] = pv.l;
                    }
            }
            // ---- softmax + P store, group0 ----
            if (g0a) {
                float alpha[4];
#pragma unroll
                for (int r = 0; r < 4; r++) {
                    float mt = fmaxf(fmaxf(s0[0][r], s0[1][r]), fmaxf(s0[2][r], s0[3][r]));
#pragma unroll
                    for (int m = 1; m < 16; m <<= 1) mt = fmaxf(mt, __shfl_xor(mt, m));
                    float mn = fmaxf(m0r[r], mt);
                    alpha[r] = __expf(m0r[r] - mn);
                    m0r[r] = mn;
                }
                float ladd[4] = {0.f, 0.f, 0.f, 0.f};
#pragma unroll
                for (int ks = 0; ks < 4; ks++)
#pragma unroll
                    for (int r = 0; r < 4; r++) {
                        float p = __expf(s0[ks][r] - m0r[r]);
                        s0[ks][r] = p;
                        ladd[r] += p;
                    }
#pragma unroll
                for (int r = 0; r < 4; r++) {
#pragma unroll
                    for (int m = 1; m < 16; m <<= 1) ladd[r] += __shfl_xor(ladd[r], m);
                    l0r[r] = l0r[r] * alpha[r] + ladd[r];
                }
#pragma unroll
                for (int sb = 0; sb < 4; sb++)
#pragma unroll
                    for (int r = 0; r < 4; r++) O0[sb][r] *= alpha[r];
                bf16_t* pwh = &PhS[wid][0][0];
                bf16_t* pwl = &PlS[wid][0][0];
#pragma unroll
                for (int ks = 0; ks < 4; ks++)
#pragma unroll
                    for (int r = 0; r < 4; r++) {
                        hl_t pv = split1(s0[ks][r]);
                        pwh[(lg * 4 + r) * 72 + ks * 16 + l15] = pv.h;
                        pwl[(lg * 4 + r) * 72 + ks * 16 + l15] = pv.l;
                    }
            }
            // ---- O += P V (V frags shared between both row-groups) ----
#pragma unroll
            for (int kst = 0; kst < 2; kst++) {
                bf16x8 pf1h = *(const bf16x8*)&PhS[wid][1][l15 * 72 + kst * 32 + lg * 8];
                bf16x8 pf1l = *(const bf16x8*)&PlS[wid][1][l15 * 72 + kst * 32 + lg * 8];
                bf16x8 pf0h, pf0l;
                if (g0a) {
                    pf0h = *(const bf16x8*)&PhS[wid][0][l15 * 72 + kst * 32 + lg * 8];
                    pf0l = *(const bf16x8*)&PlS[wid][0][l15 * 72 + kst * 32 + lg * 8];
                }
#pragma unroll
                for (int sb = 0; sb < 4; sb++) {
                    int base = (sb * 16 + l15) * 72 + kst * 32 + lg * 8;
                    bf16x8 vfh = *(const bf16x8*)&Vhc[base];
                    bf16x8 vfl = *(const bf16x8*)&Vlc[base];
                    O1[sb] = __builtin_amdgcn_mfma_f32_16x16x32_bf16(pf1h, vfh, O1[sb], 0, 0, 0);
                    O1[sb] = __builtin_amdgcn_mfma_f32_16x16x32_bf16(pf1h, vfl, O1[sb], 0, 0, 0);
                    O1[sb] = __builtin_amdgcn_mfma_f32_16x16x32_bf16(pf1l, vfh, O1[sb], 0, 0, 0);
                    if (g0a) {
                        O0[sb] = __builtin_amdgcn_mfma_f32_16x16x32_bf16(pf0h, vfh, O0[sb], 0, 0, 0);
                        O0[sb] = __builtin_amdgcn_mfma_f32_16x16x32_bf16(pf0h, vfl, O0[sb], 0, 0, 0);
                        O0[sb] = __builtin_amdgcn_mfma_f32_16x16x32_bf16(pf0l, vfh, O0[sb], 0, 0, 0);
                    }
                }
            }
            if (more) WRITEKV(cur ^ 1);
            __syncthreads();
            cur ^= 1;
        }
        // ---- write O, both groups ----
#pragma unroll
        for (int sb = 0; sb < 4; sb++)
#pragma unroll
            for (int r = 0; r < 4; r++) {
                int qg0 = qt * 128 + wid * 16 + lg * 4 + r;
                int col = h * 64 + sb * 16 + l15;
                o[(long)(b * NSEQ + qg0) * 1024 + col] = O0[sb][r] / l0r[r];
                o[(long)(b * NSEQ + qg0 + 64) * 1024 + col] = O1[sb][r] / l1r[r];
            }
    }
}

// ---------------------------------------------------------------------------
__global__ __launch_bounds__(256) void rmsnorm_kernel(const float* __restrict__ y,
                                                      const float* __restrict__ gamma,
                                                      float* __restrict__ moe)
{
    long base = (long)blockIdx.x * 1024;
    float4 v = ((const float4*)(y + base))[threadIdx.x];
    float ss = v.x * v.x + v.y * v.y + v.z * v.z + v.w * v.w;
#pragma unroll
    for (int m = 32; m; m >>= 1) ss += __shfl_xor(ss, m);
    __shared__ float ls[4];
    if ((threadIdx.x & 63) == 0) ls[threadIdx.x >> 6] = ss;
    __syncthreads();
    float tot = ls[0] + ls[1] + ls[2] + ls[3];
    float sc = 32.0f / fmaxf(sqrtf(tot), 1e-12f);
    float4 g = ((const float4*)gamma)[threadIdx.x];
    float4 ov;
    ov.x = v.x * sc * g.x; ov.y = v.y * sc * g.y; ov.z = v.z * sc * g.z; ov.w = v.w * sc * g.w;
    ((float4*)(moe + base))[threadIdx.x] = ov;
}

// ---------------------------------------------------------------------------
// Gating. Top-2 on raw f32 logits; exact logistic gates; aux accums.
// ---------------------------------------------------------------------------
__global__ __launch_bounds__(256) void gating_kernel(
    const float* __restrict__ moe, const float* __restrict__ gw,
    const float* __restrict__ runif, uint32* __restrict__ tokpack,
    float* __restrict__ tokg, float* __restrict__ acc)
{
    const int wid = threadIdx.x >> 6, lane = threadIdx.x & 63;
    const int tk = blockIdx.x * 4 + wid;
    const int b = tk >> 11, n = tk & 2047;
    float xv[16];
    const float4* xr4 = (const float4*)(moe + (long)tk * 1024 + lane * 16);
#pragma unroll
    for (int i = 0; i < 4; i++) {
        float4 v = xr4[i];
        xv[4 * i] = v.x; xv[4 * i + 1] = v.y; xv[4 * i + 2] = v.z; xv[4 * i + 3] = v.w;
    }
    float logit[16];
#pragma unroll
    for (int e = 0; e < 16; e++) {
        const float4* wr4 = (const float4*)(gw + e * 1024 + lane * 16);
        float p = 0.f;
#pragma unroll
        for (int i = 0; i < 4; i++) {
            float4 w = wr4[i];
            p = fmaf(xv[4 * i], w.x, p);     p = fmaf(xv[4 * i + 1], w.y, p);
            p = fmaf(xv[4 * i + 2], w.z, p); p = fmaf(xv[4 * i + 3], w.w, p);
        }
#pragma unroll
        for (int m = 1; m < 64; m <<= 1) p += __shfl_xor(p, m);
        logit[e] = p;
    }
    int e0 = 0; float t0 = logit[0];
#pragma unroll
    for (int e = 1; e < 16; e++) if (logit[e] > t0) { t0 = logit[e]; e0 = e; }
    int e1 = (e0 == 0) ? 1 : 0; float t1 = logit[e1];
#pragma unroll
    for (int e = 0; e < 16; e++) if (e != e0 && logit[e] > t1) { t1 = logit[e]; e1 = e; }
    float g0n = 1.f / (1.f + __expf(t1 - t0));
    float g1n = 1.f / (1.f + __expf(t0 - t1));
    int sr1 = (runif[(long)(BSZ + b) * NSEQ + n] < g1n / 0.2f) ? 1 : 0;
    float mx = t0, sum = 0.f, raw[16];
#pragma unroll
    for (int e = 0; e < 16; e++) { raw[e] = __expf(logit[e] - mx); sum += raw[e]; }
    float inv = 1.f / sum;
    float lse = mx + __logf(sum);
    if (lane == 0) {
        tokpack[tk] = (uint32)e0 | ((uint32)e1 << 4) | ((uint32)sr1 << 8);
        tokg[2 * tk] = g0n; tokg[2 * tk + 1] = g1n;
        atomicAdd(&acc[32 + b * 16 + e0], 1.0f);
        atomicAdd(&acc[64], lse * lse);
    }
    if (lane < 16) atomicAdd(&acc[b * 16 + lane], raw[lane] * inv);
}

// ---------------------------------------------------------------------------
// Parallel position scan. One block per batch, 512 threads x 4 tokens.
// ---------------------------------------------------------------------------
__global__ __launch_bounds__(512) void scan_kernel(const uint32* __restrict__ tokpack,
                                                   uint32* __restrict__ r0,
                                                   uint32* __restrict__ r1,
                                                   int* __restrict__ prev)
{
    const int b = blockIdx.x, t = threadIdx.x;
    const int wv = t >> 6, lane = t & 63;
    uint32 toks[4];
    *(uint4*)toks = ((const uint4*)(tokpack + b * NSEQ))[t];

    uint32 c0[8], c1[8];
#pragma unroll
    for (int j = 0; j < 8; j++) { c0[j] = 0u; c1[j] = 0u; }
#pragma unroll
    for (int i = 0; i < 4; i++) {
        uint32 p = toks[i];
        uint32 e0 = p & 15, e1 = (p >> 4) & 15, sr1 = (p >> 8) & 1;
        uint32 inc0 = 1u << ((e0 & 1) * 16);
        uint32 inc1 = sr1 << ((e1 & 1) * 16);
#pragma unroll
        for (int j = 0; j < 8; j++) {
            c0[j] += ((e0 >> 1) == (uint32)j) ? inc0 : 0u;
            c1[j] += ((e1 >> 1) == (uint32)j) ? inc1 : 0u;
        }
    }
    uint32 i0[8], i1[8];
#pragma unroll
    for (int j = 0; j < 8; j++) { i0[j] = c0[j]; i1[j] = c1[j]; }
#pragma unroll
    for (int off = 1; off < 64; off <<= 1) {
#pragma unroll
        for (int j = 0; j < 8; j++) {
            uint32 u0 = __shfl_up(i0[j], off);
            uint32 u1 = __shfl_up(i1[j], off);
            if (lane >= off) { i0[j] += u0; i1[j] += u1; }
        }
    }
    __shared__ uint32 wsum0[8][8], wsum1[8][8];
    if (lane == 63) {
#pragma unroll
        for (int j = 0; j < 8; j++) { wsum0[wv][j] = i0[j]; wsum1[wv][j] = i1[j]; }
    }
    __syncthreads();
    uint32 b0[8], b1[8];
#pragma unroll
    for (int j = 0; j < 8; j++) {
        uint32 s0 = 0u, s1 = 0u;
#pragma unroll
        for (int w = 0; w < 8; w++) {
            s0 += (w < wv) ? wsum0[w][j] : 0u;
            s1 += (w < wv) ? wsum1[w][j] : 0u;
        }
        b0[j] = s0 + i0[j] - c0[j];
        b1[j] = s1 + i1[j] - c1[j];
    }
    if (t == 0) {
#pragma unroll
        for (int j = 0; j < 8; j++) {
            uint32 tot = 0u;
#pragma unroll
            for (int w = 0; w < 8; w++) tot += wsum0[w][j];
            int tlo = (int)(tot & 0xffffu), thi = (int)(tot >> 16);
            prev[b * 16 + 2 * j]     = tlo < CAPC ? tlo : CAPC;
            prev[b * 16 + 2 * j + 1] = thi < CAPC ? thi : CAPC;
        }
    }
    uint32* rr0 = r0 + b * NSEQ + t * 4;
    uint32* rr1 = r1 + b * NSEQ + t * 4;
#pragma unroll
    for (int i = 0; i < 4; i++) {
        uint32 p = toks[i];
        uint32 e0 = p & 15, e1 = (p >> 4) & 15, sr1 = (p >> 8) & 1;
        uint32 sh0 = (e0 & 1) * 16, sh1 = (e1 & 1) * 16;
        uint32 w0 = 0u, w1 = 0u;
#pragma unroll
        for (int j = 0; j < 8; j++) {
            w0 += ((e0 >> 1) == (uint32)j) ? b0[j] : 0u;
            w1 += ((e1 >> 1) == (uint32)j) ? b1[j] : 0u;
        }
        uint32 s0 = (w0 >> sh0) & 0xffffu;
        uint32 s1v = (w1 >> sh1) & 0xffffu;
        uint32 kept = (s0 < CAPC) ? 1u : 0u;
        rr0[i] = e0 | (kept << 4) | (s0 << 5);
        rr1[i] = e1 | (sr1 << 4) | (s1v << 5);
        uint32 inc0 = 1u << sh0;
        uint32 inc1 = sr1 << sh1;
#pragma unroll
        for (int j = 0; j < 8; j++) {
            b0[j] += ((e0 >> 1) == (uint32)j) ? inc0 : 0u;
            b1[j] += ((e1 >> 1) == (uint32)j) ? inc1 : 0u;
        }
    }
}

// ---------------------------------------------------------------------------
__global__ __launch_bounds__(256) void gather_kernel(
    const float* __restrict__ moe, const uint32* __restrict__ r0,
    const uint32* __restrict__ r1, const int* __restrict__ prev,
    float* __restrict__ ein)
{
    int tk = blockIdx.x, b = tk >> 11;
    float4 v = ((const float4*)(moe + (long)tk * 1024))[threadIdx.x];
    uint32 a = r0[tk];
    if ((a >> 4) & 1) {
        long row = ((long)(a & 15) * 2 + b) * CAPC + (int)(a >> 5);
        ((float4*)(ein + row * 1024))[threadIdx.x] = v;
    }
    uint32 c = r1[tk];
    {
        int e = c & 15, sr1 = (c >> 4) & 1;
        int slot = (int)(c >> 5) + prev[b * 16 + e];
        if (sr1 && slot < CAPC) {
            long row = ((long)e * 2 + b) * CAPC + slot;
            ((float4*)(ein + row * 1024))[threadIdx.x] = v;
        }
    }
}

// ---------------------------------------------------------------------------
__global__ __launch_bounds__(256) void expert_ln_kernel(
    const float* __restrict__ ein, const float* __restrict__ g,
    const float* __restrict__ bb, bf16_t* __restrict__ eout)
{
    int row = blockIdx.x, e = row / (BSZ * CAPC);
    long base = (long)row * 1024;
    float4 v = ((const float4*)(ein + base))[threadIdx.x];
    float s = v.x + v.y + v.z + v.w;
    float ss = v.x * v.x + v.y * v.y + v.z * v.z + v.w * v.w;
#pragma unroll
    for (int m = 32; m; m >>= 1) { s += __shfl_xor(s, m); ss += __shfl_xor(ss, m); }
    __shared__ float l1[4], l2[4];
    if ((threadIdx.x & 63) == 0) { l1[threadIdx.x >> 6] = s; l2[threadIdx.x >> 6] = ss; }
    __syncthreads();
    float st = l1[0] + l1[1] + l1[2] + l1[3];
    float sst = l2[0] + l2[1] + l2[2] + l2[3];
    float mu = st * (1.f / 1024.f);
    float var = sst * (1.f / 1024.f) - mu * mu;
    float rstd = rsqrtf(var + 1e-5f);
    int d = threadIdx.x * 4;
    float4 gg = *(const float4*)(g + e * 1024 + d);
    float4 bv = *(const float4*)(bb + e * 1024 + d);
    bf16x4 ov;
    ov[0] = (bf16_t)((v.x - mu) * rstd * gg.x + bv.x);
    ov[1] = (bf16_t)((v.y - mu) * rstd * gg.y + bv.y);
    ov[2] = (bf16_t)((v.z - mu) * rstd * gg.z + bv.z);
    ov[3] = (bf16_t)((v.w - mu) * rstd * gg.w + bv.w);
    *(bf16x4*)(eout + base + d) = ov;
}

// ---------------------------------------------------------------------------
__global__ __launch_bounds__(256) void combine_kernel(
    const float* __restrict__ y, const float* __restrict__ eout,
    const uint32* __restrict__ r0, const uint32* __restrict__ r1,
    const float* __restrict__ tokg, const int* __restrict__ prev,
    float* __restrict__ out)
{
    int tk = blockIdx.x, b = tk >> 11;
    uint32 a = r0[tk], c = r1[tk];
    int k0f = (a >> 4) & 1;
    float w0 = k0f ? tokg[2 * tk] : 0.f;
    long row0 = ((long)(a & 15) * 2 + b) * CAPC + (int)(a >> 5);
    int e1 = c & 15;
    int slot1 = (int)(c >> 5) + prev[b * 16 + e1];
    int k1f = (((c >> 4) & 1) && slot1 < CAPC) ? 1 : 0;
    float w1 = k1f ? tokg[2 * tk + 1] : 0.f;
    long row1 = ((long)e1 * 2 + b) * CAPC + slot1;
    int i = threadIdx.x;
    float4 vy = ((const float4*)(y + (long)tk * 1024))[i];
    float4 a0 = {0.f, 0.f, 0.f, 0.f}, a1 = {0.f, 0.f, 0.f, 0.f};
    if (k0f) a0 = ((const float4*)(eout + row0 * 1024))[i];
    if (k1f) a1 = ((const float4*)(eout + row1 * 1024))[i];
    float4 ov;
    ov.x = vy.x + w0 * a0.x + w1 * a1.x;
    ov.y = vy.y + w0 * a0.y + w1 * a1.y;
    ov.z = vy.z + w0 * a0.z + w1 * a1.z;
    ov.w = vy.w + w0 * a0.w + w1 * a1.w;
    ((float4*)(out + (long)tk * 1024))[i] = ov;
}

__global__ void zero_acc_kernel(float* acc)
{
    if (threadIdx.x < 65) acc[threadIdx.x] = 0.f;
}

__global__ void finalize_kernel(const float* __restrict__ acc, float* __restrict__ tail)
{
    int t = threadIdx.x;
    float v = (t < 32) ? acc[t] * acc[32 + t] : 0.f;
#pragma unroll
    for (int m = 1; m < 64; m <<= 1) v += __shfl_xor(v, m);
    if (t == 0) {
        float bal = v * (8.0f / (2048.f * 2048.f));
        float z = acc[64] / 4096.f;
        tail[0] = 0.01f * bal + 0.001f * z;
        tail[1] = bal;
        tail[2] = z;
    }
}

// ---------------------------------------------------------------------------
extern "C" void kernel_launch(void* const* d_in, const int* in_sizes, int n_in,
                              void* d_out, int out_size, void* d_ws, size_t ws_size,
                              hipStream_t stream)
{
    (void)in_sizes; (void)n_in; (void)out_size; (void)ws_size;
    const float* x     = (const float*)d_in[0];
    // d_in[1] = attn_mask: block-causal, computed analytically; never read.
    const float* in_w  = (const float*)d_in[2];
    const float* in_b  = (const float*)d_in[3];
    const float* out_w = (const float*)d_in[4];
    const float* out_b = (const float*)d_in[5];
    const float* rg    = (const float*)d_in[6];
    const float* gw    = (const float*)d_in[7];
    const float* lng   = (const float*)d_in[8];
    const float* lnb   = (const float*)d_in[9];
    const float* w1    = (const float*)d_in[10];
    const float* b1    = (const float*)d_in[11];
    const float* w2    = (const float*)d_in[12];
    const float* b2    = (const float*)d_in[13];
    const float* runif = (const float*)d_in[14];
    float* out = (float*)d_out;

    size_t off = 0;
    char* wsb = (char*)d_ws;
    auto take = [&](size_t bytes) -> char* {
        char* p = wsb + off;
        off += (bytes + 255) & ~(size_t)255;
        return p;
    };
    bf16_t* qkvh = (bf16_t*)take((size_t)NTOK * 3072 * 2);   // 25.2 MB
    bf16_t* qkvl = (bf16_t*)take((size_t)NTOK * 3072 * 2);   // 25.2 MB
    float*  obuf = (float*)take((size_t)NTOK * 1024 * 4);
    float*  ybuf = (float*)take((size_t)NTOK * 1024 * 4);
    float*  moe  = (float*)take((size_t)NTOK * 1024 * 4);
    bf16_t* eln  = (bf16_t*)take((size_t)NEXP * BSZ * CAPC * 1024 * 2);
    bf16_t* hbuf = (bf16_t*)take((size_t)NEXP * BSZ * CAPC * HFF_P * 2);
    uint32* tokpack = (uint32*)take(NTOK * 4);
    float*  tokg = (float*)take(NTOK * 8);
    uint32* r0   = (uint32*)take(NTOK * 4);
    uint32* r1   = (uint32*)take(NTOK * 4);
    int*    prev = (int*)take(128);
    float*  acc  = (float*)take(1024);
    // aliases: qkv hi/lo are dead after attention
    float*  ein  = (float*)qkvl;   // 21.0 MB <= 25.2
    float*  eoutv = (float*)qkvh;  // 21.0 MB <= 25.2

    zero_acc_kernel<<<1, 128, 0, stream>>>(acc);

    // QKV = x @ in_proj_w^T + b  (split precision); Q cols pre-scaled 1/8
    gemm_split<0, 1><<<dim3(24, 32), 256, 0, stream>>>(
        x, in_w, in_b, nullptr, qkvh, qkvl, nullptr,
        NTOK, 3072, 1024, 1024, 0.125f);

    attn_split<<<dim3(8, 16, 2), 256, 0, stream>>>(qkvh, qkvl, obuf);

    // y = o @ out_proj_w^T + b + x  (split precision, f32 out)
    gemm_split<2, 0><<<dim3(8, 32), 256, 0, stream>>>(
        obuf, out_w, out_b, x, nullptr, nullptr, ybuf,
        NTOK, 1024, 1024, 0, 1.0f);

    rmsnorm_kernel<<<NTOK, 256, 0, stream>>>(ybuf, rg, moe);
    gating_kernel<<<NTOK / 4, 256, 0, stream>>>(moe, gw, runif, tokpack, tokg, acc);
    scan_kernel<<<dim3(BSZ), 512, 0, stream>>>(tokpack, r0, r1, prev);
    gather_kernel<<<NTOK, 256, 0, stream>>>(moe, r0, r1, prev, ein);
    expert_ln_kernel<<<NEXP * BSZ * CAPC, 256, 0, stream>>>(ein, lng, lnb, eln);

    // h = LeakyReLU(LN @ w1^T + b1) -> bf16, padded cols [2730,2752) zeroed
    gemm_nt<1, 1><<<dim3(22, 3, 16), 256, 0, stream>>>(
        eln, w1, b1, hbuf, 320, HFF_R, HFF_P, 1024, 1024,
        (long)320 * 1024, (long)HFF_R * 1024, HFF_R, (long)320 * HFF_P, HFF_P);

    // expert_out = h @ w2^T + b2 -> f32
    gemm_nt<0, 0><<<dim3(8, 3, 16), 256, 0, stream>>>(
        hbuf, w2, b2, eoutv, 320, 1024, 1024, HFF_P, HFF_R,
        (long)320 * HFF_P, (long)1024 * HFF_R, 1024, (long)320 * 1024, 1024);

    combine_kernel<<<NTOK, 256, 0, stream>>>(ybuf, eoutv, r0, r1, tokg, prev, out);
    finalize_kernel<<<1, 64, 0, stream>>>(acc, out + (size_t)NTOK * 1024);
}

// Round 7
// 749.777 us; speedup vs baseline: 1.9215x; 1.0377x over previous
//
#include <hip/hip_runtime.h>
#include <hip/hip_bf16.h>
#include <cstdint>

#define NSEQ  2048
#define BSZ   2
#define NTOK  4096          // B*N
#define EDIM  1024
#define NEXP  16
#define CAPC  160
#define HFF_R 2730
#define HFF_P 2752          // padded to multiple of 64

typedef __bf16 bf16_t;
typedef __bf16 bf16x8 __attribute__((ext_vector_type(8)));
typedef __bf16 bf16x4 __attribute__((ext_vector_type(4)));
typedef float  f32x4  __attribute__((ext_vector_type(4)));
typedef unsigned int uint32;

__device__ inline bf16x8 zero8() {
    bf16x8 v;
#pragma unroll
    for (int i = 0; i < 8; i++) v[i] = (bf16_t)0.f;
    return v;
}
__device__ inline bf16x8 pack8(float4 a, float4 b) {
    bf16x8 v;
    v[0]=(bf16_t)a.x; v[1]=(bf16_t)a.y; v[2]=(bf16_t)a.z; v[3]=(bf16_t)a.w;
    v[4]=(bf16_t)b.x; v[5]=(bf16_t)b.y; v[6]=(bf16_t)b.z; v[7]=(bf16_t)b.w;
    return v;
}
struct hl_t { bf16_t h, l; };
__device__ inline hl_t split1(float f) {
    hl_t r;
    r.h = (bf16_t)f;
    r.l = (bf16_t)(f - (float)r.h);
    return r;
}

// ---------------------------------------------------------------------------
// Split-precision NT GEMM: C[M,N] = epi(A * B^T + bias), A,B f32.
// hi*hi + hi*lo + lo*hi -> ~2^-18 relative error. BM=BN=128, BK=32.
// ---------------------------------------------------------------------------
template <int EPI, int C_SPLIT>
__global__ __launch_bounds__(256) void gemm_split(
    const float* __restrict__ A, const float* __restrict__ Bw,
    const float* __restrict__ bias, const float* __restrict__ resid,
    bf16_t* __restrict__ Chi, bf16_t* __restrict__ Clo, float* __restrict__ Cf,
    int M, int N, int K, int scale_cut, float scale_val)
{
    __shared__ __align__(16) bf16_t Ah[128 * 40], Al[128 * 40];
    __shared__ __align__(16) bf16_t Bh[128 * 40], Bl[128 * 40];
    const int t = threadIdx.x;
    const int m0 = blockIdx.y * 128, n0 = blockIdx.x * 128;
    const int lane = t & 63, l15 = lane & 15, lg = lane >> 4;
    const int wid = t >> 6, wm = wid >> 1, wn = wid & 1;
    const int srow = t >> 1, skc = (t & 1) * 16;

    f32x4 acc[4][4];
    const f32x4 zf = {0.f, 0.f, 0.f, 0.f};
#pragma unroll
    for (int i = 0; i < 4; i++)
#pragma unroll
        for (int j = 0; j < 4; j++) acc[i][j] = zf;

    for (int k0 = 0; k0 < K; k0 += 32) {
        {
            float av[16];
            const float* ap = A + (long)(m0 + srow) * K + k0 + skc;
            *(float4*)&av[0]  = *(const float4*)ap;
            *(float4*)&av[4]  = *(const float4*)(ap + 4);
            *(float4*)&av[8]  = *(const float4*)(ap + 8);
            *(float4*)&av[12] = *(const float4*)(ap + 12);
            bf16x8 h0, h1, l0, l1;
#pragma unroll
            for (int i = 0; i < 8; i++) {
                hl_t a = split1(av[i]);      h0[i] = a.h; l0[i] = a.l;
                hl_t b = split1(av[8 + i]);  h1[i] = b.h; l1[i] = b.l;
            }
            *(bf16x8*)&Ah[srow * 40 + skc] = h0; *(bf16x8*)&Ah[srow * 40 + skc + 8] = h1;
            *(bf16x8*)&Al[srow * 40 + skc] = l0; *(bf16x8*)&Al[srow * 40 + skc + 8] = l1;
        }
        {
            float bv[16];
            const float* bp = Bw + (long)(n0 + srow) * K + k0 + skc;
            *(float4*)&bv[0]  = *(const float4*)bp;
            *(float4*)&bv[4]  = *(const float4*)(bp + 4);
            *(float4*)&bv[8]  = *(const float4*)(bp + 8);
            *(float4*)&bv[12] = *(const float4*)(bp + 12);
            bf16x8 h0, h1, l0, l1;
#pragma unroll
            for (int i = 0; i < 8; i++) {
                hl_t a = split1(bv[i]);      h0[i] = a.h; l0[i] = a.l;
                hl_t b = split1(bv[8 + i]);  h1[i] = b.h; l1[i] = b.l;
            }
            *(bf16x8*)&Bh[srow * 40 + skc] = h0; *(bf16x8*)&Bh[srow * 40 + skc + 8] = h1;
            *(bf16x8*)&Bl[srow * 40 + skc] = l0; *(bf16x8*)&Bl[srow * 40 + skc + 8] = l1;
        }
        __syncthreads();
        bf16x8 amh[4], aml[4], bnh[4], bnl[4];
#pragma unroll
        for (int i = 0; i < 4; i++) {
            int base = (wm * 64 + i * 16 + l15) * 40 + lg * 8;
            amh[i] = *(const bf16x8*)&Ah[base];
            aml[i] = *(const bf16x8*)&Al[base];
        }
#pragma unroll
        for (int j = 0; j < 4; j++) {
            int base = (wn * 64 + j * 16 + l15) * 40 + lg * 8;
            bnh[j] = *(const bf16x8*)&Bh[base];
            bnl[j] = *(const bf16x8*)&Bl[base];
        }
#pragma unroll
        for (int i = 0; i < 4; i++)
#pragma unroll
            for (int j = 0; j < 4; j++) {
                acc[i][j] = __builtin_amdgcn_mfma_f32_16x16x32_bf16(amh[i], bnh[j], acc[i][j], 0, 0, 0);
                acc[i][j] = __builtin_amdgcn_mfma_f32_16x16x32_bf16(amh[i], bnl[j], acc[i][j], 0, 0, 0);
                acc[i][j] = __builtin_amdgcn_mfma_f32_16x16x32_bf16(aml[i], bnh[j], acc[i][j], 0, 0, 0);
            }
        __syncthreads();
    }

#pragma unroll
    for (int i = 0; i < 4; i++) {
        int mgb = m0 + wm * 64 + i * 16 + lg * 4;
#pragma unroll
        for (int j = 0; j < 4; j++) {
            int ng = n0 + wn * 64 + j * 16 + l15;
            float bval = bias[ng];
#pragma unroll
            for (int r = 0; r < 4; r++) {
                int mg = mgb + r;
                float val = acc[i][j][r] + bval;
                if (scale_cut > 0 && ng < scale_cut) val *= scale_val;
                if (EPI == 2) val += resid[(long)mg * N + ng];
                long idx = (long)mg * N + ng;
                if (C_SPLIT) {
                    bf16_t hi = (bf16_t)val;
                    Chi[idx] = hi;
                    Clo[idx] = (bf16_t)(val - (float)hi);
                } else {
                    Cf[idx] = val;
                }
            }
        }
    }
}

// ---------------------------------------------------------------------------
// bf16 NT GEMM (expert FFN path, value-precision only).
// ---------------------------------------------------------------------------
template <int EPI, int C_BF16>
__global__ __launch_bounds__(256) void gemm_nt(
    const bf16_t* __restrict__ Av, const float* __restrict__ Bw,
    const float* __restrict__ bias, void* __restrict__ Cv,
    int M, int N, int Nwr, int KA, int KB,
    long sAe, long sBe, long sBiasE, long sCe, int ldc)
{
    __shared__ __align__(16) bf16_t Alds[128 * 40];
    __shared__ __align__(16) bf16_t Blds[128 * 40];
    const int t = threadIdx.x;
    const int e = blockIdx.z;
    const int m0 = blockIdx.y * 128, n0 = blockIdx.x * 128;
    const int lane = t & 63, l15 = lane & 15, lg = lane >> 4;
    const int wid = t >> 6, wm = wid >> 1, wn = wid & 1;
    const int srow = t >> 1, skc = (t & 1) * 16;

    f32x4 acc[4][4];
    const f32x4 zf = {0.f, 0.f, 0.f, 0.f};
#pragma unroll
    for (int i = 0; i < 4; i++)
#pragma unroll
        for (int j = 0; j < 4; j++) acc[i][j] = zf;

    for (int k0 = 0; k0 < KA; k0 += 32) {
        {
            int mg = m0 + srow;
            bf16x8 v0 = zero8(), v1 = zero8();
            if (mg < M) {
                const bf16_t* ap = Av + (long)e * sAe + (long)mg * KA + k0 + skc;
                v0 = *(const bf16x8*)ap;
                v1 = *(const bf16x8*)(ap + 8);
            }
            *(bf16x8*)&Alds[srow * 40 + skc] = v0;
            *(bf16x8*)&Alds[srow * 40 + skc + 8] = v1;
        }
        {
            int ng = n0 + srow;
            bf16x8 v0 = zero8(), v1 = zero8();
            if (ng < N) {
                const float* bp = Bw + (long)e * sBe + (long)ng * KB + k0 + skc;
                if (k0 + 32 <= KB) {
                    float4 a = *(const float4*)bp, b = *(const float4*)(bp + 4);
                    float4 c = *(const float4*)(bp + 8), d = *(const float4*)(bp + 12);
                    v0 = pack8(a, b); v1 = pack8(c, d);
                } else {
#pragma unroll
                    for (int i = 0; i < 8; i++) {
                        int kk = k0 + skc + i;
                        v0[i] = (kk < KB) ? (bf16_t)bp[i] : (bf16_t)0.f;
                    }
#pragma unroll
                    for (int i = 0; i < 8; i++) {
                        int kk = k0 + skc + 8 + i;
                        v1[i] = (kk < KB) ? (bf16_t)bp[8 + i] : (bf16_t)0.f;
                    }
                }
            }
            *(bf16x8*)&Blds[srow * 40 + skc] = v0;
            *(bf16x8*)&Blds[srow * 40 + skc + 8] = v1;
        }
        __syncthreads();
        bf16x8 am[4], bn[4];
#pragma unroll
        for (int i = 0; i < 4; i++)
            am[i] = *(const bf16x8*)&Alds[(wm * 64 + i * 16 + l15) * 40 + lg * 8];
#pragma unroll
        for (int i = 0; i < 4; i++)
            bn[i] = *(const bf16x8*)&Blds[(wn * 64 + i * 16 + l15) * 40 + lg * 8];
#pragma unroll
        for (int i = 0; i < 4; i++)
#pragma unroll
            for (int j = 0; j < 4; j++)
                acc[i][j] = __builtin_amdgcn_mfma_f32_16x16x32_bf16(am[i], bn[j], acc[i][j], 0, 0, 0);
        __syncthreads();
    }

    const float* biasp = bias + (long)e * sBiasE;
#pragma unroll
    for (int i = 0; i < 4; i++) {
        int mgb = m0 + wm * 64 + i * 16 + lg * 4;
#pragma unroll
        for (int j = 0; j < 4; j++) {
            int ng = n0 + wn * 64 + j * 16 + l15;
            if (ng < Nwr) {
                float bval = (ng < N) ? biasp[ng] : 0.f;
#pragma unroll
                for (int r = 0; r < 4; r++) {
                    int mg = mgb + r;
                    if (mg < M) {
                        float val = acc[i][j][r] + bval;
                        if (EPI == 1) val = (val >= 0.f) ? val : 0.01f * val;
                        if (ng >= N) val = 0.f;
                        long cidx = (long)e * sCe + (long)mg * ldc + ng;
                        if (C_BF16) ((bf16_t*)Cv)[cidx] = (bf16_t)val;
                        else        ((float*)Cv)[cidx] = val;
                    }
                }
            }
        }
    }
}

// ---------------------------------------------------------------------------
// Split-precision flash attention.
// 512 one-q-tile blocks x 256 threads (4 waves x 2 row-groups = 128 q rows).
// Single-buffered K/V (73.7 KB LDS -> 2 blocks/CU = 2 waves/SIMD from
// INDEPENDENT blocks). Block-id swizzle: (a) co-resident blocks (id, id+256)
// get complementary q-tiles -> every CU does 36 iteration-units; (b) each
// XCD sees only 4 (h,b) combos -> K/V re-reads hit its 4 MB L2.
// Block-causal analytic; Q pre-scaled 1/8 in QKV epilogue.
// ---------------------------------------------------------------------------
__global__ __launch_bounds__(256) void attn_split(const bf16_t* __restrict__ qh,
                                                  const bf16_t* __restrict__ ql,
                                                  float* __restrict__ o)
{
    __shared__ __align__(16) bf16_t KhS[64 * 72], KlS[64 * 72];
    __shared__ __align__(16) bf16_t VhS[64 * 72], VlS[64 * 72];   // transposed [d][key]
    __shared__ __align__(16) bf16_t PhS[4][2][16 * 72], PlS[4][2][16 * 72];

    // swizzled decode: id -> (qt, h, b)
    const int id = blockIdx.x;
    const int x  = id & 7;            // XCD slot
    const int s  = id >> 3;           // 0..63
    const int b  = s >> 5;            // batch
    const int s5 = s & 31;
    const int qraw = s5 & 15;
    const int h  = x + 8 * (s5 >> 4); // 4 (h,b) combos per XCD
    const int qt = b ? (15 - qraw) : qraw;  // complementary pairing on a CU
    const int nkb = 2 * qt + 2;

    const int t = threadIdx.x, wid = t >> 6, lane = t & 63, l15 = lane & 15, lg = lane >> 4;
    const int krow = t >> 2, kdc = (t & 3) * 16;
    const int vk = t & 63, vdg = (t >> 6) * 16;
    const long kvb = (long)(b * NSEQ) * 3072 + 1024 + h * 64;
    const f32x4 zf = {0.f, 0.f, 0.f, 0.f};

    // Q fragments, two row-groups (rows qt*128 + wid*16.. and +64)
    const long qo0 = (long)(b * NSEQ + qt * 128 + wid * 16 + l15) * 3072 + h * 64 + lg * 8;
    const long qo1 = qo0 + (long)64 * 3072;
    bf16x8 q0h0 = *(const bf16x8*)(qh + qo0), q0h1 = *(const bf16x8*)(qh + qo0 + 32);
    bf16x8 q0l0 = *(const bf16x8*)(ql + qo0), q0l1 = *(const bf16x8*)(ql + qo0 + 32);
    bf16x8 q1h0 = *(const bf16x8*)(qh + qo1), q1h1 = *(const bf16x8*)(qh + qo1 + 32);
    bf16x8 q1l0 = *(const bf16x8*)(ql + qo1), q1l1 = *(const bf16x8*)(ql + qo1 + 32);

    f32x4 O0[4], O1[4];
    float m0r[4], l0r[4], m1r[4], l1r[4];
#pragma unroll
    for (int r = 0; r < 4; r++) {
        O0[r] = zf; O1[r] = zf;
        m0r[r] = -1e30f; l0r[r] = 0.f; m1r[r] = -1e30f; l1r[r] = 0.f;
    }

    // reg staging
    bf16x8 skh0, skh1, skl0, skl1, svh0, svh1, svl0, svl1;
    auto LOADKV = [&](int kb) {
        long ko = kvb + (long)(kb * 64 + krow) * 3072 + kdc;
        skh0 = *(const bf16x8*)(qh + ko); skh1 = *(const bf16x8*)(qh + ko + 8);
        skl0 = *(const bf16x8*)(ql + ko); skl1 = *(const bf16x8*)(ql + ko + 8);
        long vo = kvb + 1024 + (long)(kb * 64 + vk) * 3072 + vdg;
        svh0 = *(const bf16x8*)(qh + vo); svh1 = *(const bf16x8*)(qh + vo + 8);
        svl0 = *(const bf16x8*)(ql + vo); svl1 = *(const bf16x8*)(ql + vo + 8);
    };
    auto WRITEKV = [&]() {
        *(bf16x8*)&KhS[krow * 72 + kdc]     = skh0;
        *(bf16x8*)&KhS[krow * 72 + kdc + 8] = skh1;
        *(bf16x8*)&KlS[krow * 72 + kdc]     = skl0;
        *(bf16x8*)&KlS[krow * 72 + kdc + 8] = skl1;
#pragma unroll
        for (int i = 0; i < 8; i++) {
            VhS[(vdg + i) * 72 + vk]     = svh0[i];
            VhS[(vdg + 8 + i) * 72 + vk] = svh1[i];
            VlS[(vdg + i) * 72 + vk]     = svl0[i];
            VlS[(vdg + 8 + i) * 72 + vk] = svl1[i];
        }
    };

    LOADKV(0);
    for (int kb = 0; kb < nkb; kb++) {
        __syncthreads();            // all waves done reading previous tile
        WRITEKV();                  // implicit vmcnt wait via register deps
        __syncthreads();
        if (kb + 1 < nkb) LOADKV(kb + 1);   // in flight during compute
        const bool g0a = (kb < nkb - 1);    // group0 (rows 0-63) sees kb <= 2qt
        // ---- S = Q K^T (K frags shared between both row-groups) ----
        f32x4 s0[4], s1[4];
#pragma unroll
        for (int ks = 0; ks < 4; ks++) {
            int base = (ks * 16 + l15) * 72 + lg * 8;
            bf16x8 kh0 = *(const bf16x8*)&KhS[base];
            bf16x8 kh1 = *(const bf16x8*)&KhS[base + 32];
            bf16x8 kl0 = *(const bf16x8*)&KlS[base];
            bf16x8 kl1 = *(const bf16x8*)&KlS[base + 32];
            f32x4 a = zf;
            a = __builtin_amdgcn_mfma_f32_16x16x32_bf16(q1h0, kh0, a, 0, 0, 0);
            a = __builtin_amdgcn_mfma_f32_16x16x32_bf16(q1h1, kh1, a, 0, 0, 0);
            a = __builtin_amdgcn_mfma_f32_16x16x32_bf16(q1h0, kl0, a, 0, 0, 0);
            a = __builtin_amdgcn_mfma_f32_16x16x32_bf16(q1h1, kl1, a, 0, 0, 0);
            a = __builtin_amdgcn_mfma_f32_16x16x32_bf16(q1l0, kh0, a, 0, 0, 0);
            a = __builtin_amdgcn_mfma_f32_16x16x32_bf16(q1l1, kh1, a, 0, 0, 0);
            s1[ks] = a;
            f32x4 c = zf;
            if (g0a) {
                c = __builtin_amdgcn_mfma_f32_16x16x32_bf16(q0h0, kh0, c, 0, 0, 0);
                c = __builtin_amdgcn_mfma_f32_16x16x32_bf16(q0h1, kh1, c, 0, 0, 0);
                c = __builtin_amdgcn_mfma_f32_16x16x32_bf16(q0h0, kl0, c, 0, 0, 0);
                c = __builtin_amdgcn_mfma_f32_16x16x32_bf16(q0h1, kl1, c, 0, 0, 0);
                c = __builtin_amdgcn_mfma_f32_16x16x32_bf16(q0l0, kh0, c, 0, 0, 0);
                c = __builtin_amdgcn_mfma_f32_16x16x32_bf16(q0l1, kh1, c, 0, 0, 0);
            }
            s0[ks] = c;
        }
        // ---- online softmax + P store, group1 (always active) ----
        {
            float alpha[4];
#pragma unroll
            for (int r = 0; r < 4; r++) {
                float mt = fmaxf(fmaxf(s1[0][r], s1[1][r]), fmaxf(s1[2][r], s1[3][r]));
#pragma unroll
                for (int m = 1; m < 16; m <<= 1) mt = fmaxf(mt, __shfl_xor(mt, m));
                float mn = fmaxf(m1r[r], mt);
                alpha[r] = __expf(m1r[r] - mn);
                m1r[r] = mn;
            }
            float ladd[4] = {0.f, 0.f, 0.f, 0.f};
#pragma unroll
            for (int ks = 0; ks < 4; ks++)
#pragma unroll
                for (int r = 0; r < 4; r++) {
                    float p = __expf(s1[ks][r] - m1r[r]);
                    s1[ks][r] = p;
                    ladd[r] += p;
                }
#pragma unroll
            for (int r = 0; r < 4; r++) {
#pragma unroll
                for (int m = 1; m < 16; m <<= 1) ladd[r] += __shfl_xor(ladd[r], m);
                l1r[r] = l1r[r] * alpha[r] + ladd[r];
            }
#pragma unroll
            for (int sb = 0; sb < 4; sb++)
#pragma unroll
                for (int r = 0; r < 4; r++) O1[sb][r] *= alpha[r];
            bf16_t* pwh = &PhS[wid][1][0];
            bf16_t* pwl = &PlS[wid][1][0];
#pragma unroll
            for (int ks = 0; ks < 4; ks++)
#pragma unroll
                for (int r = 0; r < 4; r++) {
                    hl_t pv = split1(s1[ks][r]);
                    pwh[(lg * 4 + r) * 72 + ks * 16 + l15] = pv.h;
                    pwl[(lg * 4 + r) * 72 + ks * 16 + l15] = pv.l;
                }
        }
        // ---- softmax + P store, group0 ----
        if (g0a) {
            float alpha[4];
#pragma unroll
            for (int r = 0; r < 4; r++) {
                float mt = fmaxf(fmaxf(s0[0][r], s0[1][r]), fmaxf(s0[2][r], s0[3][r]));
#pragma unroll
                for (int m = 1; m < 16; m <<= 1) mt = fmaxf(mt, __shfl_xor(mt, m));
                float mn = fmaxf(m0r[r], mt);
                alpha[r] = __expf(m0r[r] - mn);
                m0r[r] = mn;
            }
            float ladd[4] = {0.f, 0.f, 0.f, 0.f};
#pragma unroll
            for (int ks = 0; ks < 4; ks++)
#pragma unroll
                for (int r = 0; r < 4; r++) {
                    float p = __expf(s0[ks][r] - m0r[r]);
                    s0[ks][r] = p;
                    ladd[r] += p;
                }
#pragma unroll
            for (int r = 0; r < 4; r++) {
#pragma unroll
                for (int m = 1; m < 16; m <<= 1) ladd[r] += __shfl_xor(ladd[r], m);
                l0r[r] = l0r[r] * alpha[r] + ladd[r];
            }
#pragma unroll
            for (int sb = 0; sb < 4; sb++)
#pragma unroll
                for (int r = 0; r < 4; r++) O0[sb][r] *= alpha[r];
            bf16_t* pwh = &PhS[wid][0][0];
            bf16_t* pwl = &PlS[wid][0][0];
#pragma unroll
            for (int ks = 0; ks < 4; ks++)
#pragma unroll
                for (int r = 0; r < 4; r++) {
                    hl_t pv = split1(s0[ks][r]);
                    pwh[(lg * 4 + r) * 72 + ks * 16 + l15] = pv.h;
                    pwl[(lg * 4 + r) * 72 + ks * 16 + l15] = pv.l;
                }
        }
        // ---- O += P V (V frags shared between both row-groups) ----
#pragma unroll
        for (int kst = 0; kst < 2; kst++) {
            bf16x8 pf1h = *(const bf16x8*)&PhS[wid][1][l15 * 72 + kst * 32 + lg * 8];
            bf16x8 pf1l = *(const bf16x8*)&PlS[wid][1][l15 * 72 + kst * 32 + lg * 8];
            bf16x8 pf0h, pf0l;
            if (g0a) {
                pf0h = *(const bf16x8*)&PhS[wid][0][l15 * 72 + kst * 32 + lg * 8];
                pf0l = *(const bf16x8*)&PlS[wid][0][l15 * 72 + kst * 32 + lg * 8];
            }
#pragma unroll
            for (int sb = 0; sb < 4; sb++) {
                int base = (sb * 16 + l15) * 72 + kst * 32 + lg * 8;
                bf16x8 vfh = *(const bf16x8*)&VhS[base];
                bf16x8 vfl = *(const bf16x8*)&VlS[base];
                O1[sb] = __builtin_amdgcn_mfma_f32_16x16x32_bf16(pf1h, vfh, O1[sb], 0, 0, 0);
                O1[sb] = __builtin_amdgcn_mfma_f32_16x16x32_bf16(pf1h, vfl, O1[sb], 0, 0, 0);
                O1[sb] = __builtin_amdgcn_mfma_f32_16x16x32_bf16(pf1l, vfh, O1[sb], 0, 0, 0);
                if (g0a) {
                    O0[sb] = __builtin_amdgcn_mfma_f32_16x16x32_bf16(pf0h, vfh, O0[sb], 0, 0, 0);
                    O0[sb] = __builtin_amdgcn_mfma_f32_16x16x32_bf16(pf0h, vfl, O0[sb], 0, 0, 0);
                    O0[sb] = __builtin_amdgcn_mfma_f32_16x16x32_bf16(pf0l, vfh, O0[sb], 0, 0, 0);
                }
            }
        }
    }
    // ---- write O, both groups ----
#pragma unroll
    for (int sb = 0; sb < 4; sb++)
#pragma unroll
        for (int r = 0; r < 4; r++) {
            int qg0 = qt * 128 + wid * 16 + lg * 4 + r;
            int col = h * 64 + sb * 16 + l15;
            o[(long)(b * NSEQ + qg0) * 1024 + col] = O0[sb][r] / l0r[r];
            o[(long)(b * NSEQ + qg0 + 64) * 1024 + col] = O1[sb][r] / l1r[r];
        }
}

// ---------------------------------------------------------------------------
__global__ __launch_bounds__(256) void rmsnorm_kernel(const float* __restrict__ y,
                                                      const float* __restrict__ gamma,
                                                      float* __restrict__ moe)
{
    long base = (long)blockIdx.x * 1024;
    float4 v = ((const float4*)(y + base))[threadIdx.x];
    float ss = v.x * v.x + v.y * v.y + v.z * v.z + v.w * v.w;
#pragma unroll
    for (int m = 32; m; m >>= 1) ss += __shfl_xor(ss, m);
    __shared__ float ls[4];
    if ((threadIdx.x & 63) == 0) ls[threadIdx.x >> 6] = ss;
    __syncthreads();
    float tot = ls[0] + ls[1] + ls[2] + ls[3];
    float sc = 32.0f / fmaxf(sqrtf(tot), 1e-12f);
    float4 g = ((const float4*)gamma)[threadIdx.x];
    float4 ov;
    ov.x = v.x * sc * g.x; ov.y = v.y * sc * g.y; ov.z = v.z * sc * g.z; ov.w = v.w * sc * g.w;
    ((float4*)(moe + base))[threadIdx.x] = ov;
}

// ---------------------------------------------------------------------------
// Gating. Top-2 on raw f32 logits; exact logistic gates; aux accums.
// ---------------------------------------------------------------------------
__global__ __launch_bounds__(256) void gating_kernel(
    const float* __restrict__ moe, const float* __restrict__ gw,
    const float* __restrict__ runif, uint32* __restrict__ tokpack,
    float* __restrict__ tokg, float* __restrict__ acc)
{
    const int wid = threadIdx.x >> 6, lane = threadIdx.x & 63;
    const int tk = blockIdx.x * 4 + wid;
    const int b = tk >> 11, n = tk & 2047;
    float xv[16];
    const float4* xr4 = (const float4*)(moe + (long)tk * 1024 + lane * 16);
#pragma unroll
    for (int i = 0; i < 4; i++) {
        float4 v = xr4[i];
        xv[4 * i] = v.x; xv[4 * i + 1] = v.y; xv[4 * i + 2] = v.z; xv[4 * i + 3] = v.w;
    }
    float logit[16];
#pragma unroll
    for (int e = 0; e < 16; e++) {
        const float4* wr4 = (const float4*)(gw + e * 1024 + lane * 16);
        float p = 0.f;
#pragma unroll
        for (int i = 0; i < 4; i++) {
            float4 w = wr4[i];
            p = fmaf(xv[4 * i], w.x, p);     p = fmaf(xv[4 * i + 1], w.y, p);
            p = fmaf(xv[4 * i + 2], w.z, p); p = fmaf(xv[4 * i + 3], w.w, p);
        }
#pragma unroll
        for (int m = 1; m < 64; m <<= 1) p += __shfl_xor(p, m);
        logit[e] = p;
    }
    int e0 = 0; float t0 = logit[0];
#pragma unroll
    for (int e = 1; e < 16; e++) if (logit[e] > t0) { t0 = logit[e]; e0 = e; }
    int e1 = (e0 == 0) ? 1 : 0; float t1 = logit[e1];
#pragma unroll
    for (int e = 0; e < 16; e++) if (e != e0 && logit[e] > t1) { t1 = logit[e]; e1 = e; }
    float g0n = 1.f / (1.f + __expf(t1 - t0));
    float g1n = 1.f / (1.f + __expf(t0 - t1));
    int sr1 = (runif[(long)(BSZ + b) * NSEQ + n] < g1n / 0.2f) ? 1 : 0;
    float mx = t0, sum = 0.f, raw[16];
#pragma unroll
    for (int e = 0; e < 16; e++) { raw[e] = __expf(logit[e] - mx); sum += raw[e]; }
    float inv = 1.f / sum;
    float lse = mx + __logf(sum);
    if (lane == 0) {
        tokpack[tk] = (uint32)e0 | ((uint32)e1 << 4) | ((uint32)sr1 << 8);
        tokg[2 * tk] = g0n; tokg[2 * tk + 1] = g1n;
        atomicAdd(&acc[32 + b * 16 + e0], 1.0f);
        atomicAdd(&acc[64], lse * lse);
    }
    if (lane < 16) atomicAdd(&acc[b * 16 + lane], raw[lane] * inv);
}

// ---------------------------------------------------------------------------
// Parallel position scan. One block per batch, 512 threads x 4 tokens.
// ---------------------------------------------------------------------------
__global__ __launch_bounds__(512) void scan_kernel(const uint32* __restrict__ tokpack,
                                                   uint32* __restrict__ r0,
                                                   uint32* __restrict__ r1,
                                                   int* __restrict__ prev)
{
    const int b = blockIdx.x, t = threadIdx.x;
    const int wv = t >> 6, lane = t & 63;
    uint32 toks[4];
    *(uint4*)toks = ((const uint4*)(tokpack + b * NSEQ))[t];

    uint32 c0[8], c1[8];
#pragma unroll
    for (int j = 0; j < 8; j++) { c0[j] = 0u; c1[j] = 0u; }
#pragma unroll
    for (int i = 0; i < 4; i++) {
        uint32 p = toks[i];
        uint32 e0 = p & 15, e1 = (p >> 4) & 15, sr1 = (p >> 8) & 1;
        uint32 inc0 = 1u << ((e0 & 1) * 16);
        uint32 inc1 = sr1 << ((e1 & 1) * 16);
#pragma unroll
        for (int j = 0; j < 8; j++) {
            c0[j] += ((e0 >> 1) == (uint32)j) ? inc0 : 0u;
            c1[j] += ((e1 >> 1) == (uint32)j) ? inc1 : 0u;
        }
    }
    uint32 i0[8], i1[8];
#pragma unroll
    for (int j = 0; j < 8; j++) { i0[j] = c0[j]; i1[j] = c1[j]; }
#pragma unroll
    for (int off = 1; off < 64; off <<= 1) {
#pragma unroll
        for (int j = 0; j < 8; j++) {
            uint32 u0 = __shfl_up(i0[j], off);
            uint32 u1 = __shfl_up(i1[j], off);
            if (lane >= off) { i0[j] += u0; i1[j] += u1; }
        }
    }
    __shared__ uint32 wsum0[8][8], wsum1[8][8];
    if (lane == 63) {
#pragma unroll
        for (int j = 0; j < 8; j++) { wsum0[wv][j] = i0[j]; wsum1[wv][j] = i1[j]; }
    }
    __syncthreads();
    uint32 b0[8], b1[8];
#pragma unroll
    for (int j = 0; j < 8; j++) {
        uint32 s0 = 0u, s1 = 0u;
#pragma unroll
        for (int w = 0; w < 8; w++) {
            s0 += (w < wv) ? wsum0[w][j] : 0u;
            s1 += (w < wv) ? wsum1[w][j] : 0u;
        }
        b0[j] = s0 + i0[j] - c0[j];
        b1[j] = s1 + i1[j] - c1[j];
    }
    if (t == 0) {
#pragma unroll
        for (int j = 0; j < 8; j++) {
            uint32 tot = 0u;
#pragma unroll
            for (int w = 0; w < 8; w++) tot += wsum0[w][j];
            int tlo = (int)(tot & 0xffffu), thi = (int)(tot >> 16);
            prev[b * 16 + 2 * j]     = tlo < CAPC ? tlo : CAPC;
            prev[b * 16 + 2 * j + 1] = thi < CAPC ? thi : CAPC;
        }
    }
    uint32* rr0 = r0 + b * NSEQ + t * 4;
    uint32* rr1 = r1 + b * NSEQ + t * 4;
#pragma unroll
    for (int i = 0; i < 4; i++) {
        uint32 p = toks[i];
        uint32 e0 = p & 15, e1 = (p >> 4) & 15, sr1 = (p >> 8) & 1;
        uint32 sh0 = (e0 & 1) * 16, sh1 = (e1 & 1) * 16;
        uint32 w0 = 0u, w1 = 0u;
#pragma unroll
        for (int j = 0; j < 8; j++) {
            w0 += ((e0 >> 1) == (uint32)j) ? b0[j] : 0u;
            w1 += ((e1 >> 1) == (uint32)j) ? b1[j] : 0u;
        }
        uint32 s0 = (w0 >> sh0) & 0xffffu;
        uint32 s1v = (w1 >> sh1) & 0xffffu;
        uint32 kept = (s0 < CAPC) ? 1u : 0u;
        rr0[i] = e0 | (kept << 4) | (s0 << 5);
        rr1[i] = e1 | (sr1 << 4) | (s1v << 5);
        uint32 inc0 = 1u << sh0;
        uint32 inc1 = sr1 << sh1;
#pragma unroll
        for (int j = 0; j < 8; j++) {
            b0[j] += ((e0 >> 1) == (uint32)j) ? inc0 : 0u;
            b1[j] += ((e1 >> 1) == (uint32)j) ? inc1 : 0u;
        }
    }
}

// ---------------------------------------------------------------------------
__global__ __launch_bounds__(256) void gather_kernel(
    const float* __restrict__ moe, const uint32* __restrict__ r0,
    const uint32* __restrict__ r1, const int* __restrict__ prev,
    float* __restrict__ ein)
{
    int tk = blockIdx.x, b = tk >> 11;
    float4 v = ((const float4*)(moe + (long)tk * 1024))[threadIdx.x];
    uint32 a = r0[tk];
    if ((a >> 4) & 1) {
        long row = ((long)(a & 15) * 2 + b) * CAPC + (int)(a >> 5);
        ((float4*)(ein + row * 1024))[threadIdx.x] = v;
    }
    uint32 c = r1[tk];
    {
        int e = c & 15, sr1 = (c >> 4) & 1;
        int slot = (int)(c >> 5) + prev[b * 16 + e];
        if (sr1 && slot < CAPC) {
            long row = ((long)e * 2 + b) * CAPC + slot;
            ((float4*)(ein + row * 1024))[threadIdx.x] = v;
        }
    }
}

// ---------------------------------------------------------------------------
__global__ __launch_bounds__(256) void expert_ln_kernel(
    const float* __restrict__ ein, const float* __restrict__ g,
    const float* __restrict__ bb, bf16_t* __restrict__ eout)
{
    int row = blockIdx.x, e = row / (BSZ * CAPC);
    long base = (long)row * 1024;
    float4 v = ((const float4*)(ein + base))[threadIdx.x];
    float s = v.x + v.y + v.z + v.w;
    float ss = v.x * v.x + v.y * v.y + v.z * v.z + v.w * v.w;
#pragma unroll
    for (int m = 32; m; m >>= 1) { s += __shfl_xor(s, m); ss += __shfl_xor(ss, m); }
    __shared__ float l1[4], l2[4];
    if ((threadIdx.x & 63) == 0) { l1[threadIdx.x >> 6] = s; l2[threadIdx.x >> 6] = ss; }
    __syncthreads();
    float st = l1[0] + l1[1] + l1[2] + l1[3];
    float sst = l2[0] + l2[1] + l2[2] + l2[3];
    float mu = st * (1.f / 1024.f);
    float var = sst * (1.f / 1024.f) - mu * mu;
    float rstd = rsqrtf(var + 1e-5f);
    int d = threadIdx.x * 4;
    float4 gg = *(const float4*)(g + e * 1024 + d);
    float4 bv = *(const float4*)(bb + e * 1024 + d);
    bf16x4 ov;
    ov[0] = (bf16_t)((v.x - mu) * rstd * gg.x + bv.x);
    ov[1] = (bf16_t)((v.y - mu) * rstd * gg.y + bv.y);
    ov[2] = (bf16_t)((v.z - mu) * rstd * gg.z + bv.z);
    ov[3] = (bf16_t)((v.w - mu) * rstd * gg.w + bv.w);
    *(bf16x4*)(eout + base + d) = ov;
}

// ---------------------------------------------------------------------------
__global__ __launch_bounds__(256) void combine_kernel(
    const float* __restrict__ y, const float* __restrict__ eout,
    const uint32* __restrict__ r0, const uint32* __restrict__ r1,
    const float* __restrict__ tokg, const int* __restrict__ prev,
    float* __restrict__ out)
{
    int tk = blockIdx.x, b = tk >> 11;
    uint32 a = r0[tk], c = r1[tk];
    int k0f = (a >> 4) & 1;
    float w0 = k0f ? tokg[2 * tk] : 0.f;
    long row0 = ((long)(a & 15) * 2 + b) * CAPC + (int)(a >> 5);
    int e1 = c & 15;
    int slot1 = (int)(c >> 5) + prev[b * 16 + e1];
    int k1f = (((c >> 4) & 1) && slot1 < CAPC) ? 1 : 0;
    float w1 = k1f ? tokg[2 * tk + 1] : 0.f;
    long row1 = ((long)e1 * 2 + b) * CAPC + slot1;
    int i = threadIdx.x;
    float4 vy = ((const float4*)(y + (long)tk * 1024))[i];
    float4 a0 = {0.f, 0.f, 0.f, 0.f}, a1 = {0.f, 0.f, 0.f, 0.f};
    if (k0f) a0 = ((const float4*)(eout + row0 * 1024))[i];
    if (k1f) a1 = ((const float4*)(eout + row1 * 1024))[i];
    float4 ov;
    ov.x = vy.x + w0 * a0.x + w1 * a1.x;
    ov.y = vy.y + w0 * a0.y + w1 * a1.y;
    ov.z = vy.z + w0 * a0.z + w1 * a1.z;
    ov.w = vy.w + w0 * a0.w + w1 * a1.w;
    ((float4*)(out + (long)tk * 1024))[i] = ov;
}

__global__ void zero_acc_kernel(float* acc)
{
    if (threadIdx.x < 65) acc[threadIdx.x] = 0.f;
}

__global__ void finalize_kernel(const float* __restrict__ acc, float* __restrict__ tail)
{
    int t = threadIdx.x;
    float v = (t < 32) ? acc[t] * acc[32 + t] : 0.f;
#pragma unroll
    for (int m = 1; m < 64; m <<= 1) v += __shfl_xor(v, m);
    if (t == 0) {
        float bal = v * (8.0f / (2048.f * 2048.f));
        float z = acc[64] / 4096.f;
        tail[0] = 0.01f * bal + 0.001f * z;
        tail[1] = bal;
        tail[2] = z;
    }
}

// ---------------------------------------------------------------------------
extern "C" void kernel_launch(void* const* d_in, const int* in_sizes, int n_in,
                              void* d_out, int out_size, void* d_ws, size_t ws_size,
                              hipStream_t stream)
{
    (void)in_sizes; (void)n_in; (void)out_size; (void)ws_size;
    const float* x     = (const float*)d_in[0];
    // d_in[1] = attn_mask: block-causal, computed analytically; never read.
    const float* in_w  = (const float*)d_in[2];
    const float* in_b  = (const float*)d_in[3];
    const float* out_w = (const float*)d_in[4];
    const float* out_b = (const float*)d_in[5];
    const float* rg    = (const float*)d_in[6];
    const float* gw    = (const float*)d_in[7];
    const float* lng   = (const float*)d_in[8];
    const float* lnb   = (const float*)d_in[9];
    const float* w1    = (const float*)d_in[10];
    const float* b1    = (const float*)d_in[11];
    const float* w2    = (const float*)d_in[12];
    const float* b2    = (const float*)d_in[13];
    const float* runif = (const float*)d_in[14];
    float* out = (float*)d_out;

    size_t off = 0;
    char* wsb = (char*)d_ws;
    auto take = [&](size_t bytes) -> char* {
        char* p = wsb + off;
        off += (bytes + 255) & ~(size_t)255;
        return p;
    };
    bf16_t* qkvh = (bf16_t*)take((size_t)NTOK * 3072 * 2);   // 25.2 MB
    bf16_t* qkvl = (bf16_t*)take((size_t)NTOK * 3072 * 2);   // 25.2 MB
    float*  obuf = (float*)take((size_t)NTOK * 1024 * 4);
    float*  ybuf = (float*)take((size_t)NTOK * 1024 * 4);
    float*  moe  = (float*)take((size_t)NTOK * 1024 * 4);
    bf16_t* eln  = (bf16_t*)take((size_t)NEXP * BSZ * CAPC * 1024 * 2);
    bf16_t* hbuf = (bf16_t*)take((size_t)NEXP * BSZ * CAPC * HFF_P * 2);
    uint32* tokpack = (uint32*)take(NTOK * 4);
    float*  tokg = (float*)take(NTOK * 8);
    uint32* r0   = (uint32*)take(NTOK * 4);
    uint32* r1   = (uint32*)take(NTOK * 4);
    int*    prev = (int*)take(128);
    float*  acc  = (float*)take(1024);
    // aliases: qkv hi/lo are dead after attention
    float*  ein  = (float*)qkvl;   // 21.0 MB <= 25.2
    float*  eoutv = (float*)qkvh;  // 21.0 MB <= 25.2

    zero_acc_kernel<<<1, 128, 0, stream>>>(acc);

    // QKV = x @ in_proj_w^T + b  (split precision); Q cols pre-scaled 1/8
    gemm_split<0, 1><<<dim3(24, 32), 256, 0, stream>>>(
        x, in_w, in_b, nullptr, qkvh, qkvl, nullptr,
        NTOK, 3072, 1024, 1024, 0.125f);

    attn_split<<<dim3(512), 256, 0, stream>>>(qkvh, qkvl, obuf);

    // y = o @ out_proj_w^T + b + x  (split precision, f32 out)
    gemm_split<2, 0><<<dim3(8, 32), 256, 0, stream>>>(
        obuf, out_w, out_b, x, nullptr, nullptr, ybuf,
        NTOK, 1024, 1024, 0, 1.0f);

    rmsnorm_kernel<<<NTOK, 256, 0, stream>>>(ybuf, rg, moe);
    gating_kernel<<<NTOK / 4, 256, 0, stream>>>(moe, gw, runif, tokpack, tokg, acc);
    scan_kernel<<<dim3(BSZ), 512, 0, stream>>>(tokpack, r0, r1, prev);
    gather_kernel<<<NTOK, 256, 0, stream>>>(moe, r0, r1, prev, ein);
    expert_ln_kernel<<<NEXP * BSZ * CAPC, 256, 0, stream>>>(ein, lng, lnb, eln);

    // h = LeakyReLU(LN @ w1^T + b1) -> bf16, padded cols [2730,2752) zeroed
    gemm_nt<1, 1><<<dim3(22, 3, 16), 256, 0, stream>>>(
        eln, w1, b1, hbuf, 320, HFF_R, HFF_P, 1024, 1024,
        (long)320 * 1024, (long)HFF_R * 1024, HFF_R, (long)320 * HFF_P, HFF_P);

    // expert_out = h @ w2^T + b2 -> f32
    gemm_nt<0, 0><<<dim3(8, 3, 16), 256, 0, stream>>>(
        hbuf, w2, b2, eoutv, 320, 1024, 1024, HFF_P, HFF_R,
        (long)320 * HFF_P, (long)1024 * HFF_R, 1024, (long)320 * 1024, 1024);

    combine_kernel<<<NTOK, 256, 0, stream>>>(ybuf, eoutv, r0, r1, tokg, prev, out);
    finalize_kernel<<<1, 64, 0, stream>>>(acc, out + (size_t)NTOK * 1024);
}

// Round 8
// 670.726 us; speedup vs baseline: 2.1480x; 1.1179x over previous
//
#include <hip/hip_runtime.h>
#include <hip/hip_bf16.h>
#include <cstdint>

#define NSEQ  2048
#define BSZ   2
#define NTOK  4096          // B*N
#define EDIM  1024
#define NEXP  16
#define CAPC  160
#define HFF_R 2730
#define HFF_P 2752          // padded to multiple of 64

typedef __bf16 bf16_t;
typedef __bf16 bf16x8 __attribute__((ext_vector_type(8)));
typedef __bf16 bf16x4 __attribute__((ext_vector_type(4)));
typedef float  f32x4  __attribute__((ext_vector_type(4)));
typedef unsigned int uint32;

__device__ inline bf16x8 zero8() {
    bf16x8 v;
#pragma unroll
    for (int i = 0; i < 8; i++) v[i] = (bf16_t)0.f;
    return v;
}
__device__ inline bf16x8 pack8(float4 a, float4 b) {
    bf16x8 v;
    v[0]=(bf16_t)a.x; v[1]=(bf16_t)a.y; v[2]=(bf16_t)a.z; v[3]=(bf16_t)a.w;
    v[4]=(bf16_t)b.x; v[5]=(bf16_t)b.y; v[6]=(bf16_t)b.z; v[7]=(bf16_t)b.w;
    return v;
}
struct hl_t { bf16_t h, l; };
__device__ inline hl_t split1(float f) {
    hl_t r;
    r.h = (bf16_t)f;
    r.l = (bf16_t)(f - (float)r.h);
    return r;
}

// ---------------------------------------------------------------------------
// Split-precision NT GEMM: C[M,N] = epi(A * B^T + bias), A,B f32.
// hi*hi + hi*lo + lo*hi -> ~2^-18 relative error. BM=BN=128, BK=32.
// Register-staged prefetch: next tile's loads issued before current MFMAs.
// M,N multiples of 128; K multiple of 32 (no guards).
// ---------------------------------------------------------------------------
template <int EPI, int C_SPLIT>
__global__ __launch_bounds__(256) void gemm_split(
    const float* __restrict__ A, const float* __restrict__ Bw,
    const float* __restrict__ bias, const float* __restrict__ resid,
    bf16_t* __restrict__ Chi, bf16_t* __restrict__ Clo, float* __restrict__ Cf,
    int M, int N, int K, int scale_cut, float scale_val)
{
    __shared__ __align__(16) bf16_t Ah[128 * 40], Al[128 * 40];
    __shared__ __align__(16) bf16_t Bh[128 * 40], Bl[128 * 40];
    const int t = threadIdx.x;
    const int m0 = blockIdx.y * 128, n0 = blockIdx.x * 128;
    const int lane = t & 63, l15 = lane & 15, lg = lane >> 4;
    const int wid = t >> 6, wm = wid >> 1, wn = wid & 1;
    const int srow = t >> 1, skc = (t & 1) * 16;

    f32x4 acc[4][4];
    const f32x4 zf = {0.f, 0.f, 0.f, 0.f};
#pragma unroll
    for (int i = 0; i < 4; i++)
#pragma unroll
        for (int j = 0; j < 4; j++) acc[i][j] = zf;

    float4 sa0, sa1, sa2, sa3, sb0, sb1, sb2, sb3;
    auto LOADAB = [&](int k0) {
        const float* ap = A + (long)(m0 + srow) * K + k0 + skc;
        sa0 = *(const float4*)ap;       sa1 = *(const float4*)(ap + 4);
        sa2 = *(const float4*)(ap + 8); sa3 = *(const float4*)(ap + 12);
        const float* bp = Bw + (long)(n0 + srow) * K + k0 + skc;
        sb0 = *(const float4*)bp;       sb1 = *(const float4*)(bp + 4);
        sb2 = *(const float4*)(bp + 8); sb3 = *(const float4*)(bp + 12);
    };
    auto WRITEAB = [&]() {
        float av[16], bv[16];
        *(float4*)&av[0] = sa0; *(float4*)&av[4] = sa1;
        *(float4*)&av[8] = sa2; *(float4*)&av[12] = sa3;
        *(float4*)&bv[0] = sb0; *(float4*)&bv[4] = sb1;
        *(float4*)&bv[8] = sb2; *(float4*)&bv[12] = sb3;
        bf16x8 h0, h1, l0, l1;
#pragma unroll
        for (int i = 0; i < 8; i++) {
            hl_t a = split1(av[i]);      h0[i] = a.h; l0[i] = a.l;
            hl_t b = split1(av[8 + i]);  h1[i] = b.h; l1[i] = b.l;
        }
        *(bf16x8*)&Ah[srow * 40 + skc] = h0; *(bf16x8*)&Ah[srow * 40 + skc + 8] = h1;
        *(bf16x8*)&Al[srow * 40 + skc] = l0; *(bf16x8*)&Al[srow * 40 + skc + 8] = l1;
#pragma unroll
        for (int i = 0; i < 8; i++) {
            hl_t a = split1(bv[i]);      h0[i] = a.h; l0[i] = a.l;
            hl_t b = split1(bv[8 + i]);  h1[i] = b.h; l1[i] = b.l;
        }
        *(bf16x8*)&Bh[srow * 40 + skc] = h0; *(bf16x8*)&Bh[srow * 40 + skc + 8] = h1;
        *(bf16x8*)&Bl[srow * 40 + skc] = l0; *(bf16x8*)&Bl[srow * 40 + skc + 8] = l1;
    };

    LOADAB(0);
    for (int k0 = 0; k0 < K; k0 += 32) {
        WRITEAB();
        __syncthreads();
        if (k0 + 32 < K) LOADAB(k0 + 32);   // in flight during MFMAs
        bf16x8 amh[4], aml[4], bnh[4], bnl[4];
#pragma unroll
        for (int i = 0; i < 4; i++) {
            int base = (wm * 64 + i * 16 + l15) * 40 + lg * 8;
            amh[i] = *(const bf16x8*)&Ah[base];
            aml[i] = *(const bf16x8*)&Al[base];
        }
#pragma unroll
        for (int j = 0; j < 4; j++) {
            int base = (wn * 64 + j * 16 + l15) * 40 + lg * 8;
            bnh[j] = *(const bf16x8*)&Bh[base];
            bnl[j] = *(const bf16x8*)&Bl[base];
        }
#pragma unroll
        for (int i = 0; i < 4; i++)
#pragma unroll
            for (int j = 0; j < 4; j++) {
                acc[i][j] = __builtin_amdgcn_mfma_f32_16x16x32_bf16(amh[i], bnh[j], acc[i][j], 0, 0, 0);
                acc[i][j] = __builtin_amdgcn_mfma_f32_16x16x32_bf16(amh[i], bnl[j], acc[i][j], 0, 0, 0);
                acc[i][j] = __builtin_amdgcn_mfma_f32_16x16x32_bf16(aml[i], bnh[j], acc[i][j], 0, 0, 0);
            }
        __syncthreads();
    }

#pragma unroll
    for (int i = 0; i < 4; i++) {
        int mgb = m0 + wm * 64 + i * 16 + lg * 4;
#pragma unroll
        for (int j = 0; j < 4; j++) {
            int ng = n0 + wn * 64 + j * 16 + l15;
            float bval = bias[ng];
#pragma unroll
            for (int r = 0; r < 4; r++) {
                int mg = mgb + r;
                float val = acc[i][j][r] + bval;
                if (scale_cut > 0 && ng < scale_cut) val *= scale_val;
                if (EPI == 2) val += resid[(long)mg * N + ng];
                long idx = (long)mg * N + ng;
                if (C_SPLIT) {
                    bf16_t hi = (bf16_t)val;
                    Chi[idx] = hi;
                    Clo[idx] = (bf16_t)(val - (float)hi);
                } else {
                    Cf[idx] = val;
                }
            }
        }
    }
}

// ---------------------------------------------------------------------------
// bf16 NT GEMM (expert FFN path, value-precision only).
// A: bf16 row-major; B: f32 row-major. Register-staged prefetch.
// BM template: 128 (wave-tile 64x64) or 64 (wave-tile 32x64, exact M=320).
// Writes cols [0,Nwr); value forced 0 for cols in [N,Nwr).
// ---------------------------------------------------------------------------
template <int EPI, int C_BF16, int BM>
__global__ __launch_bounds__(256) void gemm_nt(
    const bf16_t* __restrict__ Av, const float* __restrict__ Bw,
    const float* __restrict__ bias, void* __restrict__ Cv,
    int M, int N, int Nwr, int KA, int KB,
    long sAe, long sBe, long sBiasE, long sCe, int ldc)
{
    constexpr int MI = BM / 32;     // m-frags per wave (wave-tile BM/2 rows)
    __shared__ __align__(16) bf16_t Alds[BM * 40];
    __shared__ __align__(16) bf16_t Blds[128 * 40];
    const int t = threadIdx.x;
    const int e = blockIdx.z;
    const int m0 = blockIdx.y * BM, n0 = blockIdx.x * 128;
    const int lane = t & 63, l15 = lane & 15, lg = lane >> 4;
    const int wid = t >> 6, wm = wid >> 1, wn = wid & 1;
    const int arow = (BM == 128) ? (t >> 1) : (t >> 2);
    const int acol = (BM == 128) ? ((t & 1) * 16) : ((t & 3) * 8);
    const int brow = t >> 1, bcol = (t & 1) * 16;

    f32x4 acc[MI][4];
    const f32x4 zf = {0.f, 0.f, 0.f, 0.f};
#pragma unroll
    for (int i = 0; i < MI; i++)
#pragma unroll
        for (int j = 0; j < 4; j++) acc[i][j] = zf;

    bf16x8 sa0, sa1;
    float4 sb0, sb1, sb2, sb3;
    const float4 zf4 = {0.f, 0.f, 0.f, 0.f};
    auto LOADA = [&](int k0) {
        int mg = m0 + arow;
        sa0 = zero8();
        if (BM == 128) sa1 = zero8();
        if (mg < M) {
            const bf16_t* ap = Av + (long)e * sAe + (long)mg * KA + k0 + acol;
            sa0 = *(const bf16x8*)ap;
            if (BM == 128) sa1 = *(const bf16x8*)(ap + 8);
        }
    };
    auto LOADB = [&](int k0) {
        int ng = n0 + brow;
        if (ng < N) {
            const float* bp = Bw + (long)e * sBe + (long)ng * KB + k0 + bcol;
            if (k0 + 32 <= KB) {
                sb0 = *(const float4*)bp;       sb1 = *(const float4*)(bp + 4);
                sb2 = *(const float4*)(bp + 8); sb3 = *(const float4*)(bp + 12);
            } else {
                float v[16];
#pragma unroll
                for (int i = 0; i < 16; i++) {
                    int kk = k0 + bcol + i;
                    v[i] = (kk < KB) ? bp[i] : 0.f;
                }
                sb0 = *(float4*)&v[0];  sb1 = *(float4*)&v[4];
                sb2 = *(float4*)&v[8];  sb3 = *(float4*)&v[12];
            }
        } else {
            sb0 = zf4; sb1 = zf4; sb2 = zf4; sb3 = zf4;
        }
    };
    auto WRITEAB = [&]() {
        *(bf16x8*)&Alds[arow * 40 + acol] = sa0;
        if (BM == 128) *(bf16x8*)&Alds[arow * 40 + acol + 8] = sa1;
        *(bf16x8*)&Blds[brow * 40 + bcol] = pack8(sb0, sb1);
        *(bf16x8*)&Blds[brow * 40 + bcol + 8] = pack8(sb2, sb3);
    };

    LOADA(0); LOADB(0);
    for (int k0 = 0; k0 < KA; k0 += 32) {
        WRITEAB();
        __syncthreads();
        if (k0 + 32 < KA) { LOADA(k0 + 32); LOADB(k0 + 32); }
        bf16x8 am[MI], bn[4];
#pragma unroll
        for (int i = 0; i < MI; i++)
            am[i] = *(const bf16x8*)&Alds[(wm * (BM / 2) + i * 16 + l15) * 40 + lg * 8];
#pragma unroll
        for (int j = 0; j < 4; j++)
            bn[j] = *(const bf16x8*)&Blds[(wn * 64 + j * 16 + l15) * 40 + lg * 8];
#pragma unroll
        for (int i = 0; i < MI; i++)
#pragma unroll
            for (int j = 0; j < 4; j++)
                acc[i][j] = __builtin_amdgcn_mfma_f32_16x16x32_bf16(am[i], bn[j], acc[i][j], 0, 0, 0);
        __syncthreads();
    }

    const float* biasp = bias + (long)e * sBiasE;
#pragma unroll
    for (int i = 0; i < MI; i++) {
        int mgb = m0 + wm * (BM / 2) + i * 16 + lg * 4;
#pragma unroll
        for (int j = 0; j < 4; j++) {
            int ng = n0 + wn * 64 + j * 16 + l15;
            if (ng < Nwr) {
                float bval = (ng < N) ? biasp[ng] : 0.f;
#pragma unroll
                for (int r = 0; r < 4; r++) {
                    int mg = mgb + r;
                    if (mg < M) {
                        float val = acc[i][j][r] + bval;
                        if (EPI == 1) val = (val >= 0.f) ? val : 0.01f * val;
                        if (ng >= N) val = 0.f;
                        long cidx = (long)e * sCe + (long)mg * ldc + ng;
                        if (C_BF16) ((bf16_t*)Cv)[cidx] = (bf16_t)val;
                        else        ((float*)Cv)[cidx] = val;
                    }
                }
            }
        }
    }
}

// ---------------------------------------------------------------------------
// Split-precision flash attention (unchanged from round 7, passing config).
// ---------------------------------------------------------------------------
__global__ __launch_bounds__(256) void attn_split(const bf16_t* __restrict__ qh,
                                                  const bf16_t* __restrict__ ql,
                                                  float* __restrict__ o)
{
    __shared__ __align__(16) bf16_t KhS[64 * 72], KlS[64 * 72];
    __shared__ __align__(16) bf16_t VhS[64 * 72], VlS[64 * 72];   // transposed [d][key]
    __shared__ __align__(16) bf16_t PhS[4][2][16 * 72], PlS[4][2][16 * 72];

    const int id = blockIdx.x;
    const int x  = id & 7;
    const int s  = id >> 3;
    const int b  = s >> 5;
    const int s5 = s & 31;
    const int qraw = s5 & 15;
    const int h  = x + 8 * (s5 >> 4);
    const int qt = b ? (15 - qraw) : qraw;
    const int nkb = 2 * qt + 2;

    const int t = threadIdx.x, wid = t >> 6, lane = t & 63, l15 = lane & 15, lg = lane >> 4;
    const int krow = t >> 2, kdc = (t & 3) * 16;
    const int vk = t & 63, vdg = (t >> 6) * 16;
    const long kvb = (long)(b * NSEQ) * 3072 + 1024 + h * 64;
    const f32x4 zf = {0.f, 0.f, 0.f, 0.f};

    const long qo0 = (long)(b * NSEQ + qt * 128 + wid * 16 + l15) * 3072 + h * 64 + lg * 8;
    const long qo1 = qo0 + (long)64 * 3072;
    bf16x8 q0h0 = *(const bf16x8*)(qh + qo0), q0h1 = *(const bf16x8*)(qh + qo0 + 32);
    bf16x8 q0l0 = *(const bf16x8*)(ql + qo0), q0l1 = *(const bf16x8*)(ql + qo0 + 32);
    bf16x8 q1h0 = *(const bf16x8*)(qh + qo1), q1h1 = *(const bf16x8*)(qh + qo1 + 32);
    bf16x8 q1l0 = *(const bf16x8*)(ql + qo1), q1l1 = *(const bf16x8*)(ql + qo1 + 32);

    f32x4 O0[4], O1[4];
    float m0r[4], l0r[4], m1r[4], l1r[4];
#pragma unroll
    for (int r = 0; r < 4; r++) {
        O0[r] = zf; O1[r] = zf;
        m0r[r] = -1e30f; l0r[r] = 0.f; m1r[r] = -1e30f; l1r[r] = 0.f;
    }

    bf16x8 skh0, skh1, skl0, skl1, svh0, svh1, svl0, svl1;
    auto LOADKV = [&](int kb) {
        long ko = kvb + (long)(kb * 64 + krow) * 3072 + kdc;
        skh0 = *(const bf16x8*)(qh + ko); skh1 = *(const bf16x8*)(qh + ko + 8);
        skl0 = *(const bf16x8*)(ql + ko); skl1 = *(const bf16x8*)(ql + ko + 8);
        long vo = kvb + 1024 + (long)(kb * 64 + vk) * 3072 + vdg;
        svh0 = *(const bf16x8*)(qh + vo); svh1 = *(const bf16x8*)(qh + vo + 8);
        svl0 = *(const bf16x8*)(ql + vo); svl1 = *(const bf16x8*)(ql + vo + 8);
    };
    auto WRITEKV = [&]() {
        *(bf16x8*)&KhS[krow * 72 + kdc]     = skh0;
        *(bf16x8*)&KhS[krow * 72 + kdc + 8] = skh1;
        *(bf16x8*)&KlS[krow * 72 + kdc]     = skl0;
        *(bf16x8*)&KlS[krow * 72 + kdc + 8] = skl1;
#pragma unroll
        for (int i = 0; i < 8; i++) {
            VhS[(vdg + i) * 72 + vk]     = svh0[i];
            VhS[(vdg + 8 + i) * 72 + vk] = svh1[i];
            VlS[(vdg + i) * 72 + vk]     = svl0[i];
            VlS[(vdg + 8 + i) * 72 + vk] = svl1[i];
        }
    };

    LOADKV(0);
    for (int kb = 0; kb < nkb; kb++) {
        __syncthreads();
        WRITEKV();
        __syncthreads();
        if (kb + 1 < nkb) LOADKV(kb + 1);
        const bool g0a = (kb < nkb - 1);
        f32x4 s0[4], s1[4];
#pragma unroll
        for (int ks = 0; ks < 4; ks++) {
            int base = (ks * 16 + l15) * 72 + lg * 8;
            bf16x8 kh0 = *(const bf16x8*)&KhS[base];
            bf16x8 kh1 = *(const bf16x8*)&KhS[base + 32];
            bf16x8 kl0 = *(const bf16x8*)&KlS[base];
            bf16x8 kl1 = *(const bf16x8*)&KlS[base + 32];
            f32x4 a = zf;
            a = __builtin_amdgcn_mfma_f32_16x16x32_bf16(q1h0, kh0, a, 0, 0, 0);
            a = __builtin_amdgcn_mfma_f32_16x16x32_bf16(q1h1, kh1, a, 0, 0, 0);
            a = __builtin_amdgcn_mfma_f32_16x16x32_bf16(q1h0, kl0, a, 0, 0, 0);
            a = __builtin_amdgcn_mfma_f32_16x16x32_bf16(q1h1, kl1, a, 0, 0, 0);
            a = __builtin_amdgcn_mfma_f32_16x16x32_bf16(q1l0, kh0, a, 0, 0, 0);
            a = __builtin_amdgcn_mfma_f32_16x16x32_bf16(q1l1, kh1, a, 0, 0, 0);
            s1[ks] = a;
            f32x4 c = zf;
            if (g0a) {
                c = __builtin_amdgcn_mfma_f32_16x16x32_bf16(q0h0, kh0, c, 0, 0, 0);
                c = __builtin_amdgcn_mfma_f32_16x16x32_bf16(q0h1, kh1, c, 0, 0, 0);
                c = __builtin_amdgcn_mfma_f32_16x16x32_bf16(q0h0, kl0, c, 0, 0, 0);
                c = __builtin_amdgcn_mfma_f32_16x16x32_bf16(q0h1, kl1, c, 0, 0, 0);
                c = __builtin_amdgcn_mfma_f32_16x16x32_bf16(q0l0, kh0, c, 0, 0, 0);
                c = __builtin_amdgcn_mfma_f32_16x16x32_bf16(q0l1, kh1, c, 0, 0, 0);
            }
            s0[ks] = c;
        }
        {
            float alpha[4];
#pragma unroll
            for (int r = 0; r < 4; r++) {
                float mt = fmaxf(fmaxf(s1[0][r], s1[1][r]), fmaxf(s1[2][r], s1[3][r]));
#pragma unroll
                for (int m = 1; m < 16; m <<= 1) mt = fmaxf(mt, __shfl_xor(mt, m));
                float mn = fmaxf(m1r[r], mt);
                alpha[r] = __expf(m1r[r] - mn);
                m1r[r] = mn;
            }
            float ladd[4] = {0.f, 0.f, 0.f, 0.f};
#pragma unroll
            for (int ks = 0; ks < 4; ks++)
#pragma unroll
                for (int r = 0; r < 4; r++) {
                    float p = __expf(s1[ks][r] - m1r[r]);
                    s1[ks][r] = p;
                    ladd[r] += p;
                }
#pragma unroll
            for (int r = 0; r < 4; r++) {
#pragma unroll
                for (int m = 1; m < 16; m <<= 1) ladd[r] += __shfl_xor(ladd[r], m);
                l1r[r] = l1r[r] * alpha[r] + ladd[r];
            }
#pragma unroll
            for (int sb = 0; sb < 4; sb++)
#pragma unroll
                for (int r = 0; r < 4; r++) O1[sb][r] *= alpha[r];
            bf16_t* pwh = &PhS[wid][1][0];
            bf16_t* pwl = &PlS[wid][1][0];
#pragma unroll
            for (int ks = 0; ks < 4; ks++)
#pragma unroll
                for (int r = 0; r < 4; r++) {
                    hl_t pv = split1(s1[ks][r]);
                    pwh[(lg * 4 + r) * 72 + ks * 16 + l15] = pv.h;
                    pwl[(lg * 4 + r) * 72 + ks * 16 + l15] = pv.l;
                }
        }
        if (g0a) {
            float alpha[4];
#pragma unroll
            for (int r = 0; r < 4; r++) {
                float mt = fmaxf(fmaxf(s0[0][r], s0[1][r]), fmaxf(s0[2][r], s0[3][r]));
#pragma unroll
                for (int m = 1; m < 16; m <<= 1) mt = fmaxf(mt, __shfl_xor(mt, m));
                float mn = fmaxf(m0r[r], mt);
                alpha[r] = __expf(m0r[r] - mn);
                m0r[r] = mn;
            }
            float ladd[4] = {0.f, 0.f, 0.f, 0.f};
#pragma unroll
            for (int ks = 0; ks < 4; ks++)
#pragma unroll
                for (int r = 0; r < 4; r++) {
                    float p = __expf(s0[ks][r] - m0r[r]);
                    s0[ks][r] = p;
                    ladd[r] += p;
                }
#pragma unroll
            for (int r = 0; r < 4; r++) {
#pragma unroll
                for (int m = 1; m < 16; m <<= 1) ladd[r] += __shfl_xor(ladd[r], m);
                l0r[r] = l0r[r] * alpha[r] + ladd[r];
            }
#pragma unroll
            for (int sb = 0; sb < 4; sb++)
#pragma unroll
                for (int r = 0; r < 4; r++) O0[sb][r] *= alpha[r];
            bf16_t* pwh = &PhS[wid][0][0];
            bf16_t* pwl = &PlS[wid][0][0];
#pragma unroll
            for (int ks = 0; ks < 4; ks++)
#pragma unroll
                for (int r = 0; r < 4; r++) {
                    hl_t pv = split1(s0[ks][r]);
                    pwh[(lg * 4 + r) * 72 + ks * 16 + l15] = pv.h;
                    pwl[(lg * 4 + r) * 72 + ks * 16 + l15] = pv.l;
                }
        }
#pragma unroll
        for (int kst = 0; kst < 2; kst++) {
            bf16x8 pf1h = *(const bf16x8*)&PhS[wid][1][l15 * 72 + kst * 32 + lg * 8];
            bf16x8 pf1l = *(const bf16x8*)&PlS[wid][1][l15 * 72 + kst * 32 + lg * 8];
            bf16x8 pf0h, pf0l;
            if (g0a) {
                pf0h = *(const bf16x8*)&PhS[wid][0][l15 * 72 + kst * 32 + lg * 8];
                pf0l = *(const bf16x8*)&PlS[wid][0][l15 * 72 + kst * 32 + lg * 8];
            }
#pragma unroll
            for (int sb = 0; sb < 4; sb++) {
                int base = (sb * 16 + l15) * 72 + kst * 32 + lg * 8;
                bf16x8 vfh = *(const bf16x8*)&VhS[base];
                bf16x8 vfl = *(const bf16x8*)&VlS[base];
                O1[sb] = __builtin_amdgcn_mfma_f32_16x16x32_bf16(pf1h, vfh, O1[sb], 0, 0, 0);
                O1[sb] = __builtin_amdgcn_mfma_f32_16x16x32_bf16(pf1h, vfl, O1[sb], 0, 0, 0);
                O1[sb] = __builtin_amdgcn_mfma_f32_16x16x32_bf16(pf1l, vfh, O1[sb], 0, 0, 0);
                if (g0a) {
                    O0[sb] = __builtin_amdgcn_mfma_f32_16x16x32_bf16(pf0h, vfh, O0[sb], 0, 0, 0);
                    O0[sb] = __builtin_amdgcn_mfma_f32_16x16x32_bf16(pf0h, vfl, O0[sb], 0, 0, 0);
                    O0[sb] = __builtin_amdgcn_mfma_f32_16x16x32_bf16(pf0l, vfh, O0[sb], 0, 0, 0);
                }
            }
        }
    }
#pragma unroll
    for (int sb = 0; sb < 4; sb++)
#pragma unroll
        for (int r = 0; r < 4; r++) {
            int qg0 = qt * 128 + wid * 16 + lg * 4 + r;
            int col = h * 64 + sb * 16 + l15;
            o[(long)(b * NSEQ + qg0) * 1024 + col] = O0[sb][r] / l0r[r];
            o[(long)(b * NSEQ + qg0 + 64) * 1024 + col] = O1[sb][r] / l1r[r];
        }
}

// ---------------------------------------------------------------------------
__global__ __launch_bounds__(256) void rmsnorm_kernel(const float* __restrict__ y,
                                                      const float* __restrict__ gamma,
                                                      float* __restrict__ moe)
{
    long base = (long)blockIdx.x * 1024;
    float4 v = ((const float4*)(y + base))[threadIdx.x];
    float ss = v.x * v.x + v.y * v.y + v.z * v.z + v.w * v.w;
#pragma unroll
    for (int m = 32; m; m >>= 1) ss += __shfl_xor(ss, m);
    __shared__ float ls[4];
    if ((threadIdx.x & 63) == 0) ls[threadIdx.x >> 6] = ss;
    __syncthreads();
    float tot = ls[0] + ls[1] + ls[2] + ls[3];
    float sc = 32.0f / fmaxf(sqrtf(tot), 1e-12f);
    float4 g = ((const float4*)gamma)[threadIdx.x];
    float4 ov;
    ov.x = v.x * sc * g.x; ov.y = v.y * sc * g.y; ov.z = v.z * sc * g.z; ov.w = v.w * sc * g.w;
    ((float4*)(moe + base))[threadIdx.x] = ov;
}

// ---------------------------------------------------------------------------
__global__ __launch_bounds__(256) void gating_kernel(
    const float* __restrict__ moe, const float* __restrict__ gw,
    const float* __restrict__ runif, uint32* __restrict__ tokpack,
    float* __restrict__ tokg, float* __restrict__ acc)
{
    const int wid = threadIdx.x >> 6, lane = threadIdx.x & 63;
    const int tk = blockIdx.x * 4 + wid;
    const int b = tk >> 11, n = tk & 2047;
    float xv[16];
    const float4* xr4 = (const float4*)(moe + (long)tk * 1024 + lane * 16);
#pragma unroll
    for (int i = 0; i < 4; i++) {
        float4 v = xr4[i];
        xv[4 * i] = v.x; xv[4 * i + 1] = v.y; xv[4 * i + 2] = v.z; xv[4 * i + 3] = v.w;
    }
    float logit[16];
#pragma unroll
    for (int e = 0; e < 16; e++) {
        const float4* wr4 = (const float4*)(gw + e * 1024 + lane * 16);
        float p = 0.f;
#pragma unroll
        for (int i = 0; i < 4; i++) {
            float4 w = wr4[i];
            p = fmaf(xv[4 * i], w.x, p);     p = fmaf(xv[4 * i + 1], w.y, p);
            p = fmaf(xv[4 * i + 2], w.z, p); p = fmaf(xv[4 * i + 3], w.w, p);
        }
#pragma unroll
        for (int m = 1; m < 64; m <<= 1) p += __shfl_xor(p, m);
        logit[e] = p;
    }
    int e0 = 0; float t0 = logit[0];
#pragma unroll
    for (int e = 1; e < 16; e++) if (logit[e] > t0) { t0 = logit[e]; e0 = e; }
    int e1 = (e0 == 0) ? 1 : 0; float t1 = logit[e1];
#pragma unroll
    for (int e = 0; e < 16; e++) if (e != e0 && logit[e] > t1) { t1 = logit[e]; e1 = e; }
    float g0n = 1.f / (1.f + __expf(t1 - t0));
    float g1n = 1.f / (1.f + __expf(t0 - t1));
    int sr1 = (runif[(long)(BSZ + b) * NSEQ + n] < g1n / 0.2f) ? 1 : 0;
    float mx = t0, sum = 0.f, raw[16];
#pragma unroll
    for (int e = 0; e < 16; e++) { raw[e] = __expf(logit[e] - mx); sum += raw[e]; }
    float inv = 1.f / sum;
    float lse = mx + __logf(sum);
    if (lane == 0) {
        tokpack[tk] = (uint32)e0 | ((uint32)e1 << 4) | ((uint32)sr1 << 8);
        tokg[2 * tk] = g0n; tokg[2 * tk + 1] = g1n;
        atomicAdd(&acc[32 + b * 16 + e0], 1.0f);
        atomicAdd(&acc[64], lse * lse);
    }
    if (lane < 16) atomicAdd(&acc[b * 16 + lane], raw[lane] * inv);
}

// ---------------------------------------------------------------------------
__global__ __launch_bounds__(512) void scan_kernel(const uint32* __restrict__ tokpack,
                                                   uint32* __restrict__ r0,
                                                   uint32* __restrict__ r1,
                                                   int* __restrict__ prev)
{
    const int b = blockIdx.x, t = threadIdx.x;
    const int wv = t >> 6, lane = t & 63;
    uint32 toks[4];
    *(uint4*)toks = ((const uint4*)(tokpack + b * NSEQ))[t];

    uint32 c0[8], c1[8];
#pragma unroll
    for (int j = 0; j < 8; j++) { c0[j] = 0u; c1[j] = 0u; }
#pragma unroll
    for (int i = 0; i < 4; i++) {
        uint32 p = toks[i];
        uint32 e0 = p & 15, e1 = (p >> 4) & 15, sr1 = (p >> 8) & 1;
        uint32 inc0 = 1u << ((e0 & 1) * 16);
        uint32 inc1 = sr1 << ((e1 & 1) * 16);
#pragma unroll
        for (int j = 0; j < 8; j++) {
            c0[j] += ((e0 >> 1) == (uint32)j) ? inc0 : 0u;
            c1[j] += ((e1 >> 1) == (uint32)j) ? inc1 : 0u;
        }
    }
    uint32 i0[8], i1[8];
#pragma unroll
    for (int j = 0; j < 8; j++) { i0[j] = c0[j]; i1[j] = c1[j]; }
#pragma unroll
    for (int off = 1; off < 64; off <<= 1) {
#pragma unroll
        for (int j = 0; j < 8; j++) {
            uint32 u0 = __shfl_up(i0[j], off);
            uint32 u1 = __shfl_up(i1[j], off);
            if (lane >= off) { i0[j] += u0; i1[j] += u1; }
        }
    }
    __shared__ uint32 wsum0[8][8], wsum1[8][8];
    if (lane == 63) {
#pragma unroll
        for (int j = 0; j < 8; j++) { wsum0[wv][j] = i0[j]; wsum1[wv][j] = i1[j]; }
    }
    __syncthreads();
    uint32 b0[8], b1[8];
#pragma unroll
    for (int j = 0; j < 8; j++) {
        uint32 s0 = 0u, s1 = 0u;
#pragma unroll
        for (int w = 0; w < 8; w++) {
            s0 += (w < wv) ? wsum0[w][j] : 0u;
            s1 += (w < wv) ? wsum1[w][j] : 0u;
        }
        b0[j] = s0 + i0[j] - c0[j];
        b1[j] = s1 + i1[j] - c1[j];
    }
    if (t == 0) {
#pragma unroll
        for (int j = 0; j < 8; j++) {
            uint32 tot = 0u;
#pragma unroll
            for (int w = 0; w < 8; w++) tot += wsum0[w][j];
            int tlo = (int)(tot & 0xffffu), thi = (int)(tot >> 16);
            prev[b * 16 + 2 * j]     = tlo < CAPC ? tlo : CAPC;
            prev[b * 16 + 2 * j + 1] = thi < CAPC ? thi : CAPC;
        }
    }
    uint32* rr0 = r0 + b * NSEQ + t * 4;
    uint32* rr1 = r1 + b * NSEQ + t * 4;
#pragma unroll
    for (int i = 0; i < 4; i++) {
        uint32 p = toks[i];
        uint32 e0 = p & 15, e1 = (p >> 4) & 15, sr1 = (p >> 8) & 1;
        uint32 sh0 = (e0 & 1) * 16, sh1 = (e1 & 1) * 16;
        uint32 w0 = 0u, w1 = 0u;
#pragma unroll
        for (int j = 0; j < 8; j++) {
            w0 += ((e0 >> 1) == (uint32)j) ? b0[j] : 0u;
            w1 += ((e1 >> 1) == (uint32)j) ? b1[j] : 0u;
        }
        uint32 s0 = (w0 >> sh0) & 0xffffu;
        uint32 s1v = (w1 >> sh1) & 0xffffu;
        uint32 kept = (s0 < CAPC) ? 1u : 0u;
        rr0[i] = e0 | (kept << 4) | (s0 << 5);
        rr1[i] = e1 | (sr1 << 4) | (s1v << 5);
        uint32 inc0 = 1u << sh0;
        uint32 inc1 = sr1 << sh1;
#pragma unroll
        for (int j = 0; j < 8; j++) {
            b0[j] += ((e0 >> 1) == (uint32)j) ? inc0 : 0u;
            b1[j] += ((e1 >> 1) == (uint32)j) ? inc1 : 0u;
        }
    }
}

// ---------------------------------------------------------------------------
__global__ __launch_bounds__(256) void gather_kernel(
    const float* __restrict__ moe, const uint32* __restrict__ r0,
    const uint32* __restrict__ r1, const int* __restrict__ prev,
    float* __restrict__ ein)
{
    int tk = blockIdx.x, b = tk >> 11;
    float4 v = ((const float4*)(moe + (long)tk * 1024))[threadIdx.x];
    uint32 a = r0[tk];
    if ((a >> 4) & 1) {
        long row = ((long)(a & 15) * 2 + b) * CAPC + (int)(a >> 5);
        ((float4*)(ein + row * 1024))[threadIdx.x] = v;
    }
    uint32 c = r1[tk];
    {
        int e = c & 15, sr1 = (c >> 4) & 1;
        int slot = (int)(c >> 5) + prev[b * 16 + e];
        if (sr1 && slot < CAPC) {
            long row = ((long)e * 2 + b) * CAPC + slot;
            ((float4*)(ein + row * 1024))[threadIdx.x] = v;
        }
    }
}

// ---------------------------------------------------------------------------
__global__ __launch_bounds__(256) void expert_ln_kernel(
    const float* __restrict__ ein, const float* __restrict__ g,
    const float* __restrict__ bb, bf16_t* __restrict__ eout)
{
    int row = blockIdx.x, e = row / (BSZ * CAPC);
    long base = (long)row * 1024;
    float4 v = ((const float4*)(ein + base))[threadIdx.x];
    float s = v.x + v.y + v.z + v.w;
    float ss = v.x * v.x + v.y * v.y + v.z * v.z + v.w * v.w;
#pragma unroll
    for (int m = 32; m; m >>= 1) { s += __shfl_xor(s, m); ss += __shfl_xor(ss, m); }
    __shared__ float l1[4], l2[4];
    if ((threadIdx.x & 63) == 0) { l1[threadIdx.x >> 6] = s; l2[threadIdx.x >> 6] = ss; }
    __syncthreads();
    float st = l1[0] + l1[1] + l1[2] + l1[3];
    float sst = l2[0] + l2[1] + l2[2] + l2[3];
    float mu = st * (1.f / 1024.f);
    float var = sst * (1.f / 1024.f) - mu * mu;
    float rstd = rsqrtf(var + 1e-5f);
    int d = threadIdx.x * 4;
    float4 gg = *(const float4*)(g + e * 1024 + d);
    float4 bv = *(const float4*)(bb + e * 1024 + d);
    bf16x4 ov;
    ov[0] = (bf16_t)((v.x - mu) * rstd * gg.x + bv.x);
    ov[1] = (bf16_t)((v.y - mu) * rstd * gg.y + bv.y);
    ov[2] = (bf16_t)((v.z - mu) * rstd * gg.z + bv.z);
    ov[3] = (bf16_t)((v.w - mu) * rstd * gg.w + bv.w);
    *(bf16x4*)(eout + base + d) = ov;
}

// ---------------------------------------------------------------------------
__global__ __launch_bounds__(256) void combine_kernel(
    const float* __restrict__ y, const float* __restrict__ eout,
    const uint32* __restrict__ r0, const uint32* __restrict__ r1,
    const float* __restrict__ tokg, const int* __restrict__ prev,
    float* __restrict__ out)
{
    int tk = blockIdx.x, b = tk >> 11;
    uint32 a = r0[tk], c = r1[tk];
    int k0f = (a >> 4) & 1;
    float w0 = k0f ? tokg[2 * tk] : 0.f;
    long row0 = ((long)(a & 15) * 2 + b) * CAPC + (int)(a >> 5);
    int e1 = c & 15;
    int slot1 = (int)(c >> 5) + prev[b * 16 + e1];
    int k1f = (((c >> 4) & 1) && slot1 < CAPC) ? 1 : 0;
    float w1 = k1f ? tokg[2 * tk + 1] : 0.f;
    long row1 = ((long)e1 * 2 + b) * CAPC + slot1;
    int i = threadIdx.x;
    float4 vy = ((const float4*)(y + (long)tk * 1024))[i];
    float4 a0 = {0.f, 0.f, 0.f, 0.f}, a1 = {0.f, 0.f, 0.f, 0.f};
    if (k0f) a0 = ((const float4*)(eout + row0 * 1024))[i];
    if (k1f) a1 = ((const float4*)(eout + row1 * 1024))[i];
    float4 ov;
    ov.x = vy.x + w0 * a0.x + w1 * a1.x;
    ov.y = vy.y + w0 * a0.y + w1 * a1.y;
    ov.z = vy.z + w0 * a0.z + w1 * a1.z;
    ov.w = vy.w + w0 * a0.w + w1 * a1.w;
    ((float4*)(out + (long)tk * 1024))[i] = ov;
}

__global__ void zero_acc_kernel(float* acc)
{
    if (threadIdx.x < 65) acc[threadIdx.x] = 0.f;
}

__global__ void finalize_kernel(const float* __restrict__ acc, float* __restrict__ tail)
{
    int t = threadIdx.x;
    float v = (t < 32) ? acc[t] * acc[32 + t] : 0.f;
#pragma unroll
    for (int m = 1; m < 64; m <<= 1) v += __shfl_xor(v, m);
    if (t == 0) {
        float bal = v * (8.0f / (2048.f * 2048.f));
        float z = acc[64] / 4096.f;
        tail[0] = 0.01f * bal + 0.001f * z;
        tail[1] = bal;
        tail[2] = z;
    }
}

// ---------------------------------------------------------------------------
extern "C" void kernel_launch(void* const* d_in, const int* in_sizes, int n_in,
                              void* d_out, int out_size, void* d_ws, size_t ws_size,
                              hipStream_t stream)
{
    (void)in_sizes; (void)n_in; (void)out_size; (void)ws_size;
    const float* x     = (const float*)d_in[0];
    // d_in[1] = attn_mask: block-causal, computed analytically; never read.
    const float* in_w  = (const float*)d_in[2];
    const float* in_b  = (const float*)d_in[3];
    const float* out_w = (const float*)d_in[4];
    const float* out_b = (const float*)d_in[5];
    const float* rg    = (const float*)d_in[6];
    const float* gw    = (const float*)d_in[7];
    const float* lng   = (const float*)d_in[8];
    const float* lnb   = (const float*)d_in[9];
    const float* w1    = (const float*)d_in[10];
    const float* b1    = (const float*)d_in[11];
    const float* w2    = (const float*)d_in[12];
    const float* b2    = (const float*)d_in[13];
    const float* runif = (const float*)d_in[14];
    float* out = (float*)d_out;

    size_t off = 0;
    char* wsb = (char*)d_ws;
    auto take = [&](size_t bytes) -> char* {
        char* p = wsb + off;
        off += (bytes + 255) & ~(size_t)255;
        return p;
    };
    bf16_t* qkvh = (bf16_t*)take((size_t)NTOK * 3072 * 2);   // 25.2 MB
    bf16_t* qkvl = (bf16_t*)take((size_t)NTOK * 3072 * 2);   // 25.2 MB
    float*  obuf = (float*)take((size_t)NTOK * 1024 * 4);
    float*  ybuf = (float*)take((size_t)NTOK * 1024 * 4);
    float*  moe  = (float*)take((size_t)NTOK * 1024 * 4);
    bf16_t* eln  = (bf16_t*)take((size_t)NEXP * BSZ * CAPC * 1024 * 2);
    bf16_t* hbuf = (bf16_t*)take((size_t)NEXP * BSZ * CAPC * HFF_P * 2);
    uint32* tokpack = (uint32*)take(NTOK * 4);
    float*  tokg = (float*)take(NTOK * 8);
    uint32* r0   = (uint32*)take(NTOK * 4);
    uint32* r1   = (uint32*)take(NTOK * 4);
    int*    prev = (int*)take(128);
    float*  acc  = (float*)take(1024);
    // aliases: qkv hi/lo are dead after attention
    float*  ein  = (float*)qkvl;   // 21.0 MB <= 25.2
    float*  eoutv = (float*)qkvh;  // 21.0 MB <= 25.2

    zero_acc_kernel<<<1, 128, 0, stream>>>(acc);

    // QKV = x @ in_proj_w^T + b  (split precision); Q cols pre-scaled 1/8
    gemm_split<0, 1><<<dim3(24, 32), 256, 0, stream>>>(
        x, in_w, in_b, nullptr, qkvh, qkvl, nullptr,
        NTOK, 3072, 1024, 1024, 0.125f);

    attn_split<<<dim3(512), 256, 0, stream>>>(qkvh, qkvl, obuf);

    // y = o @ out_proj_w^T + b + x  (split precision, f32 out)
    gemm_split<2, 0><<<dim3(8, 32), 256, 0, stream>>>(
        obuf, out_w, out_b, x, nullptr, nullptr, ybuf,
        NTOK, 1024, 1024, 0, 1.0f);

    rmsnorm_kernel<<<NTOK, 256, 0, stream>>>(ybuf, rg, moe);
    gating_kernel<<<NTOK / 4, 256, 0, stream>>>(moe, gw, runif, tokpack, tokg, acc);
    scan_kernel<<<dim3(BSZ), 512, 0, stream>>>(tokpack, r0, r1, prev);
    gather_kernel<<<NTOK, 256, 0, stream>>>(moe, r0, r1, prev, ein);
    expert_ln_kernel<<<NEXP * BSZ * CAPC, 256, 0, stream>>>(ein, lng, lnb, eln);

    // h = LeakyReLU(LN @ w1^T + b1) -> bf16, padded cols [2730,2752) zeroed
    gemm_nt<1, 1, 64><<<dim3(22, 5, 16), 256, 0, stream>>>(
        eln, w1, b1, hbuf, 320, HFF_R, HFF_P, 1024, 1024,
        (long)320 * 1024, (long)HFF_R * 1024, HFF_R, (long)320 * HFF_P, HFF_P);

    // expert_out = h @ w2^T + b2 -> f32
    gemm_nt<0, 0, 64><<<dim3(8, 5, 16), 256, 0, stream>>>(
        hbuf, w2, b2, eoutv, 320, 1024, 1024, HFF_P, HFF_R,
        (long)320 * HFF_P, (long)1024 * HFF_R, 1024, (long)320 * 1024, 1024);

    combine_kernel<<<NTOK, 256, 0, stream>>>(ybuf, eoutv, r0, r1, tokg, prev, out);
    finalize_kernel<<<1, 64, 0, stream>>>(acc, out + (size_t)NTOK * 1024);
}